// Round 4
// baseline (1980.928 us; speedup 1.0000x reference)
//
#include <hip/hip_runtime.h>
#include <cstdint>
#include <cstddef>

// Model dims
constexpr int TT   = 64;    // T
constexpr int DD   = 512;   // D
constexpr int NHEAD= 8;
constexpr int DHH  = 64;
constexpr int NPIX = 196;   // 14*14
constexpr int CIN  = 768;
constexpr int KSEL = 44;    // int(0.7*64)
constexpr int NG_FM= 784;   // B*N
constexpr int NIMG = 256;   // B*T
// distance_adj underflow band: exp(-|0.6*d^2+0.2|) in fp32.
// d=12 -> 2.4e-38 (normal, nonzero). d=13 -> 7.6e-45 (subnormal -> FLUSHED
// to 0 on GPU f32 default FTZ; refs agree on this). d>=14 -> exact 0.
// So the reference's adj>0 gate bands the graph at |i-j| <= 12.
constexpr int DBAND = 12;

// ---------------------------------------------------------------------------
// K1: pre head 1x1 conv (768->512) + bias + ReLU, output written directly in
// graph layout ax[(b*196+hw)*64 + t][d].  Per block: one image n, one 64-wide
// o-tile; LDS-staged GEMM, LDS-staged transpose for coalesced global store.
// ---------------------------------------------------------------------------
__global__ __launch_bounds__(256) void k_preconv(
    const float* __restrict__ fmap, const float* __restrict__ pw,
    const float* __restrict__ pb, float* __restrict__ ax)
{
  __shared__ float arena[12740];                     // 50,960 B
  float (*As)[68]  = (float(*)[68])arena;            // [32][68]  As[kk][o]
  float (*Bs)[256] = (float(*)[256])(arena + 2176);  // [32][256] Bs[kk][hw]
  float (*Cs)[65]  = (float(*)[65])arena;            // [196][65] Cs[hw][o] (reuse)

  const int mt  = blockIdx.x;            // o tile (8)
  const int n   = blockIdx.y;            // image (256)
  const int b   = n >> 6, t = n & 63;
  const int tid = threadIdx.x;
  const int r   = tid >> 4, c = tid & 15;
  const int o0  = mt * 64;
  const float* fmn = fmap + (size_t)n * CIN * NPIX;

  float acc[4][16];
  #pragma unroll
  for (int i = 0; i < 4; i++)
    #pragma unroll
    for (int j = 0; j < 16; j++) acc[i][j] = 0.f;

  for (int k0 = 0; k0 < CIN; k0 += 32) {
    for (int i = tid; i < 2048; i += 256) {          // A tile
      int o = i >> 5, kk = i & 31;
      As[kk][o] = pw[(size_t)(o0 + o) * CIN + k0 + kk];
    }
    for (int i = tid; i < 2048; i += 256) {          // B tile (pad cols 196..255 = 0)
      int kk = i >> 6, q4 = i & 63;
      float4 v;
      if (q4 * 4 < NPIX) v = *(const float4*)&fmn[(size_t)(k0 + kk) * NPIX + q4 * 4];
      else               v = make_float4(0.f, 0.f, 0.f, 0.f);
      *(float4*)&Bs[kk][q4 * 4] = v;
    }
    __syncthreads();
    #pragma unroll 4
    for (int kk = 0; kk < 32; kk++) {
      float4 a4 = *(const float4*)&As[kk][r * 4];
      float av[4] = {a4.x, a4.y, a4.z, a4.w};
      #pragma unroll
      for (int q = 0; q < 4; q++) {
        float4 b4 = *(const float4*)&Bs[kk][(c + 16 * q) * 4];
        float bv[4] = {b4.x, b4.y, b4.z, b4.w};
        #pragma unroll
        for (int di = 0; di < 4; di++)
          #pragma unroll
          for (int e = 0; e < 4; e++)
            acc[di][q * 4 + e] += av[di] * bv[e];
      }
    }
    __syncthreads();
  }

  // bias + relu -> Cs[hw][o]
  float4 pb4 = *(const float4*)&pb[o0 + r * 4];
  float bias[4] = {pb4.x, pb4.y, pb4.z, pb4.w};
  #pragma unroll
  for (int q = 0; q < 4; q++)
    #pragma unroll
    for (int e = 0; e < 4; e++) {
      int hw = (c + 16 * q) * 4 + e;
      if (hw < NPIX) {
        #pragma unroll
        for (int di = 0; di < 4; di++) {
          float v = acc[di][q * 4 + e] + bias[di];
          Cs[hw][r * 4 + di] = v > 0.f ? v : 0.f;
        }
      }
    }
  __syncthreads();
  for (int i = tid; i < NPIX * 64; i += 256) {       // coalesced store
    int hw = i >> 6, o = i & 63;
    ax[((size_t)(b * NPIX + hw) * TT + t) * DD + o0 + o] = Cs[hw][o];
  }
}

// ---------------------------------------------------------------------------
// B-matrix preps: put both W (heads-concat) and lin_w into (K x N) row-major.
// ---------------------------------------------------------------------------
__global__ void k_prepW(const float* __restrict__ W, float* __restrict__ o)
{
  int m = blockIdx.x * 256 + threadIdx.x;            // < 262144
  int k = m >> 9, j = m & 511;
  o[m] = W[(size_t)(j >> 6) * (DD * DHH) + (size_t)k * DHH + (j & 63)];
}

__global__ __launch_bounds__(256) void k_prepT(const float* __restrict__ a, float* __restrict__ o)
{
  __shared__ float tile[64][65];
  int j0 = blockIdx.x * 64, k0 = blockIdx.y * 64;
  for (int i = threadIdx.x; i < 4096; i += 256) {
    int jl = i >> 6, kk = i & 63;
    tile[jl][kk] = a[(size_t)(j0 + jl) * DD + k0 + kk];
  }
  __syncthreads();
  for (int i = threadIdx.x; i < 4096; i += 256) {
    int kk = i >> 6, jl = i & 63;
    o[(size_t)(k0 + kk) * DD + j0 + jl] = tile[jl][kk];
  }
}

// ---------------------------------------------------------------------------
// K2: per-graph top-k selection bitmask (rank by fp64 squared row norm, ties
// by lower index to match jax.lax.top_k).
// ---------------------------------------------------------------------------
__global__ void k_topk(const float* __restrict__ x, unsigned long long* __restrict__ sel)
{
  int g = blockIdx.x, lane = threadIdx.x;            // 64 threads
  const float* row = x + ((size_t)g * TT + lane) * DD;
  double s = 0.0;
  for (int dd = 0; dd < DD; dd += 4) {
    float4 v = *(const float4*)(row + dd);
    s += (double)v.x * (double)v.x + (double)v.y * (double)v.y
       + (double)v.z * (double)v.z + (double)v.w * (double)v.w;
  }
  __shared__ double mag[64];
  mag[lane] = s;
  __syncthreads();
  int rank = 0;
  for (int j = 0; j < 64; j++) {
    double m = mag[j];
    rank += (m > s) || (m == s && j < lane);
  }
  unsigned long long bal = __ballot(rank < KSEL);
  if (lane == 0) sel[g] = bal;
}

// ---------------------------------------------------------------------------
// K3a/K4: per-graph GEMM  Out[g] = A[g](64x512) @ Bt(512x512) [+bias][+Res]
// grid (jb=2, g). Bt is (K x N) row-major. Out may alias Res (in-place).
// ---------------------------------------------------------------------------
__global__ __launch_bounds__(256) void k_ggemm(
    const float* __restrict__ A, const float* __restrict__ Bt,
    const float* __restrict__ bias, const float* __restrict__ Res,
    float* __restrict__ Out)
{
  __shared__ float ast[32][72];     // [kk][t]
  __shared__ float bs[32][260];     // [kk][j]
  const int jb = blockIdx.x, g = blockIdx.y;
  const int tid = threadIdx.x;
  const int tr = tid >> 5, tc = tid & 31;
  const int j0 = jb * 256;
  const float* Ag = A + (size_t)g * TT * DD;
  float acc[8][8];
  #pragma unroll
  for (int i = 0; i < 8; i++)
    #pragma unroll
    for (int j = 0; j < 8; j++) acc[i][j] = 0.f;

  for (int k0 = 0; k0 < DD; k0 += 32) {
    for (int i = tid; i < 2048; i += 256) {
      int kk = i >> 6, t = i & 63;
      ast[kk][t] = Ag[(size_t)t * DD + k0 + kk];
    }
    for (int i = tid; i < 2048; i += 256) {
      int kk = i >> 6, jq = i & 63;
      *(float4*)&bs[kk][jq * 4] = *(const float4*)&Bt[(size_t)(k0 + kk) * DD + j0 + jq * 4];
    }
    __syncthreads();
    #pragma unroll 4
    for (int kk = 0; kk < 32; kk++) {
      float4 a0 = *(const float4*)&ast[kk][tr * 8];
      float4 a1 = *(const float4*)&ast[kk][tr * 8 + 4];
      float4 b0 = *(const float4*)&bs[kk][tc * 8];
      float4 b1 = *(const float4*)&bs[kk][tc * 8 + 4];
      float av[8] = {a0.x, a0.y, a0.z, a0.w, a1.x, a1.y, a1.z, a1.w};
      float bv[8] = {b0.x, b0.y, b0.z, b0.w, b1.x, b1.y, b1.z, b1.w};
      #pragma unroll
      for (int di = 0; di < 8; di++)
        #pragma unroll
        for (int dj = 0; dj < 8; dj++)
          acc[di][dj] += av[di] * bv[dj];
    }
    __syncthreads();
  }

  float* Og = Out + (size_t)g * TT * DD;
  const float* Rg = Res ? (Res + (size_t)g * TT * DD) : nullptr;
  #pragma unroll
  for (int di = 0; di < 8; di++) {
    int t = tr * 8 + di;
    int j = j0 + tc * 8;
    float o8[8];
    #pragma unroll
    for (int dj = 0; dj < 8; dj++) o8[dj] = acc[di][dj];
    if (bias) {
      float4 bb0 = *(const float4*)&bias[j];
      float4 bb1 = *(const float4*)&bias[j + 4];
      o8[0] += bb0.x; o8[1] += bb0.y; o8[2] += bb0.z; o8[3] += bb0.w;
      o8[4] += bb1.x; o8[5] += bb1.y; o8[6] += bb1.z; o8[7] += bb1.w;
    }
    if (Rg) {
      float4 r0 = *(const float4*)&Rg[(size_t)t * DD + j];
      float4 r1 = *(const float4*)&Rg[(size_t)t * DD + j + 4];
      o8[0] += r0.x; o8[1] += r0.y; o8[2] += r0.z; o8[3] += r0.w;
      o8[4] += r1.x; o8[5] += r1.y; o8[6] += r1.z; o8[7] += r1.w;
    }
    *(float4*)&Og[(size_t)t * DD + j]     = make_float4(o8[0], o8[1], o8[2], o8[3]);
    *(float4*)&Og[(size_t)t * DD + j + 4] = make_float4(o8[4], o8[5], o8[6], o8[7]);
  }
}

// ---------------------------------------------------------------------------
// K3b: fused GAT attention per (head, graph): e = leaky(s1[i]+s2[j]) masked by
// (sel_i|sel_j) AND |i-j|<=DBAND (fp32 underflow band of distance_adj);
// softmax; out = attn@h; elu; signed-sqrt; column-normalize over T; in-place.
// ---------------------------------------------------------------------------
__global__ __launch_bounds__(256) void k_attn(
    float* __restrict__ tmp, const float* __restrict__ a1v,
    const float* __restrict__ a2v, const unsigned long long* __restrict__ sel)
{
  __shared__ float hs[64][68];
  __shared__ float attnv[64][68];
  __shared__ float s1[64], s2[64], aw[128], cnorm[64];
  const int h = blockIdx.x, g = blockIdx.y;
  const int tid = threadIdx.x;
  const int r = tid >> 4, c = tid & 15;
  float* base = tmp + (size_t)g * TT * DD + h * DHH;

  for (int i = tid; i < 4096; i += 256) {
    int t = i >> 6, dh = i & 63;
    hs[t][dh] = base[(size_t)t * DD + dh];
  }
  if (tid < 128) aw[tid] = (tid < 64) ? a1v[h * 64 + tid] : a2v[h * 64 + (tid - 64)];
  __syncthreads();

  if (tid < 64) {
    float v1 = 0.f, v2 = 0.f;
    for (int dh = 0; dh < 64; dh++) { float hv = hs[tid][dh]; v1 += hv * aw[dh]; v2 += hv * aw[64 + dh]; }
    s1[tid] = v1; s2[tid] = v2;
  }
  __syncthreads();

  const unsigned long long sm = sel[g];
  if (tid < 64) {
    const int i = tid;
    const bool seli = (sm >> i) & 1ULL;
    const float vi = s1[i];
    float mx = -1e30f;
    for (int j = 0; j < 64; j++) {
      float e = vi + s2[j];
      e = e >= 0.f ? e : 0.2f * e;                   // leaky_relu(0.2)
      int dist = i > j ? i - j : j - i;
      bool ok = (seli || ((sm >> j) & 1ULL)) && (dist <= DBAND);
      e = ok ? e : -9e15f;
      attnv[i][j] = e;
      mx = fmaxf(mx, e);
    }
    float sum = 0.f;
    for (int j = 0; j < 64; j++) { float p = expf(attnv[i][j] - mx); attnv[i][j] = p; sum += p; }
    float inv = 1.f / sum;
    for (int j = 0; j < 64; j++) attnv[i][j] *= inv;
  }
  __syncthreads();

  float oc[4][4];
  #pragma unroll
  for (int i = 0; i < 4; i++)
    #pragma unroll
    for (int j = 0; j < 4; j++) oc[i][j] = 0.f;
  for (int j = 0; j < 64; j++) {
    float p[4];
    #pragma unroll
    for (int di = 0; di < 4; di++) p[di] = attnv[r * 4 + di][j];
    float4 hv = *(const float4*)&hs[j][c * 4];
    float hb[4] = {hv.x, hv.y, hv.z, hv.w};
    #pragma unroll
    for (int di = 0; di < 4; di++)
      #pragma unroll
      for (int dj = 0; dj < 4; dj++)
        oc[di][dj] += p[di] * hb[dj];
  }

  // elu -> signed sqrt -> per-column squared partials
  float cs4[4] = {0.f, 0.f, 0.f, 0.f};
  #pragma unroll
  for (int di = 0; di < 4; di++)
    #pragma unroll
    for (int dj = 0; dj < 4; dj++) {
      float v = oc[di][dj];
      v = v > 0.f ? v : expm1f(v);
      v = v >= 0.f ? sqrtf(v) : -sqrtf(-v);
      oc[di][dj] = v;
      cs4[dj] += v * v;
    }
  __syncthreads();                                    // all done reading attnv/hs
  *(float4*)&attnv[r][c * 4] = make_float4(cs4[0], cs4[1], cs4[2], cs4[3]);
  __syncthreads();
  if (tid < 64) {
    float ssum = 0.f;
    for (int rr = 0; rr < 16; rr++) ssum += attnv[rr][tid];
    cnorm[tid] = fmaxf(sqrtf(ssum), 1e-12f);
  }
  __syncthreads();
  float4 cn = *(const float4*)&cnorm[c * 4];
  float inv4[4] = {1.f / cn.x, 1.f / cn.y, 1.f / cn.z, 1.f / cn.w};
  #pragma unroll
  for (int di = 0; di < 4; di++) {
    float4 o4 = make_float4(oc[di][0] * inv4[0], oc[di][1] * inv4[1],
                            oc[di][2] * inv4[2], oc[di][3] * inv4[3]);
    *(float4*)&base[(size_t)(r * 4 + di) * DD + c * 4] = o4;
  }
}

// ---------------------------------------------------------------------------
// K5: LayerNorm in-place, one wave per 512-row.
// ---------------------------------------------------------------------------
__global__ void k_ln(float* __restrict__ x, const float* __restrict__ gam, const float* __restrict__ bet)
{
  const size_t row = blockIdx.x;
  const int lane = threadIdx.x;
  float* p = x + row * DD + lane * 8;
  float4 v0 = *(float4*)p;
  float4 v1 = *(float4*)(p + 4);
  float va[8] = {v0.x, v0.y, v0.z, v0.w, v1.x, v1.y, v1.z, v1.w};
  float s = 0.f;
  #pragma unroll
  for (int i = 0; i < 8; i++) s += va[i];
  #pragma unroll
  for (int m = 32; m >= 1; m >>= 1) s += __shfl_xor(s, m);
  float mean = s * (1.f / 512.f);
  float q = 0.f;
  #pragma unroll
  for (int i = 0; i < 8; i++) { float d = va[i] - mean; q += d * d; }
  #pragma unroll
  for (int m = 32; m >= 1; m >>= 1) q += __shfl_xor(q, m);
  float rstd = rsqrtf(q * (1.f / 512.f) + 1e-5f);
  const float* gp = gam + lane * 8;
  const float* bp = bet + lane * 8;
  float4 g0 = *(const float4*)gp, g1 = *(const float4*)(gp + 4);
  float4 b0 = *(const float4*)bp, b1 = *(const float4*)(bp + 4);
  float ga[8] = {g0.x, g0.y, g0.z, g0.w, g1.x, g1.y, g1.z, g1.w};
  float ba[8] = {b0.x, b0.y, b0.z, b0.w, b1.x, b1.y, b1.z, b1.w};
  float o[8];
  #pragma unroll
  for (int i = 0; i < 8; i++) o[i] = (va[i] - mean) * rstd * ga[i] + ba[i];
  *(float4*)p       = make_float4(o[0], o[1], o[2], o[3]);
  *(float4*)(p + 4) = make_float4(o[4], o[5], o[6], o[7]);
}

// ---------------------------------------------------------------------------
// K6: post head 1x1 conv (512->1): one wave per (b,t,hw) output.
// ---------------------------------------------------------------------------
__global__ void k_post(const float* __restrict__ y, const float* __restrict__ pw,
                       const float* __restrict__ pb, float* __restrict__ outp)
{
  int m = blockIdx.x * 4 + (threadIdx.x >> 6);
  int lane = threadIdx.x & 63;
  int b = m / 12544;
  int rem = m - b * 12544;
  int t = rem / 196;
  int hw = rem - t * 196;
  const float* row = y + ((size_t)(b * NPIX + hw) * TT + t) * DD + lane * 8;
  float4 a0 = *(const float4*)row, a1 = *(const float4*)(row + 4);
  float4 w0 = *(const float4*)(pw + lane * 8), w1 = *(const float4*)(pw + lane * 8 + 4);
  float s = a0.x * w0.x + a0.y * w0.y + a0.z * w0.z + a0.w * w0.w
          + a1.x * w1.x + a1.y * w1.y + a1.z * w1.z + a1.w * w1.w;
  #pragma unroll
  for (int mm = 32; mm >= 1; mm >>= 1) s += __shfl_xor(s, mm);
  if (lane == 0) outp[m] = s + pb[0];
}

// ---------------------------------------------------------------------------
// K7: classifier Conv1d(512->512)+GELU(exact)+Conv1d(512->1), one block per (b,t).
// ---------------------------------------------------------------------------
__global__ __launch_bounds__(256) void k_cls(
    const float* __restrict__ xv, const float* __restrict__ w1,
    const float* __restrict__ b1, const float* __restrict__ w2,
    const float* __restrict__ b2, float* __restrict__ outp)
{
  const int m = blockIdx.x;                          // b*64+t
  const int tid = threadIdx.x;
  __shared__ float xr[512];
  __shared__ float red[256];
  xr[tid] = xv[(size_t)m * DD + tid];
  xr[tid + 256] = xv[(size_t)m * DD + tid + 256];
  __syncthreads();
  float part = 0.f;
  for (int o = tid; o < 512; o += 256) {
    const float* wr = w1 + (size_t)o * DD;
    float d = 0.f;
    for (int cc = 0; cc < DD; cc += 4) {
      float4 wv = *(const float4*)(wr + cc);
      d += wv.x * xr[cc] + wv.y * xr[cc + 1] + wv.z * xr[cc + 2] + wv.w * xr[cc + 3];
    }
    d += b1[o];
    float ge = 0.5f * d * (1.0f + erff(d * 0.70710678118654752f));
    part += ge * w2[o];
  }
  red[tid] = part;
  __syncthreads();
  for (int s = 128; s > 0; s >>= 1) {
    if (tid < s) red[tid] += red[tid + s];
    __syncthreads();
  }
  if (tid == 0) outp[m] = red[0] + b2[0];
}

// ---------------------------------------------------------------------------
extern "C" void kernel_launch(void* const* d_in, const int* in_sizes, int n_in,
                              void* d_out, int out_size, void* d_ws, size_t ws_size,
                              hipStream_t stream)
{
  const float* x_v    = (const float*)d_in[0];
  const float* fmap   = (const float*)d_in[1];
  const float* pre_w  = (const float*)d_in[2];
  const float* pre_b  = (const float*)d_in[3];
  const float* post_w = (const float*)d_in[4];
  const float* post_b = (const float*)d_in[5];
  const float* tm_W   = (const float*)d_in[6];
  const float* tm_a1  = (const float*)d_in[7];
  const float* tm_a2  = (const float*)d_in[8];
  const float* tm_lw  = (const float*)d_in[9];
  const float* tm_lb  = (const float*)d_in[10];
  const float* tm_g   = (const float*)d_in[11];
  const float* tm_b   = (const float*)d_in[12];
  const float* fm_W   = (const float*)d_in[13];
  const float* fm_a1  = (const float*)d_in[14];
  const float* fm_a2  = (const float*)d_in[15];
  const float* fm_lw  = (const float*)d_in[16];
  const float* fm_lb  = (const float*)d_in[17];
  const float* fm_g   = (const float*)d_in[18];
  const float* fm_b   = (const float*)d_in[19];
  const float* c_w1   = (const float*)d_in[20];
  const float* c_b1   = (const float*)d_in[21];
  const float* c_w2   = (const float*)d_in[22];
  const float* c_b2   = (const float*)d_in[23];
  float* out = (float*)d_out;

  // workspace carve-up (floats)
  float* wsf    = (float*)d_ws;
  float* ax     = wsf;                     // 784*64*512 = 25,690,112
  float* tmp    = ax + 25690112;           // 25,690,112
  float* xtm    = tmp + 25690112;          // 131,072
  float* tmptm  = xtm + 131072;            // 131,072
  float* WT_fm  = tmptm + 131072;          // 262,144
  float* WT_tm  = WT_fm + 262144;          // 262,144
  float* lwT_fm = WT_tm + 262144;          // 262,144
  float* lwT_tm = lwT_fm + 262144;         // 262,144
  unsigned long long* sel_fm = (unsigned long long*)(lwT_tm + 262144); // 784
  unsigned long long* sel_tm = sel_fm + 784;                           // 4

  // 1) pre head conv -> graph-layout ax
  k_preconv<<<dim3(8, 256), 256, 0, stream>>>(fmap, pre_w, pre_b, ax);

  // 2) weight preps (tiny)
  k_prepW<<<1024, 256, 0, stream>>>(fm_W, WT_fm);
  k_prepW<<<1024, 256, 0, stream>>>(tm_W, WT_tm);
  k_prepT<<<dim3(8, 8), 256, 0, stream>>>(fm_lw, lwT_fm);
  k_prepT<<<dim3(8, 8), 256, 0, stream>>>(tm_lw, lwT_tm);

  // 3) top-k selection bitmasks (fp64 ranking)
  k_topk<<<NG_FM, 64, 0, stream>>>(ax, sel_fm);
  k_topk<<<4, 64, 0, stream>>>(x_v, sel_tm);

  // 4) h = x @ Wcat  (all heads fused as one 512-wide GEMM)
  k_ggemm<<<dim3(2, NG_FM), 256, 0, stream>>>(ax, WT_fm, nullptr, nullptr, tmp);
  k_ggemm<<<dim3(2, 4), 256, 0, stream>>>(x_v, WT_tm, nullptr, nullptr, tmptm);

  // 5) fused attention + elu + signed-sqrt + column-normalize (in-place on h)
  k_attn<<<dim3(NHEAD, NG_FM), 256, 0, stream>>>(tmp, fm_a1, fm_a2, sel_fm);
  k_attn<<<dim3(NHEAD, 4), 256, 0, stream>>>(tmptm, tm_a1, tm_a2, sel_tm);

  // 6) x = x + tmp @ lin_w.T + lin_b  (in-place on x buffers)
  hipMemcpyAsync(xtm, x_v, (size_t)131072 * 4, hipMemcpyDeviceToDevice, stream);
  k_ggemm<<<dim3(2, NG_FM), 256, 0, stream>>>(tmp, lwT_fm, fm_lb, ax, ax);
  k_ggemm<<<dim3(2, 4), 256, 0, stream>>>(tmptm, lwT_tm, tm_lb, xtm, xtm);

  // 7) layernorm in-place
  k_ln<<<NG_FM * TT, 64, 0, stream>>>(ax, fm_g, fm_b);
  k_ln<<<NIMG, 64, 0, stream>>>(xtm, tm_g, tm_b);

  // 8) post head -> ano_map (d_out offset 256), classifier -> logits (d_out[0:256])
  k_post<<<12544, 256, 0, stream>>>(ax, post_w, post_b, out + 256);
  k_cls<<<NIMG, 256, 0, stream>>>(xtm, c_w1, c_b1, c_w2, c_b2, out);
}

// Round 5
// 1663.420 us; speedup vs baseline: 1.1909x; 1.1909x over previous
//
#include <hip/hip_runtime.h>
#include <cstdint>
#include <cstddef>

// Model dims
constexpr int TT   = 64;    // T
constexpr int DD   = 512;   // D
constexpr int NHEAD= 8;
constexpr int DHH  = 64;
constexpr int NPIX = 196;   // 14*14
constexpr int CIN  = 768;
constexpr int KSEL = 44;    // int(0.7*64)
constexpr int NG_FM= 784;   // B*N
constexpr int NIMG = 256;   // B*T
// distance_adj underflow band: exp(-|0.6*d^2+0.2|) in fp32.
// d=12 -> 2.4e-38 (normal, nonzero). d=13 -> subnormal -> flushed to 0 (FTZ).
// d>=14 -> exact 0. So the reference's adj>0 gate bands the graph at |i-j|<=12.
constexpr int DBAND = 12;

typedef __attribute__((ext_vector_type(8))) short bf16x8;
typedef __attribute__((ext_vector_type(4))) float f32x4;

__device__ __forceinline__ short bfr(float x) {
  union { float f; unsigned u; } v; v.f = x;
  unsigned r = (v.u + 0x7fffu + ((v.u >> 16) & 1u)) >> 16;   // RNE
  return (short)r;
}

// ---------------------------------------------------------------------------
// K1: pre head 1x1 conv (768->512) + bias + ReLU, output written directly in
// graph layout ax[(b*196+hw)*64 + t][d].  (fp32: feeds top-k ranking; will be
// converted to split-bf16 MFMA once fragment layout is HW-validated.)
// ---------------------------------------------------------------------------
__global__ __launch_bounds__(256) void k_preconv(
    const float* __restrict__ fmap, const float* __restrict__ pw,
    const float* __restrict__ pb, float* __restrict__ ax)
{
  __shared__ float arena[12740];                     // 50,960 B
  float (*As)[68]  = (float(*)[68])arena;            // [32][68]  As[kk][o]
  float (*Bs)[256] = (float(*)[256])(arena + 2176);  // [32][256] Bs[kk][hw]
  float (*Cs)[65]  = (float(*)[65])arena;            // [196][65] Cs[hw][o] (reuse)

  const int mt  = blockIdx.x;            // o tile (8)
  const int n   = blockIdx.y;            // image (256)
  const int b   = n >> 6, t = n & 63;
  const int tid = threadIdx.x;
  const int r   = tid >> 4, c = tid & 15;
  const int o0  = mt * 64;
  const float* fmn = fmap + (size_t)n * CIN * NPIX;

  float acc[4][16];
  #pragma unroll
  for (int i = 0; i < 4; i++)
    #pragma unroll
    for (int j = 0; j < 16; j++) acc[i][j] = 0.f;

  for (int k0 = 0; k0 < CIN; k0 += 32) {
    for (int i = tid; i < 2048; i += 256) {          // A tile
      int o = i >> 5, kk = i & 31;
      As[kk][o] = pw[(size_t)(o0 + o) * CIN + k0 + kk];
    }
    for (int i = tid; i < 2048; i += 256) {          // B tile (pad cols 196..255 = 0)
      int kk = i >> 6, q4 = i & 63;
      float4 v;
      if (q4 * 4 < NPIX) v = *(const float4*)&fmn[(size_t)(k0 + kk) * NPIX + q4 * 4];
      else               v = make_float4(0.f, 0.f, 0.f, 0.f);
      *(float4*)&Bs[kk][q4 * 4] = v;
    }
    __syncthreads();
    #pragma unroll 4
    for (int kk = 0; kk < 32; kk++) {
      float4 a4 = *(const float4*)&As[kk][r * 4];
      float av[4] = {a4.x, a4.y, a4.z, a4.w};
      #pragma unroll
      for (int q = 0; q < 4; q++) {
        float4 b4 = *(const float4*)&Bs[kk][(c + 16 * q) * 4];
        float bv[4] = {b4.x, b4.y, b4.z, b4.w};
        #pragma unroll
        for (int di = 0; di < 4; di++)
          #pragma unroll
          for (int e = 0; e < 4; e++)
            acc[di][q * 4 + e] += av[di] * bv[e];
      }
    }
    __syncthreads();
  }

  // bias + relu -> Cs[hw][o]
  float4 pb4 = *(const float4*)&pb[o0 + r * 4];
  float bias[4] = {pb4.x, pb4.y, pb4.z, pb4.w};
  #pragma unroll
  for (int q = 0; q < 4; q++)
    #pragma unroll
    for (int e = 0; e < 4; e++) {
      int hw = (c + 16 * q) * 4 + e;
      if (hw < NPIX) {
        #pragma unroll
        for (int di = 0; di < 4; di++) {
          float v = acc[di][q * 4 + e] + bias[di];
          Cs[hw][r * 4 + di] = v > 0.f ? v : 0.f;
        }
      }
    }
  __syncthreads();
  for (int i = tid; i < NPIX * 64; i += 256) {       // coalesced store
    int hw = i >> 6, o = i & 63;
    ax[((size_t)(b * NPIX + hw) * TT + t) * DD + o0 + o] = Cs[hw][o];
  }
}

// ---------------------------------------------------------------------------
// Weight preps -> bf16, N-major [j][k] so MFMA B-fragments are contiguous-K.
// ---------------------------------------------------------------------------
__global__ void k_prepWb(const float* __restrict__ W, short* __restrict__ o)
{
  int m = blockIdx.x * 256 + threadIdx.x;            // j*512+k, < 262144
  int j = m >> 9, k = m & 511;
  o[m] = bfr(W[(size_t)(j >> 6) * (DD * DHH) + (size_t)k * DHH + (j & 63)]);
}

__global__ void k_prepLWb(const float* __restrict__ a, short* __restrict__ o)
{
  int m = blockIdx.x * 256 + threadIdx.x;            // lin_w is already [j][k]
  o[m] = bfr(a[m]);
}

// ---------------------------------------------------------------------------
// K2: per-graph top-k selection bitmask (rank by fp64 squared row norm, ties
// by lower index to match jax.lax.top_k).
// ---------------------------------------------------------------------------
__global__ void k_topk(const float* __restrict__ x, unsigned long long* __restrict__ sel)
{
  int g = blockIdx.x, lane = threadIdx.x;            // 64 threads
  const float* row = x + ((size_t)g * TT + lane) * DD;
  double s = 0.0;
  for (int dd = 0; dd < DD; dd += 4) {
    float4 v = *(const float4*)(row + dd);
    s += (double)v.x * (double)v.x + (double)v.y * (double)v.y
       + (double)v.z * (double)v.z + (double)v.w * (double)v.w;
  }
  __shared__ double mag[64];
  mag[lane] = s;
  __syncthreads();
  int rank = 0;
  for (int j = 0; j < 64; j++) {
    double m = mag[j];
    rank += (m > s) || (m == s && j < lane);
  }
  unsigned long long bal = __ballot(rank < KSEL);
  if (lane == 0) sel[g] = bal;
}

// ---------------------------------------------------------------------------
// K3a/K4: per-graph MFMA GEMM  Out[g](64x512) = A[g](64x512,f32) @ Bb^T
// with Bb bf16 N-major [j][k]; optional +bias +Res; Out may alias Res.
// Grid (jb=4, g); block 256 = 4 waves. Wave w owns rows [w*16,w*16+16) and
// all 8 col-tiles of the block's 128-col slab. No LDS, no barriers.
// MFMA fragments (16x16x32 bf16): A/B lane l -> row/col = l&15,
// k = (l>>4)*8 + 0..7 (contiguous); C/D: col = l&15, row = (l>>4)*4 + reg.
// ---------------------------------------------------------------------------
__global__ __launch_bounds__(256) void k_gmfma(
    const float* __restrict__ A, const short* __restrict__ Bb,
    const float* __restrict__ bias, const float* __restrict__ Res,
    float* __restrict__ Out)
{
  const int jb = blockIdx.x, g = blockIdx.y;
  const int tid = threadIdx.x;
  const int w = tid >> 6, l = tid & 63;
  const int lr = l & 15, lg = l >> 4;
  const float* Ar = A + (size_t)g * TT * DD + (size_t)(w * 16 + lr) * DD;

  f32x4 acc[8] = {};

  for (int ks = 0; ks < 16; ks++) {
    const int kb = ks * 32 + lg * 8;
    float4 a0 = *(const float4*)(Ar + kb);
    float4 a1 = *(const float4*)(Ar + kb + 4);
    bf16x8 af;
    af[0] = bfr(a0.x); af[1] = bfr(a0.y); af[2] = bfr(a0.z); af[3] = bfr(a0.w);
    af[4] = bfr(a1.x); af[5] = bfr(a1.y); af[6] = bfr(a1.z); af[7] = bfr(a1.w);
    #pragma unroll
    for (int ct = 0; ct < 8; ct++) {
      const int j = jb * 128 + ct * 16 + lr;
      bf16x8 bb = *(const bf16x8*)&Bb[(size_t)j * DD + kb];
      acc[ct] = __builtin_amdgcn_mfma_f32_16x16x32_bf16(af, bb, acc[ct], 0, 0, 0);
    }
  }

  float* Og = Out + (size_t)g * TT * DD;
  const float* Rg = Res ? (Res + (size_t)g * TT * DD) : nullptr;
  #pragma unroll
  for (int ct = 0; ct < 8; ct++) {
    const int j = jb * 128 + ct * 16 + lr;
    const float bv = bias ? bias[j] : 0.f;
    #pragma unroll
    for (int r = 0; r < 4; r++) {
      const int row = w * 16 + lg * 4 + r;
      float v = acc[ct][r] + bv;
      if (Rg) v += Rg[(size_t)row * DD + j];
      Og[(size_t)row * DD + j] = v;
    }
  }
}

// ---------------------------------------------------------------------------
// K3b: fused GAT attention per (head, graph): e = leaky(s1[i]+s2[j]) masked by
// (sel_i|sel_j) AND |i-j|<=DBAND; softmax; out = attn@h; elu; signed-sqrt;
// column-normalize over T; in-place.
// ---------------------------------------------------------------------------
__global__ __launch_bounds__(256) void k_attn(
    float* __restrict__ tmp, const float* __restrict__ a1v,
    const float* __restrict__ a2v, const unsigned long long* __restrict__ sel)
{
  __shared__ float hs[64][68];
  __shared__ float attnv[64][68];
  __shared__ float s1[64], s2[64], aw[128], cnorm[64];
  const int h = blockIdx.x, g = blockIdx.y;
  const int tid = threadIdx.x;
  const int r = tid >> 4, c = tid & 15;
  float* base = tmp + (size_t)g * TT * DD + h * DHH;

  for (int i = tid; i < 4096; i += 256) {
    int t = i >> 6, dh = i & 63;
    hs[t][dh] = base[(size_t)t * DD + dh];
  }
  if (tid < 128) aw[tid] = (tid < 64) ? a1v[h * 64 + tid] : a2v[h * 64 + (tid - 64)];
  __syncthreads();

  if (tid < 64) {
    float v1 = 0.f, v2 = 0.f;
    for (int dh = 0; dh < 64; dh++) { float hv = hs[tid][dh]; v1 += hv * aw[dh]; v2 += hv * aw[64 + dh]; }
    s1[tid] = v1; s2[tid] = v2;
  }
  __syncthreads();

  const unsigned long long sm = sel[g];
  if (tid < 64) {
    const int i = tid;
    const bool seli = (sm >> i) & 1ULL;
    const float vi = s1[i];
    float mx = -1e30f;
    for (int j = 0; j < 64; j++) {
      float e = vi + s2[j];
      e = e >= 0.f ? e : 0.2f * e;                   // leaky_relu(0.2)
      int dist = i > j ? i - j : j - i;
      bool ok = (seli || ((sm >> j) & 1ULL)) && (dist <= DBAND);
      e = ok ? e : -9e15f;
      attnv[i][j] = e;
      mx = fmaxf(mx, e);
    }
    float sum = 0.f;
    for (int j = 0; j < 64; j++) { float p = expf(attnv[i][j] - mx); attnv[i][j] = p; sum += p; }
    float inv = 1.f / sum;
    for (int j = 0; j < 64; j++) attnv[i][j] *= inv;
  }
  __syncthreads();

  float oc[4][4];
  #pragma unroll
  for (int i = 0; i < 4; i++)
    #pragma unroll
    for (int j = 0; j < 4; j++) oc[i][j] = 0.f;
  for (int j = 0; j < 64; j++) {
    float p[4];
    #pragma unroll
    for (int di = 0; di < 4; di++) p[di] = attnv[r * 4 + di][j];
    float4 hv = *(const float4*)&hs[j][c * 4];
    float hb[4] = {hv.x, hv.y, hv.z, hv.w};
    #pragma unroll
    for (int di = 0; di < 4; di++)
      #pragma unroll
      for (int dj = 0; dj < 4; dj++)
        oc[di][dj] += p[di] * hb[dj];
  }

  // elu -> signed sqrt -> per-column squared partials
  float cs4[4] = {0.f, 0.f, 0.f, 0.f};
  #pragma unroll
  for (int di = 0; di < 4; di++)
    #pragma unroll
    for (int dj = 0; dj < 4; dj++) {
      float v = oc[di][dj];
      v = v > 0.f ? v : expm1f(v);
      v = v >= 0.f ? sqrtf(v) : -sqrtf(-v);
      oc[di][dj] = v;
      cs4[dj] += v * v;
    }
  __syncthreads();                                    // all done reading attnv/hs
  *(float4*)&attnv[r][c * 4] = make_float4(cs4[0], cs4[1], cs4[2], cs4[3]);
  __syncthreads();
  if (tid < 64) {
    float ssum = 0.f;
    for (int rr = 0; rr < 16; rr++) ssum += attnv[rr][tid];
    cnorm[tid] = fmaxf(sqrtf(ssum), 1e-12f);
  }
  __syncthreads();
  float4 cn = *(const float4*)&cnorm[c * 4];
  float inv4[4] = {1.f / cn.x, 1.f / cn.y, 1.f / cn.z, 1.f / cn.w};
  #pragma unroll
  for (int di = 0; di < 4; di++) {
    float4 o4 = make_float4(oc[di][0] * inv4[0], oc[di][1] * inv4[1],
                            oc[di][2] * inv4[2], oc[di][3] * inv4[3]);
    *(float4*)&base[(size_t)(r * 4 + di) * DD + c * 4] = o4;
  }
}

// ---------------------------------------------------------------------------
// K5: LayerNorm in-place, one wave per 512-row.
// ---------------------------------------------------------------------------
__global__ void k_ln(float* __restrict__ x, const float* __restrict__ gam, const float* __restrict__ bet)
{
  const size_t row = blockIdx.x;
  const int lane = threadIdx.x;
  float* p = x + row * DD + lane * 8;
  float4 v0 = *(float4*)p;
  float4 v1 = *(float4*)(p + 4);
  float va[8] = {v0.x, v0.y, v0.z, v0.w, v1.x, v1.y, v1.z, v1.w};
  float s = 0.f;
  #pragma unroll
  for (int i = 0; i < 8; i++) s += va[i];
  #pragma unroll
  for (int m = 32; m >= 1; m >>= 1) s += __shfl_xor(s, m);
  float mean = s * (1.f / 512.f);
  float q = 0.f;
  #pragma unroll
  for (int i = 0; i < 8; i++) { float d = va[i] - mean; q += d * d; }
  #pragma unroll
  for (int m = 32; m >= 1; m >>= 1) q += __shfl_xor(q, m);
  float rstd = rsqrtf(q * (1.f / 512.f) + 1e-5f);
  const float* gp = gam + lane * 8;
  const float* bp = bet + lane * 8;
  float4 g0 = *(const float4*)gp, g1 = *(const float4*)(gp + 4);
  float4 b0 = *(const float4*)bp, b1 = *(const float4*)(bp + 4);
  float ga[8] = {g0.x, g0.y, g0.z, g0.w, g1.x, g1.y, g1.z, g1.w};
  float ba[8] = {b0.x, b0.y, b0.z, b0.w, b1.x, b1.y, b1.z, b1.w};
  float o[8];
  #pragma unroll
  for (int i = 0; i < 8; i++) o[i] = (va[i] - mean) * rstd * ga[i] + ba[i];
  *(float4*)p       = make_float4(o[0], o[1], o[2], o[3]);
  *(float4*)(p + 4) = make_float4(o[4], o[5], o[6], o[7]);
}

// ---------------------------------------------------------------------------
// K6: post head 1x1 conv (512->1): one wave per (b,t,hw) output.
// ---------------------------------------------------------------------------
__global__ void k_post(const float* __restrict__ y, const float* __restrict__ pw,
                       const float* __restrict__ pb, float* __restrict__ outp)
{
  int m = blockIdx.x * 4 + (threadIdx.x >> 6);
  int lane = threadIdx.x & 63;
  int b = m / 12544;
  int rem = m - b * 12544;
  int t = rem / 196;
  int hw = rem - t * 196;
  const float* row = y + ((size_t)(b * NPIX + hw) * TT + t) * DD + lane * 8;
  float4 a0 = *(const float4*)row, a1 = *(const float4*)(row + 4);
  float4 w0 = *(const float4*)(pw + lane * 8), w1 = *(const float4*)(pw + lane * 8 + 4);
  float s = a0.x * w0.x + a0.y * w0.y + a0.z * w0.z + a0.w * w0.w
          + a1.x * w1.x + a1.y * w1.y + a1.z * w1.z + a1.w * w1.w;
  #pragma unroll
  for (int mm = 32; mm >= 1; mm >>= 1) s += __shfl_xor(s, mm);
  if (lane == 0) outp[m] = s + pb[0];
}

// ---------------------------------------------------------------------------
// K7: classifier Conv1d(512->512)+GELU(exact)+Conv1d(512->1), one block per (b,t).
// ---------------------------------------------------------------------------
__global__ __launch_bounds__(256) void k_cls(
    const float* __restrict__ xv, const float* __restrict__ w1,
    const float* __restrict__ b1, const float* __restrict__ w2,
    const float* __restrict__ b2, float* __restrict__ outp)
{
  const int m = blockIdx.x;                          // b*64+t
  const int tid = threadIdx.x;
  __shared__ float xr[512];
  __shared__ float red[256];
  xr[tid] = xv[(size_t)m * DD + tid];
  xr[tid + 256] = xv[(size_t)m * DD + tid + 256];
  __syncthreads();
  float part = 0.f;
  for (int o = tid; o < 512; o += 256) {
    const float* wr = w1 + (size_t)o * DD;
    float d = 0.f;
    for (int cc = 0; cc < DD; cc += 4) {
      float4 wv = *(const float4*)(wr + cc);
      d += wv.x * xr[cc] + wv.y * xr[cc + 1] + wv.z * xr[cc + 2] + wv.w * xr[cc + 3];
    }
    d += b1[o];
    float ge = 0.5f * d * (1.0f + erff(d * 0.70710678118654752f));
    part += ge * w2[o];
  }
  red[tid] = part;
  __syncthreads();
  for (int s = 128; s > 0; s >>= 1) {
    if (tid < s) red[tid] += red[tid + s];
    __syncthreads();
  }
  if (tid == 0) outp[m] = red[0] + b2[0];
}

// ---------------------------------------------------------------------------
extern "C" void kernel_launch(void* const* d_in, const int* in_sizes, int n_in,
                              void* d_out, int out_size, void* d_ws, size_t ws_size,
                              hipStream_t stream)
{
  const float* x_v    = (const float*)d_in[0];
  const float* fmap   = (const float*)d_in[1];
  const float* pre_w  = (const float*)d_in[2];
  const float* pre_b  = (const float*)d_in[3];
  const float* post_w = (const float*)d_in[4];
  const float* post_b = (const float*)d_in[5];
  const float* tm_W   = (const float*)d_in[6];
  const float* tm_a1  = (const float*)d_in[7];
  const float* tm_a2  = (const float*)d_in[8];
  const float* tm_lw  = (const float*)d_in[9];
  const float* tm_lb  = (const float*)d_in[10];
  const float* tm_g   = (const float*)d_in[11];
  const float* tm_b   = (const float*)d_in[12];
  const float* fm_W   = (const float*)d_in[13];
  const float* fm_a1  = (const float*)d_in[14];
  const float* fm_a2  = (const float*)d_in[15];
  const float* fm_lw  = (const float*)d_in[16];
  const float* fm_lb  = (const float*)d_in[17];
  const float* fm_g   = (const float*)d_in[18];
  const float* fm_b   = (const float*)d_in[19];
  const float* c_w1   = (const float*)d_in[20];
  const float* c_b1   = (const float*)d_in[21];
  const float* c_w2   = (const float*)d_in[22];
  const float* c_b2   = (const float*)d_in[23];
  float* out = (float*)d_out;

  // workspace carve-up
  float* wsf    = (float*)d_ws;
  float* ax     = wsf;                     // 25,690,112 f
  float* tmp    = ax + 25690112;           // 25,690,112 f
  float* xtm    = tmp + 25690112;          // 131,072 f
  float* tmptm  = xtm + 131072;            // 131,072 f
  short* WTb_fm = (short*)(tmptm + 131072);      // 262,144 bf16
  short* WTb_tm = WTb_fm + 262144;               // 262,144 bf16
  short* LWb_fm = WTb_tm + 262144;               // 262,144 bf16
  short* LWb_tm = LWb_fm + 262144;               // 262,144 bf16
  unsigned long long* sel_fm = (unsigned long long*)(LWb_tm + 262144); // 784
  unsigned long long* sel_tm = sel_fm + 784;                           // 4

  // 1) pre head conv -> graph-layout ax
  k_preconv<<<dim3(8, 256), 256, 0, stream>>>(fmap, pre_w, pre_b, ax);

  // 2) weight preps -> bf16 N-major [j][k]
  k_prepWb<<<1024, 256, 0, stream>>>(fm_W, WTb_fm);
  k_prepWb<<<1024, 256, 0, stream>>>(tm_W, WTb_tm);
  k_prepLWb<<<1024, 256, 0, stream>>>(fm_lw, LWb_fm);
  k_prepLWb<<<1024, 256, 0, stream>>>(tm_lw, LWb_tm);

  // 3) top-k selection bitmasks (fp64 ranking)
  k_topk<<<NG_FM, 64, 0, stream>>>(ax, sel_fm);
  k_topk<<<4, 64, 0, stream>>>(x_v, sel_tm);

  // 4) h = x @ Wcat  (MFMA bf16)
  k_gmfma<<<dim3(4, NG_FM), 256, 0, stream>>>(ax, WTb_fm, nullptr, nullptr, tmp);
  k_gmfma<<<dim3(4, 4), 256, 0, stream>>>(x_v, WTb_tm, nullptr, nullptr, tmptm);

  // 5) fused attention + elu + signed-sqrt + column-normalize (in-place on h)
  k_attn<<<dim3(NHEAD, NG_FM), 256, 0, stream>>>(tmp, fm_a1, fm_a2, sel_fm);
  k_attn<<<dim3(NHEAD, 4), 256, 0, stream>>>(tmptm, tm_a1, tm_a2, sel_tm);

  // 6) x = x + tmp @ lin_w.T + lin_b  (MFMA bf16, in-place on x buffers)
  hipMemcpyAsync(xtm, x_v, (size_t)131072 * 4, hipMemcpyDeviceToDevice, stream);
  k_gmfma<<<dim3(4, NG_FM), 256, 0, stream>>>(tmp, LWb_fm, fm_lb, ax, ax);
  k_gmfma<<<dim3(4, 4), 256, 0, stream>>>(tmptm, LWb_tm, tm_lb, xtm, xtm);

  // 7) layernorm in-place
  k_ln<<<NG_FM * TT, 64, 0, stream>>>(ax, fm_g, fm_b);
  k_ln<<<NIMG, 64, 0, stream>>>(xtm, tm_g, tm_b);

  // 8) post head -> ano_map (d_out offset 256), classifier -> logits
  k_post<<<12544, 256, 0, stream>>>(ax, post_w, post_b, out + 256);
  k_cls<<<NIMG, 256, 0, stream>>>(xtm, c_w1, c_b1, c_w2, c_b2, out);
}

// Round 6
// 1430.112 us; speedup vs baseline: 1.3852x; 1.1631x over previous
//
#include <hip/hip_runtime.h>
#include <cstdint>
#include <cstddef>

// Model dims
constexpr int TT   = 64;    // T
constexpr int DD   = 512;   // D
constexpr int NHEAD= 8;
constexpr int DHH  = 64;
constexpr int NPIX = 196;   // 14*14
constexpr int CIN  = 768;
constexpr int KSEL = 44;    // int(0.7*64)
constexpr int NG_FM= 784;   // B*N
constexpr int NIMG = 256;   // B*T
// distance_adj underflow band: exp(-|0.6*d^2+0.2|) in fp32.
// d=12 -> 2.4e-38 (normal). d=13 -> subnormal -> flushed (FTZ). d>=14 -> 0.
constexpr int DBAND = 12;

typedef __attribute__((ext_vector_type(8))) short bf16x8;
typedef __attribute__((ext_vector_type(4))) float f32x4;

__device__ __forceinline__ short bfr(float x) {
  union { float f; unsigned u; } v; v.f = x;
  unsigned r = (v.u + 0x7fffu + ((v.u >> 16) & 1u)) >> 16;   // RNE
  return (short)r;
}

// ---------------------------------------------------------------------------
// prep: split pre_w (f32 [o][k]) into bf16 hi/lo pair, same layout.
// ---------------------------------------------------------------------------
__global__ void k_prepPW(const float* __restrict__ pw, short* __restrict__ hi,
                         short* __restrict__ lo)
{
  int m = blockIdx.x * 256 + threadIdx.x;            // < 512*768
  float x = pw[m];
  short h = bfr(x);
  union { unsigned u; float f; } hf; hf.u = ((unsigned)(unsigned short)h) << 16;
  hi[m] = h;
  lo[m] = bfr(x - hf.f);
}

// ---------------------------------------------------------------------------
// K1: pre head 1x1 conv (768->512) + bias + ReLU via split-bf16 MFMA.
// C = Ah*Bh + Ah*Bl + Al*Bh  (error ~2^-16 rel: safe for downstream top-k).
// Block = (image n, 64-wide o-chunk mt); 4 waves split 13 hw-tiles, each wave
// covers all 4 o-tiles (B-fragments built once, shared across o-tiles).
// XCD swizzle: the 8 o-chunks of one image land back-to-back on one XCD.
// Output in graph layout ax[(b*196+hw)*64 + t][d], coalesced via skewed-LDS.
// ---------------------------------------------------------------------------
__global__ __launch_bounds__(256) void k_preconv_mfma(
    const float* __restrict__ fmap, const short* __restrict__ pwh,
    const short* __restrict__ pwl, const float* __restrict__ pb,
    float* __restrict__ ax)
{
  __shared__ float arena[7616];                      // 30.46 KB
  const int wg = blockIdx.x;
  const int mt = (wg >> 3) & 7;                      // o-chunk
  const int n  = (wg & 7) | ((wg >> 6) << 3);        // image; n%8 == XCD
  const int b  = n >> 6, t = n & 63;
  const int tid = threadIdx.x;
  const int w = tid >> 6, l = tid & 63;
  const int lr = l & 15, lg = l >> 4;
  const int o0 = mt * 64;
  const float* fmn = fmap + (size_t)n * CIN * NPIX;

  const int hwt0 = (w == 0) ? 0 : 1 + 3 * w;         // waves: 4,3,3,3 hw-tiles
  const int nq   = (w == 0) ? 4 : 3;

  f32x4 acc[4][4];                                   // [q][ot]
  #pragma unroll
  for (int q = 0; q < 4; q++)
    #pragma unroll
    for (int ot = 0; ot < 4; ot++) acc[q][ot] = (f32x4){0.f, 0.f, 0.f, 0.f};

  for (int ks = 0; ks < 24; ks++) {
    const int k0 = ks * 32;
    __syncthreads();
    // stage fm slab f32 [32 k][213-pad hw] (rows of 196, zero-pad to 208)
    #pragma unroll
    for (int it = 0; it < 7; it++) {
      int i = tid + it * 256;
      if (i < 1664) {
        int kk = i / 52, q4 = i - kk * 52;
        float4 v = make_float4(0.f, 0.f, 0.f, 0.f);
        if (q4 < 49) v = *(const float4*)&fmn[(size_t)(k0 + kk) * NPIX + q4 * 4];
        *(float4*)&arena[kk * 213 + q4 * 4] = v;
      }
    }
    __syncthreads();
    // A fragments (weights, bf16 hi/lo direct from L2)
    bf16x8 Ah[4], Al[4];
    #pragma unroll
    for (int ot = 0; ot < 4; ot++) {
      size_t arow = (size_t)(o0 + ot * 16 + lr) * CIN + k0 + lg * 8;
      Ah[ot] = *(const bf16x8*)&pwh[arow];
      Al[ot] = *(const bf16x8*)&pwl[arow];
    }
    #pragma unroll
    for (int q = 0; q < 4; q++) if (q < nq) {
      const int hwc = (hwt0 + q) * 16 + lr;
      float v[8];
      #pragma unroll
      for (int j = 0; j < 8; j++) v[j] = arena[(lg * 8 + j) * 213 + hwc];
      // truncation split: hi = top16(x), lo = top16(x - hi)
      union { unsigned u[4]; bf16x8 s; } bh, bl;
      #pragma unroll
      for (int p = 0; p < 4; p++) {
        unsigned u0 = __float_as_uint(v[2 * p]);
        unsigned u1 = __float_as_uint(v[2 * p + 1]);
        bh.u[p] = (u0 >> 16) | (u1 & 0xffff0000u);
        float l0 = v[2 * p]     - __uint_as_float(u0 & 0xffff0000u);
        float l1 = v[2 * p + 1] - __uint_as_float(u1 & 0xffff0000u);
        bl.u[p] = (__float_as_uint(l0) >> 16) | (__float_as_uint(l1) & 0xffff0000u);
      }
      #pragma unroll
      for (int ot = 0; ot < 4; ot++) {
        acc[q][ot] = __builtin_amdgcn_mfma_f32_16x16x32_bf16(Al[ot], bh.s, acc[q][ot], 0, 0, 0);
        acc[q][ot] = __builtin_amdgcn_mfma_f32_16x16x32_bf16(Ah[ot], bl.s, acc[q][ot], 0, 0, 0);
        acc[q][ot] = __builtin_amdgcn_mfma_f32_16x16x32_bf16(Ah[ot], bh.s, acc[q][ot], 0, 0, 0);
      }
    }
  }

  // epilogue: bias + relu, reorder via skewed LDS, coalesced 64-float rows
  float4 pbf[4];
  #pragma unroll
  for (int ot = 0; ot < 4; ot++)
    pbf[ot] = *(const float4*)&pb[o0 + ot * 16 + 4 * lg];

  #pragma unroll
  for (int pass = 0; pass < 2; pass++) {
    const int tbase = pass ? 7 : 0;
    const int tend  = pass ? 13 : 7;
    const int rbase = tbase * 16;
    const int rows  = (tend - tbase) * 16;
    __syncthreads();
    #pragma unroll
    for (int q = 0; q < 4; q++) if (q < nq) {
      int hwt = hwt0 + q;
      if (hwt >= tbase && hwt < tend) {
        int row_l = hwt * 16 + lr - rbase;
        #pragma unroll
        for (int ot = 0; ot < 4; ot++) {
          int col = (ot * 16 + 4 * lg + 4 * row_l) % 68;   // skew: conflict-free
          f32x4 a = acc[q][ot];
          float4 o4v;
          o4v.x = fmaxf(a[0] + pbf[ot].x, 0.f);
          o4v.y = fmaxf(a[1] + pbf[ot].y, 0.f);
          o4v.z = fmaxf(a[2] + pbf[ot].z, 0.f);
          o4v.w = fmaxf(a[3] + pbf[ot].w, 0.f);
          *(float4*)&arena[row_l * 68 + col] = o4v;
        }
      }
    }
    __syncthreads();
    for (int i = tid; i < rows * 16; i += 256) {
      int row_l = i >> 4, o4 = i & 15;
      int hw = rbase + row_l;
      if (hw < NPIX) {
        int col = (o4 * 4 + 4 * row_l) % 68;
        float4 v = *(const float4*)&arena[row_l * 68 + col];
        *(float4*)&ax[((size_t)(b * NPIX + hw) * TT + t) * DD + o0 + o4 * 4] = v;
      }
    }
  }
}

// ---------------------------------------------------------------------------
// Weight preps -> bf16, N-major [j][k] so MFMA B-fragments are contiguous-K.
// ---------------------------------------------------------------------------
__global__ void k_prepWb(const float* __restrict__ W, short* __restrict__ o)
{
  int m = blockIdx.x * 256 + threadIdx.x;            // j*512+k, < 262144
  int k = m & 511, j = m >> 9;
  o[m] = bfr(W[(size_t)(j >> 6) * (DD * DHH) + (size_t)k * DHH + (j & 63)]);
}

__global__ void k_prepLWb(const float* __restrict__ a, short* __restrict__ o)
{
  int m = blockIdx.x * 256 + threadIdx.x;            // lin_w is already [j][k]
  o[m] = bfr(a[m]);
}

// ---------------------------------------------------------------------------
// K2: per-graph top-k selection bitmask (fp64 squared-norm ranking).
// ---------------------------------------------------------------------------
__global__ void k_topk(const float* __restrict__ x, unsigned long long* __restrict__ sel)
{
  int g = blockIdx.x, lane = threadIdx.x;            // 64 threads
  const float* row = x + ((size_t)g * TT + lane) * DD;
  double s = 0.0;
  for (int dd = 0; dd < DD; dd += 4) {
    float4 v = *(const float4*)(row + dd);
    s += (double)v.x * (double)v.x + (double)v.y * (double)v.y
       + (double)v.z * (double)v.z + (double)v.w * (double)v.w;
  }
  __shared__ double mag[64];
  mag[lane] = s;
  __syncthreads();
  int rank = 0;
  for (int j = 0; j < 64; j++) {
    double m = mag[j];
    rank += (m > s) || (m == s && j < lane);
  }
  unsigned long long bal = __ballot(rank < KSEL);
  if (lane == 0) sel[g] = bal;
}

// ---------------------------------------------------------------------------
// K3a/K4: per-graph MFMA GEMM  Out[g](64x512) = A[g](64x512,f32) @ Bb^T,
// Bb bf16 N-major [j][k]; optional +bias +Res; Out may alias Res.
// ---------------------------------------------------------------------------
__global__ __launch_bounds__(256) void k_gmfma(
    const float* __restrict__ A, const short* __restrict__ Bb,
    const float* __restrict__ bias, const float* __restrict__ Res,
    float* __restrict__ Out)
{
  const int jb = blockIdx.x, g = blockIdx.y;
  const int tid = threadIdx.x;
  const int w = tid >> 6, l = tid & 63;
  const int lr = l & 15, lg = l >> 4;
  const float* Ar = A + (size_t)g * TT * DD + (size_t)(w * 16 + lr) * DD;

  f32x4 acc[8] = {};

  for (int ks = 0; ks < 16; ks++) {
    const int kb = ks * 32 + lg * 8;
    float4 a0 = *(const float4*)(Ar + kb);
    float4 a1 = *(const float4*)(Ar + kb + 4);
    bf16x8 af;
    af[0] = bfr(a0.x); af[1] = bfr(a0.y); af[2] = bfr(a0.z); af[3] = bfr(a0.w);
    af[4] = bfr(a1.x); af[5] = bfr(a1.y); af[6] = bfr(a1.z); af[7] = bfr(a1.w);
    #pragma unroll
    for (int ct = 0; ct < 8; ct++) {
      const int j = jb * 128 + ct * 16 + lr;
      bf16x8 bb = *(const bf16x8*)&Bb[(size_t)j * DD + kb];
      acc[ct] = __builtin_amdgcn_mfma_f32_16x16x32_bf16(af, bb, acc[ct], 0, 0, 0);
    }
  }

  float* Og = Out + (size_t)g * TT * DD;
  const float* Rg = Res ? (Res + (size_t)g * TT * DD) : nullptr;
  #pragma unroll
  for (int ct = 0; ct < 8; ct++) {
    const int j = jb * 128 + ct * 16 + lr;
    const float bv = bias ? bias[j] : 0.f;
    #pragma unroll
    for (int r = 0; r < 4; r++) {
      const int row = w * 16 + lg * 4 + r;
      float v = acc[ct][r] + bv;
      if (Rg) v += Rg[(size_t)row * DD + j];
      Og[(size_t)row * DD + j] = v;
    }
  }
}

// ---------------------------------------------------------------------------
// K3b: fused GAT attention per (head, graph).
// ---------------------------------------------------------------------------
__global__ __launch_bounds__(256) void k_attn(
    float* __restrict__ tmp, const float* __restrict__ a1v,
    const float* __restrict__ a2v, const unsigned long long* __restrict__ sel)
{
  __shared__ float hs[64][68];
  __shared__ float attnv[64][68];
  __shared__ float s1[64], s2[64], aw[128], cnorm[64];
  const int h = blockIdx.x, g = blockIdx.y;
  const int tid = threadIdx.x;
  const int r = tid >> 4, c = tid & 15;
  float* base = tmp + (size_t)g * TT * DD + h * DHH;

  for (int i = tid; i < 4096; i += 256) {
    int t = i >> 6, dh = i & 63;
    hs[t][dh] = base[(size_t)t * DD + dh];
  }
  if (tid < 128) aw[tid] = (tid < 64) ? a1v[h * 64 + tid] : a2v[h * 64 + (tid - 64)];
  __syncthreads();

  if (tid < 64) {
    float v1 = 0.f, v2 = 0.f;
    for (int dh = 0; dh < 64; dh++) { float hv = hs[tid][dh]; v1 += hv * aw[dh]; v2 += hv * aw[64 + dh]; }
    s1[tid] = v1; s2[tid] = v2;
  }
  __syncthreads();

  const unsigned long long sm = sel[g];
  if (tid < 64) {
    const int i = tid;
    const bool seli = (sm >> i) & 1ULL;
    const float vi = s1[i];
    float mx = -1e30f;
    for (int j = 0; j < 64; j++) {
      float e = vi + s2[j];
      e = e >= 0.f ? e : 0.2f * e;                   // leaky_relu(0.2)
      int dist = i > j ? i - j : j - i;
      bool ok = (seli || ((sm >> j) & 1ULL)) && (dist <= DBAND);
      e = ok ? e : -9e15f;
      attnv[i][j] = e;
      mx = fmaxf(mx, e);
    }
    float sum = 0.f;
    for (int j = 0; j < 64; j++) { float p = expf(attnv[i][j] - mx); attnv[i][j] = p; sum += p; }
    float inv = 1.f / sum;
    for (int j = 0; j < 64; j++) attnv[i][j] *= inv;
  }
  __syncthreads();

  float oc[4][4];
  #pragma unroll
  for (int i = 0; i < 4; i++)
    #pragma unroll
    for (int j = 0; j < 4; j++) oc[i][j] = 0.f;
  for (int j = 0; j < 64; j++) {
    float p[4];
    #pragma unroll
    for (int di = 0; di < 4; di++) p[di] = attnv[r * 4 + di][j];
    float4 hv = *(const float4*)&hs[j][c * 4];
    float hb[4] = {hv.x, hv.y, hv.z, hv.w};
    #pragma unroll
    for (int di = 0; di < 4; di++)
      #pragma unroll
      for (int dj = 0; dj < 4; dj++)
        oc[di][dj] += p[di] * hb[dj];
  }

  float cs4[4] = {0.f, 0.f, 0.f, 0.f};
  #pragma unroll
  for (int di = 0; di < 4; di++)
    #pragma unroll
    for (int dj = 0; dj < 4; dj++) {
      float v = oc[di][dj];
      v = v > 0.f ? v : expm1f(v);
      v = v >= 0.f ? sqrtf(v) : -sqrtf(-v);
      oc[di][dj] = v;
      cs4[dj] += v * v;
    }
  __syncthreads();
  *(float4*)&attnv[r][c * 4] = make_float4(cs4[0], cs4[1], cs4[2], cs4[3]);
  __syncthreads();
  if (tid < 64) {
    float ssum = 0.f;
    for (int rr = 0; rr < 16; rr++) ssum += attnv[rr][tid];
    cnorm[tid] = fmaxf(sqrtf(ssum), 1e-12f);
  }
  __syncthreads();
  float4 cn = *(const float4*)&cnorm[c * 4];
  float inv4[4] = {1.f / cn.x, 1.f / cn.y, 1.f / cn.z, 1.f / cn.w};
  #pragma unroll
  for (int di = 0; di < 4; di++) {
    float4 o4 = make_float4(oc[di][0] * inv4[0], oc[di][1] * inv4[1],
                            oc[di][2] * inv4[2], oc[di][3] * inv4[3]);
    *(float4*)&base[(size_t)(r * 4 + di) * DD + c * 4] = o4;
  }
}

// ---------------------------------------------------------------------------
// K5: LayerNorm in-place, one wave per 512-row.
// ---------------------------------------------------------------------------
__global__ void k_ln(float* __restrict__ x, const float* __restrict__ gam, const float* __restrict__ bet)
{
  const size_t row = blockIdx.x;
  const int lane = threadIdx.x;
  float* p = x + row * DD + lane * 8;
  float4 v0 = *(float4*)p;
  float4 v1 = *(float4*)(p + 4);
  float va[8] = {v0.x, v0.y, v0.z, v0.w, v1.x, v1.y, v1.z, v1.w};
  float s = 0.f;
  #pragma unroll
  for (int i = 0; i < 8; i++) s += va[i];
  #pragma unroll
  for (int m = 32; m >= 1; m >>= 1) s += __shfl_xor(s, m);
  float mean = s * (1.f / 512.f);
  float q = 0.f;
  #pragma unroll
  for (int i = 0; i < 8; i++) { float d = va[i] - mean; q += d * d; }
  #pragma unroll
  for (int m = 32; m >= 1; m >>= 1) q += __shfl_xor(q, m);
  float rstd = rsqrtf(q * (1.f / 512.f) + 1e-5f);
  const float* gp = gam + lane * 8;
  const float* bp = bet + lane * 8;
  float4 g0 = *(const float4*)gp, g1 = *(const float4*)(gp + 4);
  float4 b0 = *(const float4*)bp, b1 = *(const float4*)(bp + 4);
  float ga[8] = {g0.x, g0.y, g0.z, g0.w, g1.x, g1.y, g1.z, g1.w};
  float ba[8] = {b0.x, b0.y, b0.z, b0.w, b1.x, b1.y, b1.z, b1.w};
  float o[8];
  #pragma unroll
  for (int i = 0; i < 8; i++) o[i] = (va[i] - mean) * rstd * ga[i] + ba[i];
  *(float4*)p       = make_float4(o[0], o[1], o[2], o[3]);
  *(float4*)(p + 4) = make_float4(o[4], o[5], o[6], o[7]);
}

// ---------------------------------------------------------------------------
// K6: post head 1x1 conv (512->1): one wave per (b,t,hw) output.
// ---------------------------------------------------------------------------
__global__ void k_post(const float* __restrict__ y, const float* __restrict__ pw,
                       const float* __restrict__ pb, float* __restrict__ outp)
{
  int m = blockIdx.x * 4 + (threadIdx.x >> 6);
  int lane = threadIdx.x & 63;
  int b = m / 12544;
  int rem = m - b * 12544;
  int t = rem / 196;
  int hw = rem - t * 196;
  const float* row = y + ((size_t)(b * NPIX + hw) * TT + t) * DD + lane * 8;
  float4 a0 = *(const float4*)row, a1 = *(const float4*)(row + 4);
  float4 w0 = *(const float4*)(pw + lane * 8), w1 = *(const float4*)(pw + lane * 8 + 4);
  float s = a0.x * w0.x + a0.y * w0.y + a0.z * w0.z + a0.w * w0.w
          + a1.x * w1.x + a1.y * w1.y + a1.z * w1.z + a1.w * w1.w;
  #pragma unroll
  for (int mm = 32; mm >= 1; mm >>= 1) s += __shfl_xor(s, mm);
  if (lane == 0) outp[m] = s + pb[0];
}

// ---------------------------------------------------------------------------
// K7: classifier Conv1d(512->512)+GELU(exact)+Conv1d(512->1), one block per (b,t).
// ---------------------------------------------------------------------------
__global__ __launch_bounds__(256) void k_cls(
    const float* __restrict__ xv, const float* __restrict__ w1,
    const float* __restrict__ b1, const float* __restrict__ w2,
    const float* __restrict__ b2, float* __restrict__ outp)
{
  const int m = blockIdx.x;                          // b*64+t
  const int tid = threadIdx.x;
  __shared__ float xr[512];
  __shared__ float red[256];
  xr[tid] = xv[(size_t)m * DD + tid];
  xr[tid + 256] = xv[(size_t)m * DD + tid + 256];
  __syncthreads();
  float part = 0.f;
  for (int o = tid; o < 512; o += 256) {
    const float* wr = w1 + (size_t)o * DD;
    float d = 0.f;
    for (int cc = 0; cc < DD; cc += 4) {
      float4 wv = *(const float4*)(wr + cc);
      d += wv.x * xr[cc] + wv.y * xr[cc + 1] + wv.z * xr[cc + 2] + wv.w * xr[cc + 3];
    }
    d += b1[o];
    float ge = 0.5f * d * (1.0f + erff(d * 0.70710678118654752f));
    part += ge * w2[o];
  }
  red[tid] = part;
  __syncthreads();
  for (int s = 128; s > 0; s >>= 1) {
    if (tid < s) red[tid] += red[tid + s];
    __syncthreads();
  }
  if (tid == 0) outp[m] = red[0] + b2[0];
}

// ---------------------------------------------------------------------------
extern "C" void kernel_launch(void* const* d_in, const int* in_sizes, int n_in,
                              void* d_out, int out_size, void* d_ws, size_t ws_size,
                              hipStream_t stream)
{
  const float* x_v    = (const float*)d_in[0];
  const float* fmap   = (const float*)d_in[1];
  const float* pre_w  = (const float*)d_in[2];
  const float* pre_b  = (const float*)d_in[3];
  const float* post_w = (const float*)d_in[4];
  const float* post_b = (const float*)d_in[5];
  const float* tm_W   = (const float*)d_in[6];
  const float* tm_a1  = (const float*)d_in[7];
  const float* tm_a2  = (const float*)d_in[8];
  const float* tm_lw  = (const float*)d_in[9];
  const float* tm_lb  = (const float*)d_in[10];
  const float* tm_g   = (const float*)d_in[11];
  const float* tm_b   = (const float*)d_in[12];
  const float* fm_W   = (const float*)d_in[13];
  const float* fm_a1  = (const float*)d_in[14];
  const float* fm_a2  = (const float*)d_in[15];
  const float* fm_lw  = (const float*)d_in[16];
  const float* fm_lb  = (const float*)d_in[17];
  const float* fm_g   = (const float*)d_in[18];
  const float* fm_b   = (const float*)d_in[19];
  const float* c_w1   = (const float*)d_in[20];
  const float* c_b1   = (const float*)d_in[21];
  const float* c_w2   = (const float*)d_in[22];
  const float* c_b2   = (const float*)d_in[23];
  float* out = (float*)d_out;

  // workspace carve-up
  float* wsf    = (float*)d_ws;
  float* ax     = wsf;                     // 25,690,112 f
  float* tmp    = ax + 25690112;           // 25,690,112 f
  float* xtm    = tmp + 25690112;          // 131,072 f
  float* tmptm  = xtm + 131072;            // 131,072 f
  short* WTb_fm = (short*)(tmptm + 131072);      // 262,144 bf16
  short* WTb_tm = WTb_fm + 262144;               // 262,144 bf16
  short* LWb_fm = WTb_tm + 262144;               // 262,144 bf16
  short* LWb_tm = LWb_fm + 262144;               // 262,144 bf16
  unsigned long long* sel_fm = (unsigned long long*)(LWb_tm + 262144); // 784
  unsigned long long* sel_tm = sel_fm + 784;                           // 4
  short* pwb_hi = (short*)(sel_tm + 4);          // 393,216 bf16
  short* pwb_lo = pwb_hi + 393216;               // 393,216 bf16

  // 1) weight preps
  k_prepPW<<<1536, 256, 0, stream>>>(pre_w, pwb_hi, pwb_lo);
  k_prepWb<<<1024, 256, 0, stream>>>(fm_W, WTb_fm);
  k_prepWb<<<1024, 256, 0, stream>>>(tm_W, WTb_tm);
  k_prepLWb<<<1024, 256, 0, stream>>>(fm_lw, LWb_fm);
  k_prepLWb<<<1024, 256, 0, stream>>>(tm_lw, LWb_tm);

  // 2) pre head conv -> graph-layout ax (split-bf16 MFMA)
  k_preconv_mfma<<<2048, 256, 0, stream>>>(fmap, pwb_hi, pwb_lo, pre_b, ax);

  // 3) top-k selection bitmasks (fp64 ranking)
  k_topk<<<NG_FM, 64, 0, stream>>>(ax, sel_fm);
  k_topk<<<4, 64, 0, stream>>>(x_v, sel_tm);

  // 4) h = x @ Wcat  (MFMA bf16)
  k_gmfma<<<dim3(4, NG_FM), 256, 0, stream>>>(ax, WTb_fm, nullptr, nullptr, tmp);
  k_gmfma<<<dim3(4, 4), 256, 0, stream>>>(x_v, WTb_tm, nullptr, nullptr, tmptm);

  // 5) fused attention + elu + signed-sqrt + column-normalize (in-place on h)
  k_attn<<<dim3(NHEAD, NG_FM), 256, 0, stream>>>(tmp, fm_a1, fm_a2, sel_fm);
  k_attn<<<dim3(NHEAD, 4), 256, 0, stream>>>(tmptm, tm_a1, tm_a2, sel_tm);

  // 6) x = x + tmp @ lin_w.T + lin_b  (MFMA bf16, in-place on x buffers)
  hipMemcpyAsync(xtm, x_v, (size_t)131072 * 4, hipMemcpyDeviceToDevice, stream);
  k_gmfma<<<dim3(4, NG_FM), 256, 0, stream>>>(tmp, LWb_fm, fm_lb, ax, ax);
  k_gmfma<<<dim3(4, 4), 256, 0, stream>>>(tmptm, LWb_tm, tm_lb, xtm, xtm);

  // 7) layernorm in-place
  k_ln<<<NG_FM * TT, 64, 0, stream>>>(ax, fm_g, fm_b);
  k_ln<<<NIMG, 64, 0, stream>>>(xtm, tm_g, tm_b);

  // 8) post head -> ano_map (d_out offset 256), classifier -> logits
  k_post<<<12544, 256, 0, stream>>>(ax, post_w, post_b, out + 256);
  k_cls<<<NIMG, 256, 0, stream>>>(xtm, c_w1, c_b1, c_w2, c_b2, out);
}

// Round 7
// 1348.140 us; speedup vs baseline: 1.4694x; 1.0608x over previous
//
#include <hip/hip_runtime.h>
#include <cstdint>
#include <cstddef>

// Model dims
constexpr int TT   = 64;    // T
constexpr int DD   = 512;   // D
constexpr int NHEAD= 8;
constexpr int DHH  = 64;
constexpr int NPIX = 196;   // 14*14
constexpr int CIN  = 768;
constexpr int KSEL = 44;    // int(0.7*64)
constexpr int NG_FM= 784;   // B*N
constexpr int NIMG = 256;   // B*T
// distance_adj underflow band: exp(-|0.6*d^2+0.2|) in fp32.
// d=12 -> 2.4e-38 (normal). d=13 -> subnormal -> flushed (FTZ). d>=14 -> 0.
constexpr int DBAND = 12;

typedef __attribute__((ext_vector_type(8))) short bf16x8;
typedef __attribute__((ext_vector_type(4))) float f32x4;

__device__ __forceinline__ short bfr(float x) {
  union { float f; unsigned u; } v; v.f = x;
  unsigned r = (v.u + 0x7fffu + ((v.u >> 16) & 1u)) >> 16;   // RNE
  return (short)r;
}

// ---------------------------------------------------------------------------
// prep: split pre_w (f32 [o][k]) into bf16 hi/lo pair, same layout.
// ---------------------------------------------------------------------------
__global__ void k_prepPW(const float* __restrict__ pw, short* __restrict__ hi,
                         short* __restrict__ lo)
{
  int m = blockIdx.x * 256 + threadIdx.x;            // < 512*768
  float x = pw[m];
  short h = bfr(x);
  union { unsigned u; float f; } hf; hf.u = ((unsigned)(unsigned short)h) << 16;
  hi[m] = h;
  lo[m] = bfr(x - hf.f);
}

// ---------------------------------------------------------------------------
// prep: transpose fmap [n][c][hw] f32 -> [n][hw][c] bf16 hi/lo (half-batch).
// Moves the split VALU + transpose out of the conv hot loop; BW-bound.
// ---------------------------------------------------------------------------
__global__ __launch_bounds__(256) void k_prepFM(
    const float* __restrict__ fmap, short* __restrict__ fh,
    short* __restrict__ fl, int n0)
{
  __shared__ float ar[64][197];                      // pitch 197: 2-way max
  const int cc = blockIdx.x;                         // 12 chunks of 64 ch
  const int nl = blockIdx.y;                         // 0..127
  const int tid = threadIdx.x;
  const float* src = fmap + ((size_t)(n0 + nl) * CIN + cc * 64) * NPIX;
  for (int i = tid; i < 64 * 49; i += 256) {         // 196 = 49 float4, aligned
    int c = i / 49, q = i - c * 49;
    float4 v = *(const float4*)&src[(size_t)c * NPIX + q * 4];
    *(float4*)&ar[c][q * 4] = v;
  }
  __syncthreads();
  for (int i = tid; i < NPIX * 16; i += 256) {
    int hw = i >> 4, cg = i & 15;
    short h4[4], l4[4];
    #pragma unroll
    for (int j = 0; j < 4; j++) {
      float x = ar[cg * 4 + j][hw];
      unsigned u = __float_as_uint(x);
      h4[j] = (short)(u >> 16);                      // truncation hi
      float r = x - __uint_as_float(u & 0xffff0000u);
      l4[j] = bfr(r);                                // RNE lo
    }
    size_t dst = ((size_t)nl * NPIX + hw) * CIN + cc * 64 + cg * 4;
    *(short4*)&fh[dst] = make_short4(h4[0], h4[1], h4[2], h4[3]);
    *(short4*)&fl[dst] = make_short4(l4[0], l4[1], l4[2], l4[3]);
  }
}

// ---------------------------------------------------------------------------
// K1: pre head 1x1 conv (768->512) + bias + ReLU via split-bf16 MFMA.
// C = Al*Bh + Ah*Bl + Ah*Bh  (error ~2^-16 rel: safe for downstream top-k).
// Pure-MFMA main loop: A (weights) and B (transposed fmap) fragments are
// direct contiguous-K 16B global loads; no LDS, no barriers until epilogue.
// Block = (image nl, 64-o chunk); 4 waves split 13 hw-tiles (4,3,3,3).
// XCD swizzle: an image's 8 o-chunk blocks share one XCD -> B L2-local.
// Output in graph layout ax[(b*196+hw)*64 + t][d] via skewed-LDS epilogue.
// ---------------------------------------------------------------------------
__global__ __launch_bounds__(256) void k_preconv2(
    const short* __restrict__ fh, const short* __restrict__ fl,
    const short* __restrict__ pwh, const short* __restrict__ pwl,
    const float* __restrict__ pb, float* __restrict__ ax, int n0)
{
  __shared__ float arena[7616];                      // epilogue only
  const int wg = blockIdx.x;                         // 1024
  const int mt = (wg >> 3) & 7;                      // o-chunk
  const int nl = (wg & 7) | ((wg >> 6) << 3);        // local image (XCD-group)
  const int n  = n0 + nl;
  const int b  = n >> 6, t = n & 63;
  const int tid = threadIdx.x;
  const int w = tid >> 6, l = tid & 63;
  const int lr = l & 15, lg = l >> 4;
  const int o0 = mt * 64;

  const int hwt0 = (w == 0) ? 0 : 1 + 3 * w;         // waves: 4,3,3,3 hw-tiles
  const int nq   = (w == 0) ? 4 : 3;

  const short* fhb = fh + (size_t)nl * (NPIX * CIN);
  const short* flb = fl + (size_t)nl * (NPIX * CIN);

  f32x4 acc[4][4];                                   // [q][ot]
  #pragma unroll
  for (int q = 0; q < 4; q++)
    #pragma unroll
    for (int ot = 0; ot < 4; ot++) acc[q][ot] = (f32x4){0.f, 0.f, 0.f, 0.f};

  for (int ks = 0; ks < 24; ks++) {
    const int kb = ks * 32 + lg * 8;
    bf16x8 Ah[4], Al[4];
    #pragma unroll
    for (int ot = 0; ot < 4; ot++) {
      size_t arow = (size_t)(o0 + ot * 16 + lr) * CIN + kb;
      Ah[ot] = *(const bf16x8*)&pwh[arow];
      Al[ot] = *(const bf16x8*)&pwl[arow];
    }
    #pragma unroll
    for (int q = 0; q < 4; q++) if (q < nq) {
      const int hw = (hwt0 + q) * 16 + lr;           // may reach 207: pad'd buf
      size_t brow = (size_t)hw * CIN + kb;
      bf16x8 Bh = *(const bf16x8*)&fhb[brow];
      bf16x8 Bl = *(const bf16x8*)&flb[brow];
      #pragma unroll
      for (int ot = 0; ot < 4; ot++) {
        acc[q][ot] = __builtin_amdgcn_mfma_f32_16x16x32_bf16(Al[ot], Bh, acc[q][ot], 0, 0, 0);
        acc[q][ot] = __builtin_amdgcn_mfma_f32_16x16x32_bf16(Ah[ot], Bl, acc[q][ot], 0, 0, 0);
        acc[q][ot] = __builtin_amdgcn_mfma_f32_16x16x32_bf16(Ah[ot], Bh, acc[q][ot], 0, 0, 0);
      }
    }
  }

  // epilogue: bias + relu, reorder via skewed LDS, coalesced 64-float rows
  float4 pbf[4];
  #pragma unroll
  for (int ot = 0; ot < 4; ot++)
    pbf[ot] = *(const float4*)&pb[o0 + ot * 16 + 4 * lg];

  #pragma unroll
  for (int pass = 0; pass < 2; pass++) {
    const int tbase = pass ? 7 : 0;
    const int tend  = pass ? 13 : 7;
    const int rbase = tbase * 16;
    const int rows  = (tend - tbase) * 16;
    __syncthreads();
    #pragma unroll
    for (int q = 0; q < 4; q++) if (q < nq) {
      int hwt = hwt0 + q;
      if (hwt >= tbase && hwt < tend) {
        int row_l = hwt * 16 + lr - rbase;
        #pragma unroll
        for (int ot = 0; ot < 4; ot++) {
          int col = (ot * 16 + 4 * lg + 4 * row_l) % 68;   // skew: conflict-free
          f32x4 a = acc[q][ot];
          float4 o4v;
          o4v.x = fmaxf(a[0] + pbf[ot].x, 0.f);
          o4v.y = fmaxf(a[1] + pbf[ot].y, 0.f);
          o4v.z = fmaxf(a[2] + pbf[ot].z, 0.f);
          o4v.w = fmaxf(a[3] + pbf[ot].w, 0.f);
          *(float4*)&arena[row_l * 68 + col] = o4v;
        }
      }
    }
    __syncthreads();
    for (int i = tid; i < rows * 16; i += 256) {
      int row_l = i >> 4, o4 = i & 15;
      int hw = rbase + row_l;
      if (hw < NPIX) {
        int col = (o4 * 4 + 4 * row_l) % 68;
        float4 v = *(const float4*)&arena[row_l * 68 + col];
        *(float4*)&ax[((size_t)(b * NPIX + hw) * TT + t) * DD + o0 + o4 * 4] = v;
      }
    }
  }
}

// ---------------------------------------------------------------------------
// Weight preps -> bf16, N-major [j][k] so MFMA B-fragments are contiguous-K.
// ---------------------------------------------------------------------------
__global__ void k_prepWb(const float* __restrict__ W, short* __restrict__ o)
{
  int m = blockIdx.x * 256 + threadIdx.x;            // j*512+k, < 262144
  int k = m & 511, j = m >> 9;
  o[m] = bfr(W[(size_t)(j >> 6) * (DD * DHH) + (size_t)k * DHH + (j & 63)]);
}

__global__ void k_prepLWb(const float* __restrict__ a, short* __restrict__ o)
{
  int m = blockIdx.x * 256 + threadIdx.x;            // lin_w is already [j][k]
  o[m] = bfr(a[m]);
}

// ---------------------------------------------------------------------------
// K2: per-graph top-k selection bitmask (fp64 squared-norm ranking).
// ---------------------------------------------------------------------------
__global__ void k_topk(const float* __restrict__ x, unsigned long long* __restrict__ sel)
{
  int g = blockIdx.x, lane = threadIdx.x;            // 64 threads
  const float* row = x + ((size_t)g * TT + lane) * DD;
  double s = 0.0;
  for (int dd = 0; dd < DD; dd += 4) {
    float4 v = *(const float4*)(row + dd);
    s += (double)v.x * (double)v.x + (double)v.y * (double)v.y
       + (double)v.z * (double)v.z + (double)v.w * (double)v.w;
  }
  __shared__ double mag[64];
  mag[lane] = s;
  __syncthreads();
  int rank = 0;
  for (int j = 0; j < 64; j++) {
    double m = mag[j];
    rank += (m > s) || (m == s && j < lane);
  }
  unsigned long long bal = __ballot(rank < KSEL);
  if (lane == 0) sel[g] = bal;
}

// ---------------------------------------------------------------------------
// K3a/K4: per-graph MFMA GEMM  Out[g](64x512) = A[g](64x512,f32) @ Bb^T,
// Bb bf16 N-major [j][k]; optional +bias +Res; Out may alias Res.
// ---------------------------------------------------------------------------
__global__ __launch_bounds__(256) void k_gmfma(
    const float* __restrict__ A, const short* __restrict__ Bb,
    const float* __restrict__ bias, const float* __restrict__ Res,
    float* __restrict__ Out)
{
  const int jb = blockIdx.x, g = blockIdx.y;
  const int tid = threadIdx.x;
  const int w = tid >> 6, l = tid & 63;
  const int lr = l & 15, lg = l >> 4;
  const float* Ar = A + (size_t)g * TT * DD + (size_t)(w * 16 + lr) * DD;

  f32x4 acc[8] = {};

  for (int ks = 0; ks < 16; ks++) {
    const int kb = ks * 32 + lg * 8;
    float4 a0 = *(const float4*)(Ar + kb);
    float4 a1 = *(const float4*)(Ar + kb + 4);
    bf16x8 af;
    af[0] = bfr(a0.x); af[1] = bfr(a0.y); af[2] = bfr(a0.z); af[3] = bfr(a0.w);
    af[4] = bfr(a1.x); af[5] = bfr(a1.y); af[6] = bfr(a1.z); af[7] = bfr(a1.w);
    #pragma unroll
    for (int ct = 0; ct < 8; ct++) {
      const int j = jb * 128 + ct * 16 + lr;
      bf16x8 bb = *(const bf16x8*)&Bb[(size_t)j * DD + kb];
      acc[ct] = __builtin_amdgcn_mfma_f32_16x16x32_bf16(af, bb, acc[ct], 0, 0, 0);
    }
  }

  float* Og = Out + (size_t)g * TT * DD;
  const float* Rg = Res ? (Res + (size_t)g * TT * DD) : nullptr;
  #pragma unroll
  for (int ct = 0; ct < 8; ct++) {
    const int j = jb * 128 + ct * 16 + lr;
    const float bv = bias ? bias[j] : 0.f;
    #pragma unroll
    for (int r = 0; r < 4; r++) {
      const int row = w * 16 + lg * 4 + r;
      float v = acc[ct][r] + bv;
      if (Rg) v += Rg[(size_t)row * DD + j];
      Og[(size_t)row * DD + j] = v;
    }
  }
}

// ---------------------------------------------------------------------------
// K3b: fused GAT attention per (head, graph).
// ---------------------------------------------------------------------------
__global__ __launch_bounds__(256) void k_attn(
    float* __restrict__ tmp, const float* __restrict__ a1v,
    const float* __restrict__ a2v, const unsigned long long* __restrict__ sel)
{
  __shared__ float hs[64][68];
  __shared__ float attnv[64][68];
  __shared__ float s1[64], s2[64], aw[128], cnorm[64];
  const int h = blockIdx.x, g = blockIdx.y;
  const int tid = threadIdx.x;
  const int r = tid >> 4, c = tid & 15;
  float* base = tmp + (size_t)g * TT * DD + h * DHH;

  for (int i = tid; i < 4096; i += 256) {
    int t = i >> 6, dh = i & 63;
    hs[t][dh] = base[(size_t)t * DD + dh];
  }
  if (tid < 128) aw[tid] = (tid < 64) ? a1v[h * 64 + tid] : a2v[h * 64 + (tid - 64)];
  __syncthreads();

  if (tid < 64) {
    float v1 = 0.f, v2 = 0.f;
    for (int dh = 0; dh < 64; dh++) { float hv = hs[tid][dh]; v1 += hv * aw[dh]; v2 += hv * aw[64 + dh]; }
    s1[tid] = v1; s2[tid] = v2;
  }
  __syncthreads();

  const unsigned long long sm = sel[g];
  if (tid < 64) {
    const int i = tid;
    const bool seli = (sm >> i) & 1ULL;
    const float vi = s1[i];
    float mx = -1e30f;
    for (int j = 0; j < 64; j++) {
      float e = vi + s2[j];
      e = e >= 0.f ? e : 0.2f * e;                   // leaky_relu(0.2)
      int dist = i > j ? i - j : j - i;
      bool ok = (seli || ((sm >> j) & 1ULL)) && (dist <= DBAND);
      e = ok ? e : -9e15f;
      attnv[i][j] = e;
      mx = fmaxf(mx, e);
    }
    float sum = 0.f;
    for (int j = 0; j < 64; j++) { float p = expf(attnv[i][j] - mx); attnv[i][j] = p; sum += p; }
    float inv = 1.f / sum;
    for (int j = 0; j < 64; j++) attnv[i][j] *= inv;
  }
  __syncthreads();

  float oc[4][4];
  #pragma unroll
  for (int i = 0; i < 4; i++)
    #pragma unroll
    for (int j = 0; j < 4; j++) oc[i][j] = 0.f;
  for (int j = 0; j < 64; j++) {
    float p[4];
    #pragma unroll
    for (int di = 0; di < 4; di++) p[di] = attnv[r * 4 + di][j];
    float4 hv = *(const float4*)&hs[j][c * 4];
    float hb[4] = {hv.x, hv.y, hv.z, hv.w};
    #pragma unroll
    for (int di = 0; di < 4; di++)
      #pragma unroll
      for (int dj = 0; dj < 4; dj++)
        oc[di][dj] += p[di] * hb[dj];
  }

  float cs4[4] = {0.f, 0.f, 0.f, 0.f};
  #pragma unroll
  for (int di = 0; di < 4; di++)
    #pragma unroll
    for (int dj = 0; dj < 4; dj++) {
      float v = oc[di][dj];
      v = v > 0.f ? v : expm1f(v);
      v = v >= 0.f ? sqrtf(v) : -sqrtf(-v);
      oc[di][dj] = v;
      cs4[dj] += v * v;
    }
  __syncthreads();
  *(float4*)&attnv[r][c * 4] = make_float4(cs4[0], cs4[1], cs4[2], cs4[3]);
  __syncthreads();
  if (tid < 64) {
    float ssum = 0.f;
    for (int rr = 0; rr < 16; rr++) ssum += attnv[rr][tid];
    cnorm[tid] = fmaxf(sqrtf(ssum), 1e-12f);
  }
  __syncthreads();
  float4 cn = *(const float4*)&cnorm[c * 4];
  float inv4[4] = {1.f / cn.x, 1.f / cn.y, 1.f / cn.z, 1.f / cn.w};
  #pragma unroll
  for (int di = 0; di < 4; di++) {
    float4 o4 = make_float4(oc[di][0] * inv4[0], oc[di][1] * inv4[1],
                            oc[di][2] * inv4[2], oc[di][3] * inv4[3]);
    *(float4*)&base[(size_t)(r * 4 + di) * DD + c * 4] = o4;
  }
}

// ---------------------------------------------------------------------------
// K5: LayerNorm in-place, one wave per 512-row.
// ---------------------------------------------------------------------------
__global__ void k_ln(float* __restrict__ x, const float* __restrict__ gam, const float* __restrict__ bet)
{
  const size_t row = blockIdx.x;
  const int lane = threadIdx.x;
  float* p = x + row * DD + lane * 8;
  float4 v0 = *(float4*)p;
  float4 v1 = *(float4*)(p + 4);
  float va[8] = {v0.x, v0.y, v0.z, v0.w, v1.x, v1.y, v1.z, v1.w};
  float s = 0.f;
  #pragma unroll
  for (int i = 0; i < 8; i++) s += va[i];
  #pragma unroll
  for (int m = 32; m >= 1; m >>= 1) s += __shfl_xor(s, m);
  float mean = s * (1.f / 512.f);
  float q = 0.f;
  #pragma unroll
  for (int i = 0; i < 8; i++) { float d = va[i] - mean; q += d * d; }
  #pragma unroll
  for (int m = 32; m >= 1; m >>= 1) q += __shfl_xor(q, m);
  float rstd = rsqrtf(q * (1.f / 512.f) + 1e-5f);
  const float* gp = gam + lane * 8;
  const float* bp = bet + lane * 8;
  float4 g0 = *(const float4*)gp, g1 = *(const float4*)(gp + 4);
  float4 b0 = *(const float4*)bp, b1 = *(const float4*)(bp + 4);
  float ga[8] = {g0.x, g0.y, g0.z, g0.w, g1.x, g1.y, g1.z, g1.w};
  float ba[8] = {b0.x, b0.y, b0.z, b0.w, b1.x, b1.y, b1.z, b1.w};
  float o[8];
  #pragma unroll
  for (int i = 0; i < 8; i++) o[i] = (va[i] - mean) * rstd * ga[i] + ba[i];
  *(float4*)p       = make_float4(o[0], o[1], o[2], o[3]);
  *(float4*)(p + 4) = make_float4(o[4], o[5], o[6], o[7]);
}

// ---------------------------------------------------------------------------
// K6: post head 1x1 conv (512->1): one wave per (b,t,hw) output.
// ---------------------------------------------------------------------------
__global__ void k_post(const float* __restrict__ y, const float* __restrict__ pw,
                       const float* __restrict__ pb, float* __restrict__ outp)
{
  int m = blockIdx.x * 4 + (threadIdx.x >> 6);
  int lane = threadIdx.x & 63;
  int b = m / 12544;
  int rem = m - b * 12544;
  int t = rem / 196;
  int hw = rem - t * 196;
  const float* row = y + ((size_t)(b * NPIX + hw) * TT + t) * DD + lane * 8;
  float4 a0 = *(const float4*)row, a1 = *(const float4*)(row + 4);
  float4 w0 = *(const float4*)(pw + lane * 8), w1 = *(const float4*)(pw + lane * 8 + 4);
  float s = a0.x * w0.x + a0.y * w0.y + a0.z * w0.z + a0.w * w0.w
          + a1.x * w1.x + a1.y * w1.y + a1.z * w1.z + a1.w * w1.w;
  #pragma unroll
  for (int mm = 32; mm >= 1; mm >>= 1) s += __shfl_xor(s, mm);
  if (lane == 0) outp[m] = s + pb[0];
}

// ---------------------------------------------------------------------------
// K7: classifier Conv1d(512->512)+GELU(exact)+Conv1d(512->1), one block per (b,t).
// ---------------------------------------------------------------------------
__global__ __launch_bounds__(256) void k_cls(
    const float* __restrict__ xv, const float* __restrict__ w1,
    const float* __restrict__ b1, const float* __restrict__ w2,
    const float* __restrict__ b2, float* __restrict__ outp)
{
  const int m = blockIdx.x;                          // b*64+t
  const int tid = threadIdx.x;
  __shared__ float xr[512];
  __shared__ float red[256];
  xr[tid] = xv[(size_t)m * DD + tid];
  xr[tid + 256] = xv[(size_t)m * DD + tid + 256];
  __syncthreads();
  float part = 0.f;
  for (int o = tid; o < 512; o += 256) {
    const float* wr = w1 + (size_t)o * DD;
    float d = 0.f;
    for (int cc = 0; cc < DD; cc += 4) {
      float4 wv = *(const float4*)(wr + cc);
      d += wv.x * xr[cc] + wv.y * xr[cc + 1] + wv.z * xr[cc + 2] + wv.w * xr[cc + 3];
    }
    d += b1[o];
    float ge = 0.5f * d * (1.0f + erff(d * 0.70710678118654752f));
    part += ge * w2[o];
  }
  red[tid] = part;
  __syncthreads();
  for (int s = 128; s > 0; s >>= 1) {
    if (tid < s) red[tid] += red[tid + s];
    __syncthreads();
  }
  if (tid == 0) outp[m] = red[0] + b2[0];
}

// ---------------------------------------------------------------------------
extern "C" void kernel_launch(void* const* d_in, const int* in_sizes, int n_in,
                              void* d_out, int out_size, void* d_ws, size_t ws_size,
                              hipStream_t stream)
{
  const float* x_v    = (const float*)d_in[0];
  const float* fmap   = (const float*)d_in[1];
  const float* pre_w  = (const float*)d_in[2];
  const float* pre_b  = (const float*)d_in[3];
  const float* post_w = (const float*)d_in[4];
  const float* post_b = (const float*)d_in[5];
  const float* tm_W   = (const float*)d_in[6];
  const float* tm_a1  = (const float*)d_in[7];
  const float* tm_a2  = (const float*)d_in[8];
  const float* tm_lw  = (const float*)d_in[9];
  const float* tm_lb  = (const float*)d_in[10];
  const float* tm_g   = (const float*)d_in[11];
  const float* tm_b   = (const float*)d_in[12];
  const float* fm_W   = (const float*)d_in[13];
  const float* fm_a1  = (const float*)d_in[14];
  const float* fm_a2  = (const float*)d_in[15];
  const float* fm_lw  = (const float*)d_in[16];
  const float* fm_lb  = (const float*)d_in[17];
  const float* fm_g   = (const float*)d_in[18];
  const float* fm_b   = (const float*)d_in[19];
  const float* c_w1   = (const float*)d_in[20];
  const float* c_b1   = (const float*)d_in[21];
  const float* c_w2   = (const float*)d_in[22];
  const float* c_b2   = (const float*)d_in[23];
  float* out = (float*)d_out;

  // workspace carve-up
  float* wsf    = (float*)d_ws;
  float* ax     = wsf;                     // 25,690,112 f
  float* tmp    = ax + 25690112;           // 25,690,112 f
  float* xtm    = tmp + 25690112;          // 131,072 f
  float* tmptm  = xtm + 131072;            // 131,072 f
  short* WTb_fm = (short*)(tmptm + 131072);      // 262,144 bf16
  short* WTb_tm = WTb_fm + 262144;               // 262,144 bf16
  short* LWb_fm = WTb_tm + 262144;               // 262,144 bf16
  short* LWb_tm = LWb_fm + 262144;               // 262,144 bf16
  unsigned long long* sel_fm = (unsigned long long*)(LWb_tm + 262144); // 784
  unsigned long long* sel_tm = sel_fm + 784;                           // 4
  short* pwb_hi = (short*)(sel_tm + 4);          // 393,216 bf16
  short* pwb_lo = pwb_hi + 393216;               // 393,216 bf16
  // bf16 fmap half-batch buffers ALIAS tmp (tmp first written at step 4;
  // conv consumes fm buffers before that — stream-ordered, zero extra ws).
  // 128 imgs * 196 * 768 = 19,267,584 shorts + 12,288 pad (tile-12 overrun).
  short* fmh = (short*)tmp;                      // 19,279,872 shorts
  short* fml = fmh + 19279872;                   // 19,279,872 shorts (sum < tmp)

  // 1) weight preps
  k_prepPW<<<1536, 256, 0, stream>>>(pre_w, pwb_hi, pwb_lo);
  k_prepWb<<<1024, 256, 0, stream>>>(fm_W, WTb_fm);
  k_prepWb<<<1024, 256, 0, stream>>>(tm_W, WTb_tm);
  k_prepLWb<<<1024, 256, 0, stream>>>(fm_lw, LWb_fm);
  k_prepLWb<<<1024, 256, 0, stream>>>(tm_lw, LWb_tm);

  // 2) pre head conv in two image-halves: transpose+split, then pure-MFMA conv
  for (int half = 0; half < 2; half++) {
    k_prepFM<<<dim3(12, 128), 256, 0, stream>>>(fmap, fmh, fml, half * 128);
    k_preconv2<<<1024, 256, 0, stream>>>(fmh, fml, pwb_hi, pwb_lo, pre_b, ax, half * 128);
  }

  // 3) top-k selection bitmasks (fp64 ranking)
  k_topk<<<NG_FM, 64, 0, stream>>>(ax, sel_fm);
  k_topk<<<4, 64, 0, stream>>>(x_v, sel_tm);

  // 4) h = x @ Wcat  (MFMA bf16)
  k_gmfma<<<dim3(4, NG_FM), 256, 0, stream>>>(ax, WTb_fm, nullptr, nullptr, tmp);
  k_gmfma<<<dim3(4, 4), 256, 0, stream>>>(x_v, WTb_tm, nullptr, nullptr, tmptm);

  // 5) fused attention + elu + signed-sqrt + column-normalize (in-place on h)
  k_attn<<<dim3(NHEAD, NG_FM), 256, 0, stream>>>(tmp, fm_a1, fm_a2, sel_fm);
  k_attn<<<dim3(NHEAD, 4), 256, 0, stream>>>(tmptm, tm_a1, tm_a2, sel_tm);

  // 6) x = x + tmp @ lin_w.T + lin_b  (MFMA bf16, in-place on x buffers)
  hipMemcpyAsync(xtm, x_v, (size_t)131072 * 4, hipMemcpyDeviceToDevice, stream);
  k_gmfma<<<dim3(4, NG_FM), 256, 0, stream>>>(tmp, LWb_fm, fm_lb, ax, ax);
  k_gmfma<<<dim3(4, 4), 256, 0, stream>>>(tmptm, LWb_tm, tm_lb, xtm, xtm);

  // 7) layernorm in-place
  k_ln<<<NG_FM * TT, 64, 0, stream>>>(ax, fm_g, fm_b);
  k_ln<<<NIMG, 64, 0, stream>>>(xtm, tm_g, tm_b);

  // 8) post head -> ano_map (d_out offset 256), classifier -> logits
  k_post<<<12544, 256, 0, stream>>>(ax, post_w, post_b, out + 256);
  k_cls<<<NIMG, 256, 0, stream>>>(xtm, c_w1, c_b1, c_w2, c_b2, out);
}

// Round 8
// 1325.230 us; speedup vs baseline: 1.4948x; 1.0173x over previous
//
#include <hip/hip_runtime.h>
#include <cstdint>
#include <cstddef>

// Model dims
constexpr int TT   = 64;    // T
constexpr int DD   = 512;   // D
constexpr int NHEAD= 8;
constexpr int DHH  = 64;
constexpr int NPIX = 196;   // 14*14
constexpr int CIN  = 768;
constexpr int KSEL = 44;    // int(0.7*64)
constexpr int NG_FM= 784;   // B*N
constexpr int NIMG = 256;   // B*T
// distance_adj underflow band: exp(-|0.6*d^2+0.2|) in fp32.
// d=12 -> 2.4e-38 (normal). d=13 -> subnormal -> flushed (FTZ). d>=14 -> 0.
constexpr int DBAND = 12;

typedef __attribute__((ext_vector_type(8))) short bf16x8;
typedef __attribute__((ext_vector_type(4))) float f32x4;

__device__ __forceinline__ short bfr(float x) {
  union { float f; unsigned u; } v; v.f = x;
  unsigned r = (v.u + 0x7fffu + ((v.u >> 16) & 1u)) >> 16;   // RNE
  return (short)r;
}
__device__ __forceinline__ float bf2f(short s) {
  return __uint_as_float(((unsigned)(unsigned short)s) << 16);
}

// ---------------------------------------------------------------------------
// prep: split pre_w (f32 [o][k]) into bf16 hi/lo pair, same layout.
// ---------------------------------------------------------------------------
__global__ void k_prepPW(const float* __restrict__ pw, short* __restrict__ hi,
                         short* __restrict__ lo)
{
  int m = blockIdx.x * 256 + threadIdx.x;            // < 512*768
  float x = pw[m];
  short h = bfr(x);
  union { unsigned u; float f; } hf; hf.u = ((unsigned)(unsigned short)h) << 16;
  hi[m] = h;
  lo[m] = bfr(x - hf.f);
}

// ---------------------------------------------------------------------------
// prep: transpose fmap [n][c][hw] f32 -> [n][hw][c] bf16 hi/lo (quarter-batch).
// ---------------------------------------------------------------------------
__global__ __launch_bounds__(256) void k_prepFM(
    const float* __restrict__ fmap, short* __restrict__ fh,
    short* __restrict__ fl, int n0)
{
  __shared__ float ar[64][197];                      // pitch 197: 2-way max
  const int cc = blockIdx.x;                         // 12 chunks of 64 ch
  const int nl = blockIdx.y;                         // 0..63
  const int tid = threadIdx.x;
  const float* src = fmap + ((size_t)(n0 + nl) * CIN + cc * 64) * NPIX;
  for (int i = tid; i < 64 * 49; i += 256) {         // 196 = 49 float4, aligned
    int c = i / 49, q = i - c * 49;
    float4 v = *(const float4*)&src[(size_t)c * NPIX + q * 4];
    *(float4*)&ar[c][q * 4] = v;
  }
  __syncthreads();
  for (int i = tid; i < NPIX * 16; i += 256) {
    int hw = i >> 4, cg = i & 15;
    short h4[4], l4[4];
    #pragma unroll
    for (int j = 0; j < 4; j++) {
      float x = ar[cg * 4 + j][hw];
      unsigned u = __float_as_uint(x);
      h4[j] = (short)(u >> 16);                      // truncation hi
      float r = x - __uint_as_float(u & 0xffff0000u);
      l4[j] = bfr(r);                                // RNE lo
    }
    size_t dst = ((size_t)nl * NPIX + hw) * CIN + cc * 64 + cg * 4;
    *(short4*)&fh[dst] = make_short4(h4[0], h4[1], h4[2], h4[3]);
    *(short4*)&fl[dst] = make_short4(l4[0], l4[1], l4[2], l4[3]);
  }
}

// ---------------------------------------------------------------------------
// K1: pre head 1x1 conv (768->512) + bias + ReLU via split-bf16 MFMA.
// Pure-MFMA main loop, direct global fragment loads, no LDS/barriers until
// epilogue. Writes fp32 ax (top-k/residual/LN) AND bf16 axb (GEMM A-operand).
// ---------------------------------------------------------------------------
__global__ __launch_bounds__(256) void k_preconv2(
    const short* __restrict__ fh, const short* __restrict__ fl,
    const short* __restrict__ pwh, const short* __restrict__ pwl,
    const float* __restrict__ pb, float* __restrict__ ax,
    short* __restrict__ axb, int n0)
{
  __shared__ float arena[7616];                      // epilogue only
  const int wg = blockIdx.x;                         // 512 (64 imgs)
  const int mt = (wg >> 3) & 7;                      // o-chunk
  const int nl = (wg & 7) | ((wg >> 6) << 3);        // local image (XCD-group)
  const int n  = n0 + nl;
  const int b  = n >> 6, t = n & 63;
  const int tid = threadIdx.x;
  const int w = tid >> 6, l = tid & 63;
  const int lr = l & 15, lg = l >> 4;
  const int o0 = mt * 64;

  const int hwt0 = (w == 0) ? 0 : 1 + 3 * w;         // waves: 4,3,3,3 hw-tiles
  const int nq   = (w == 0) ? 4 : 3;

  const short* fhb = fh + (size_t)nl * (NPIX * CIN);
  const short* flb = fl + (size_t)nl * (NPIX * CIN);

  f32x4 acc[4][4];                                   // [q][ot]
  #pragma unroll
  for (int q = 0; q < 4; q++)
    #pragma unroll
    for (int ot = 0; ot < 4; ot++) acc[q][ot] = (f32x4){0.f, 0.f, 0.f, 0.f};

  for (int ks = 0; ks < 24; ks++) {
    const int kb = ks * 32 + lg * 8;
    bf16x8 Ah[4], Al[4];
    #pragma unroll
    for (int ot = 0; ot < 4; ot++) {
      size_t arow = (size_t)(o0 + ot * 16 + lr) * CIN + kb;
      Ah[ot] = *(const bf16x8*)&pwh[arow];
      Al[ot] = *(const bf16x8*)&pwl[arow];
    }
    #pragma unroll
    for (int q = 0; q < 4; q++) if (q < nq) {
      const int hw = (hwt0 + q) * 16 + lr;           // may reach 207: pad'd buf
      size_t brow = (size_t)hw * CIN + kb;
      bf16x8 Bh = *(const bf16x8*)&fhb[brow];
      bf16x8 Bl = *(const bf16x8*)&flb[brow];
      #pragma unroll
      for (int ot = 0; ot < 4; ot++) {
        acc[q][ot] = __builtin_amdgcn_mfma_f32_16x16x32_bf16(Al[ot], Bh, acc[q][ot], 0, 0, 0);
        acc[q][ot] = __builtin_amdgcn_mfma_f32_16x16x32_bf16(Ah[ot], Bl, acc[q][ot], 0, 0, 0);
        acc[q][ot] = __builtin_amdgcn_mfma_f32_16x16x32_bf16(Ah[ot], Bh, acc[q][ot], 0, 0, 0);
      }
    }
  }

  // epilogue: bias + relu, reorder via skewed LDS, coalesced 64-float rows
  float4 pbf[4];
  #pragma unroll
  for (int ot = 0; ot < 4; ot++)
    pbf[ot] = *(const float4*)&pb[o0 + ot * 16 + 4 * lg];

  #pragma unroll
  for (int pass = 0; pass < 2; pass++) {
    const int tbase = pass ? 7 : 0;
    const int tend  = pass ? 13 : 7;
    const int rbase = tbase * 16;
    const int rows  = (tend - tbase) * 16;
    __syncthreads();
    #pragma unroll
    for (int q = 0; q < 4; q++) if (q < nq) {
      int hwt = hwt0 + q;
      if (hwt >= tbase && hwt < tend) {
        int row_l = hwt * 16 + lr - rbase;
        #pragma unroll
        for (int ot = 0; ot < 4; ot++) {
          int col = (ot * 16 + 4 * lg + 4 * row_l) % 68;   // skew: conflict-free
          f32x4 a = acc[q][ot];
          float4 o4v;
          o4v.x = fmaxf(a[0] + pbf[ot].x, 0.f);
          o4v.y = fmaxf(a[1] + pbf[ot].y, 0.f);
          o4v.z = fmaxf(a[2] + pbf[ot].z, 0.f);
          o4v.w = fmaxf(a[3] + pbf[ot].w, 0.f);
          *(float4*)&arena[row_l * 68 + col] = o4v;
        }
      }
    }
    __syncthreads();
    for (int i = tid; i < rows * 16; i += 256) {
      int row_l = i >> 4, o4 = i & 15;
      int hw = rbase + row_l;
      if (hw < NPIX) {
        int col = (o4 * 4 + 4 * row_l) % 68;
        float4 v = *(const float4*)&arena[row_l * 68 + col];
        size_t idx = ((size_t)(b * NPIX + hw) * TT + t) * DD + o0 + o4 * 4;
        *(float4*)&ax[idx] = v;
        *(short4*)&axb[idx] = make_short4(bfr(v.x), bfr(v.y), bfr(v.z), bfr(v.w));
      }
    }
  }
}

// ---------------------------------------------------------------------------
// Weight preps -> bf16, N-major [j][k] so MFMA B-fragments are contiguous-K.
// ---------------------------------------------------------------------------
__global__ void k_prepWb(const float* __restrict__ W, short* __restrict__ o)
{
  int m = blockIdx.x * 256 + threadIdx.x;            // j*512+k, < 262144
  int k = m & 511, j = m >> 9;
  o[m] = bfr(W[(size_t)(j >> 6) * (DD * DHH) + (size_t)k * DHH + (j & 63)]);
}

__global__ void k_prepLWb(const float* __restrict__ a, short* __restrict__ o)
{
  int m = blockIdx.x * 256 + threadIdx.x;            // lin_w is already [j][k]
  o[m] = bfr(a[m]);
}

__global__ void k_cvt(const float* __restrict__ a, short* __restrict__ o)
{
  int m = blockIdx.x * 256 + threadIdx.x;
  o[m] = bfr(a[m]);
}

// ---------------------------------------------------------------------------
// K2: per-graph top-k selection bitmask (fp64 squared-norm ranking).
// ---------------------------------------------------------------------------
__global__ void k_topk(const float* __restrict__ x, unsigned long long* __restrict__ sel)
{
  int g = blockIdx.x, lane = threadIdx.x;            // 64 threads
  const float* row = x + ((size_t)g * TT + lane) * DD;
  double s = 0.0;
  for (int dd = 0; dd < DD; dd += 4) {
    float4 v = *(const float4*)(row + dd);
    s += (double)v.x * (double)v.x + (double)v.y * (double)v.y
       + (double)v.z * (double)v.z + (double)v.w * (double)v.w;
  }
  __shared__ double mag[64];
  mag[lane] = s;
  __syncthreads();
  int rank = 0;
  for (int j = 0; j < 64; j++) {
    double m = mag[j];
    rank += (m > s) || (m == s && j < lane);
  }
  unsigned long long bal = __ballot(rank < KSEL);
  if (lane == 0) sel[g] = bal;
}

// ---------------------------------------------------------------------------
// K3a/K4: per-graph MFMA GEMM  Out[g](64x512) = Ab[g](64x512,bf16) @ Bb^T,
// Bb bf16 N-major [j][k]; +bias +Res(f32) optional; writes f32 Outf and/or
// bf16 Outb. 1D grid with XCD grouping (swz=1): the 4 jb-blocks of a graph
// share an XCD so the A tile is fetched once to that L2.
// ---------------------------------------------------------------------------
__global__ __launch_bounds__(256) void k_gmfma_b(
    const short* __restrict__ Ab, const short* __restrict__ Bb,
    const float* __restrict__ bias, const float* __restrict__ Res,
    float* __restrict__ Outf, short* __restrict__ Outb, int swz)
{
  const int wg = blockIdx.x;
  int g, jb;
  if (swz) { int xcd = wg & 7, q = wg >> 3; g = xcd * 98 + (q >> 2); jb = q & 3; }
  else     { g = wg >> 2; jb = wg & 3; }
  const int tid = threadIdx.x;
  const int w = tid >> 6, l = tid & 63;
  const int lr = l & 15, lg = l >> 4;
  const short* Ar = Ab + (size_t)g * TT * DD + (size_t)(w * 16 + lr) * DD;

  f32x4 acc[8] = {};

  for (int ks = 0; ks < 16; ks++) {
    const int kb = ks * 32 + lg * 8;
    bf16x8 af = *(const bf16x8*)&Ar[kb];
    #pragma unroll
    for (int ct = 0; ct < 8; ct++) {
      const int j = jb * 128 + ct * 16 + lr;
      bf16x8 bb = *(const bf16x8*)&Bb[(size_t)j * DD + kb];
      acc[ct] = __builtin_amdgcn_mfma_f32_16x16x32_bf16(af, bb, acc[ct], 0, 0, 0);
    }
  }

  const size_t gbase = (size_t)g * TT * DD;
  #pragma unroll
  for (int ct = 0; ct < 8; ct++) {
    const int j = jb * 128 + ct * 16 + lr;
    const float bv = bias ? bias[j] : 0.f;
    #pragma unroll
    for (int r = 0; r < 4; r++) {
      const int row = w * 16 + lg * 4 + r;
      float v = acc[ct][r] + bv;
      if (Res)  v += Res[gbase + (size_t)row * DD + j];
      if (Outf) Outf[gbase + (size_t)row * DD + j] = v;
      if (Outb) Outb[gbase + (size_t)row * DD + j] = bfr(v);
    }
  }
}

// ---------------------------------------------------------------------------
// K3b: fused GAT attention per (head, graph); h in bf16, in-place.
// ---------------------------------------------------------------------------
__global__ __launch_bounds__(256) void k_attn(
    short* __restrict__ tmp, const float* __restrict__ a1v,
    const float* __restrict__ a2v, const unsigned long long* __restrict__ sel)
{
  __shared__ float hs[64][68];
  __shared__ float attnv[64][68];
  __shared__ float s1[64], s2[64], aw[128], cnorm[64];
  const int h = blockIdx.x, g = blockIdx.y;
  const int tid = threadIdx.x;
  const int r = tid >> 4, c = tid & 15;
  short* base = tmp + (size_t)g * TT * DD + h * DHH;

  for (int i = tid; i < 4096; i += 256) {
    int t = i >> 6, dh = i & 63;
    hs[t][dh] = bf2f(base[(size_t)t * DD + dh]);
  }
  if (tid < 128) aw[tid] = (tid < 64) ? a1v[h * 64 + tid] : a2v[h * 64 + (tid - 64)];
  __syncthreads();

  if (tid < 64) {
    float v1 = 0.f, v2 = 0.f;
    for (int dh = 0; dh < 64; dh++) { float hv = hs[tid][dh]; v1 += hv * aw[dh]; v2 += hv * aw[64 + dh]; }
    s1[tid] = v1; s2[tid] = v2;
  }
  __syncthreads();

  const unsigned long long sm = sel[g];
  if (tid < 64) {
    const int i = tid;
    const bool seli = (sm >> i) & 1ULL;
    const float vi = s1[i];
    float mx = -1e30f;
    for (int j = 0; j < 64; j++) {
      float e = vi + s2[j];
      e = e >= 0.f ? e : 0.2f * e;                   // leaky_relu(0.2)
      int dist = i > j ? i - j : j - i;
      bool ok = (seli || ((sm >> j) & 1ULL)) && (dist <= DBAND);
      e = ok ? e : -9e15f;
      attnv[i][j] = e;
      mx = fmaxf(mx, e);
    }
    float sum = 0.f;
    for (int j = 0; j < 64; j++) { float p = expf(attnv[i][j] - mx); attnv[i][j] = p; sum += p; }
    float inv = 1.f / sum;
    for (int j = 0; j < 64; j++) attnv[i][j] *= inv;
  }
  __syncthreads();

  float oc[4][4];
  #pragma unroll
  for (int i = 0; i < 4; i++)
    #pragma unroll
    for (int j = 0; j < 4; j++) oc[i][j] = 0.f;
  for (int j = 0; j < 64; j++) {
    float p[4];
    #pragma unroll
    for (int di = 0; di < 4; di++) p[di] = attnv[r * 4 + di][j];
    float4 hv = *(const float4*)&hs[j][c * 4];
    float hb[4] = {hv.x, hv.y, hv.z, hv.w};
    #pragma unroll
    for (int di = 0; di < 4; di++)
      #pragma unroll
      for (int dj = 0; dj < 4; dj++)
        oc[di][dj] += p[di] * hb[dj];
  }

  float cs4[4] = {0.f, 0.f, 0.f, 0.f};
  #pragma unroll
  for (int di = 0; di < 4; di++)
    #pragma unroll
    for (int dj = 0; dj < 4; dj++) {
      float v = oc[di][dj];
      v = v > 0.f ? v : expm1f(v);
      v = v >= 0.f ? sqrtf(v) : -sqrtf(-v);
      oc[di][dj] = v;
      cs4[dj] += v * v;
    }
  __syncthreads();
  *(float4*)&attnv[r][c * 4] = make_float4(cs4[0], cs4[1], cs4[2], cs4[3]);
  __syncthreads();
  if (tid < 64) {
    float ssum = 0.f;
    for (int rr = 0; rr < 16; rr++) ssum += attnv[rr][tid];
    cnorm[tid] = fmaxf(sqrtf(ssum), 1e-12f);
  }
  __syncthreads();
  float4 cn = *(const float4*)&cnorm[c * 4];
  float inv4[4] = {1.f / cn.x, 1.f / cn.y, 1.f / cn.z, 1.f / cn.w};
  #pragma unroll
  for (int di = 0; di < 4; di++) {
    short4 s4 = make_short4(bfr(oc[di][0] * inv4[0]), bfr(oc[di][1] * inv4[1]),
                            bfr(oc[di][2] * inv4[2]), bfr(oc[di][3] * inv4[3]));
    *(short4*)&base[(size_t)(r * 4 + di) * DD + c * 4] = s4;
  }
}

// ---------------------------------------------------------------------------
// K5: LayerNorm in-place, one wave per 512-row.
// ---------------------------------------------------------------------------
__global__ void k_ln(float* __restrict__ x, const float* __restrict__ gam, const float* __restrict__ bet)
{
  const size_t row = blockIdx.x;
  const int lane = threadIdx.x;
  float* p = x + row * DD + lane * 8;
  float4 v0 = *(float4*)p;
  float4 v1 = *(float4*)(p + 4);
  float va[8] = {v0.x, v0.y, v0.z, v0.w, v1.x, v1.y, v1.z, v1.w};
  float s = 0.f;
  #pragma unroll
  for (int i = 0; i < 8; i++) s += va[i];
  #pragma unroll
  for (int m = 32; m >= 1; m >>= 1) s += __shfl_xor(s, m);
  float mean = s * (1.f / 512.f);
  float q = 0.f;
  #pragma unroll
  for (int i = 0; i < 8; i++) { float d = va[i] - mean; q += d * d; }
  #pragma unroll
  for (int m = 32; m >= 1; m >>= 1) q += __shfl_xor(q, m);
  float rstd = rsqrtf(q * (1.f / 512.f) + 1e-5f);
  const float* gp = gam + lane * 8;
  const float* bp = bet + lane * 8;
  float4 g0 = *(const float4*)gp, g1 = *(const float4*)(gp + 4);
  float4 b0 = *(const float4*)bp, b1 = *(const float4*)(bp + 4);
  float ga[8] = {g0.x, g0.y, g0.z, g0.w, g1.x, g1.y, g1.z, g1.w};
  float ba[8] = {b0.x, b0.y, b0.z, b0.w, b1.x, b1.y, b1.z, b1.w};
  float o[8];
  #pragma unroll
  for (int i = 0; i < 8; i++) o[i] = (va[i] - mean) * rstd * ga[i] + ba[i];
  *(float4*)p       = make_float4(o[0], o[1], o[2], o[3]);
  *(float4*)(p + 4) = make_float4(o[4], o[5], o[6], o[7]);
}

// ---------------------------------------------------------------------------
// K6: post head 1x1 conv (512->1): one wave per (b,t,hw) output.
// ---------------------------------------------------------------------------
__global__ void k_post(const float* __restrict__ y, const float* __restrict__ pw,
                       const float* __restrict__ pb, float* __restrict__ outp)
{
  int m = blockIdx.x * 4 + (threadIdx.x >> 6);
  int lane = threadIdx.x & 63;
  int b = m / 12544;
  int rem = m - b * 12544;
  int t = rem / 196;
  int hw = rem - t * 196;
  const float* row = y + ((size_t)(b * NPIX + hw) * TT + t) * DD + lane * 8;
  float4 a0 = *(const float4*)row, a1 = *(const float4*)(row + 4);
  float4 w0 = *(const float4*)(pw + lane * 8), w1 = *(const float4*)(pw + lane * 8 + 4);
  float s = a0.x * w0.x + a0.y * w0.y + a0.z * w0.z + a0.w * w0.w
          + a1.x * w1.x + a1.y * w1.y + a1.z * w1.z + a1.w * w1.w;
  #pragma unroll
  for (int mm = 32; mm >= 1; mm >>= 1) s += __shfl_xor(s, mm);
  if (lane == 0) outp[m] = s + pb[0];
}

// ---------------------------------------------------------------------------
// K7: classifier Conv1d(512->512)+GELU(exact)+Conv1d(512->1), one block per (b,t).
// ---------------------------------------------------------------------------
__global__ __launch_bounds__(256) void k_cls(
    const float* __restrict__ xv, const float* __restrict__ w1,
    const float* __restrict__ b1, const float* __restrict__ w2,
    const float* __restrict__ b2, float* __restrict__ outp)
{
  const int m = blockIdx.x;                          // b*64+t
  const int tid = threadIdx.x;
  __shared__ float xr[512];
  __shared__ float red[256];
  xr[tid] = xv[(size_t)m * DD + tid];
  xr[tid + 256] = xv[(size_t)m * DD + tid + 256];
  __syncthreads();
  float part = 0.f;
  for (int o = tid; o < 512; o += 256) {
    const float* wr = w1 + (size_t)o * DD;
    float d = 0.f;
    for (int cc = 0; cc < DD; cc += 4) {
      float4 wv = *(const float4*)(wr + cc);
      d += wv.x * xr[cc] + wv.y * xr[cc + 1] + wv.z * xr[cc + 2] + wv.w * xr[cc + 3];
    }
    d += b1[o];
    float ge = 0.5f * d * (1.0f + erff(d * 0.70710678118654752f));
    part += ge * w2[o];
  }
  red[tid] = part;
  __syncthreads();
  for (int s = 128; s > 0; s >>= 1) {
    if (tid < s) red[tid] += red[tid + s];
    __syncthreads();
  }
  if (tid == 0) outp[m] = red[0] + b2[0];
}

// ---------------------------------------------------------------------------
extern "C" void kernel_launch(void* const* d_in, const int* in_sizes, int n_in,
                              void* d_out, int out_size, void* d_ws, size_t ws_size,
                              hipStream_t stream)
{
  const float* x_v    = (const float*)d_in[0];
  const float* fmap   = (const float*)d_in[1];
  const float* pre_w  = (const float*)d_in[2];
  const float* pre_b  = (const float*)d_in[3];
  const float* post_w = (const float*)d_in[4];
  const float* post_b = (const float*)d_in[5];
  const float* tm_W   = (const float*)d_in[6];
  const float* tm_a1  = (const float*)d_in[7];
  const float* tm_a2  = (const float*)d_in[8];
  const float* tm_lw  = (const float*)d_in[9];
  const float* tm_lb  = (const float*)d_in[10];
  const float* tm_g   = (const float*)d_in[11];
  const float* tm_b   = (const float*)d_in[12];
  const float* fm_W   = (const float*)d_in[13];
  const float* fm_a1  = (const float*)d_in[14];
  const float* fm_a2  = (const float*)d_in[15];
  const float* fm_lw  = (const float*)d_in[16];
  const float* fm_lb  = (const float*)d_in[17];
  const float* fm_g   = (const float*)d_in[18];
  const float* fm_b   = (const float*)d_in[19];
  const float* c_w1   = (const float*)d_in[20];
  const float* c_b1   = (const float*)d_in[21];
  const float* c_w2   = (const float*)d_in[22];
  const float* c_b2   = (const float*)d_in[23];
  float* out = (float*)d_out;

  // workspace carve-up (~210 MB, same footprint as before)
  float* wsf    = (float*)d_ws;
  float* ax     = wsf;                           // 25,690,112 f
  short* axb    = (short*)(ax + 25690112);       // 25,690,112 bf16
  short* tmpb   = axb + 25690112;                // 25,690,112 bf16
  float* xtm    = (float*)(tmpb + 25690112);     // 131,072 f
  short* xvb    = (short*)(xtm + 131072);        // 131,072 bf16
  short* tmptmb = xvb + 131072;                  // 131,072 bf16
  short* WTb_fm = tmptmb + 131072;               // 262,144 bf16
  short* WTb_tm = WTb_fm + 262144;               // 262,144 bf16
  short* LWb_fm = WTb_tm + 262144;               // 262,144 bf16
  short* LWb_tm = LWb_fm + 262144;               // 262,144 bf16
  short* pwb_hi = LWb_tm + 262144;               // 393,216 bf16
  short* pwb_lo = pwb_hi + 393216;               // 393,216 bf16
  unsigned long long* sel_fm = (unsigned long long*)(pwb_lo + 393216); // 784
  unsigned long long* sel_tm = sel_fm + 784;                           // 4
  // bf16 fmap quarter-batch staging ALIASES tmpb (tmpb first written at
  // step 4, after all preconv quarters are done). 64 imgs * 196 * 768 =
  // 9,633,792 shorts + 12,288 pad (hw-tile overrun) each.
  short* fmh = tmpb;                             // 9,646,080 shorts
  short* fml = fmh + 9646080;                    // 9,646,080 shorts (< tmpb sz)

  // 1) weight preps + x_v bf16
  k_prepPW<<<1536, 256, 0, stream>>>(pre_w, pwb_hi, pwb_lo);
  k_prepWb<<<1024, 256, 0, stream>>>(fm_W, WTb_fm);
  k_prepWb<<<1024, 256, 0, stream>>>(tm_W, WTb_tm);
  k_prepLWb<<<1024, 256, 0, stream>>>(fm_lw, LWb_fm);
  k_prepLWb<<<1024, 256, 0, stream>>>(tm_lw, LWb_tm);
  k_cvt<<<512, 256, 0, stream>>>(x_v, xvb);

  // 2) pre head conv in four image-quarters: transpose+split, pure-MFMA conv
  for (int qtr = 0; qtr < 4; qtr++) {
    k_prepFM<<<dim3(12, 64), 256, 0, stream>>>(fmap, fmh, fml, qtr * 64);
    k_preconv2<<<512, 256, 0, stream>>>(fmh, fml, pwb_hi, pwb_lo, pre_b, ax, axb, qtr * 64);
  }

  // 3) top-k selection bitmasks (fp64 ranking)
  k_topk<<<NG_FM, 64, 0, stream>>>(ax, sel_fm);
  k_topk<<<4, 64, 0, stream>>>(x_v, sel_tm);

  // 4) h = x @ Wcat  (MFMA bf16, bf16 out)
  k_gmfma_b<<<3136, 256, 0, stream>>>(axb, WTb_fm, nullptr, nullptr, nullptr, tmpb, 1);
  k_gmfma_b<<<16, 256, 0, stream>>>(xvb, WTb_tm, nullptr, nullptr, nullptr, tmptmb, 0);

  // 5) fused attention + elu + signed-sqrt + column-normalize (bf16 in-place)
  k_attn<<<dim3(NHEAD, NG_FM), 256, 0, stream>>>(tmpb, fm_a1, fm_a2, sel_fm);
  k_attn<<<dim3(NHEAD, 4), 256, 0, stream>>>(tmptmb, tm_a1, tm_a2, sel_tm);

  // 6) x = x + tmp @ lin_w.T + lin_b  (MFMA bf16, f32 out w/ residual)
  hipMemcpyAsync(xtm, x_v, (size_t)131072 * 4, hipMemcpyDeviceToDevice, stream);
  k_gmfma_b<<<3136, 256, 0, stream>>>(tmpb, LWb_fm, fm_lb, ax, ax, nullptr, 1);
  k_gmfma_b<<<16, 256, 0, stream>>>(tmptmb, LWb_tm, tm_lb, xtm, xtm, nullptr, 0);

  // 7) layernorm in-place
  k_ln<<<NG_FM * TT, 64, 0, stream>>>(ax, fm_g, fm_b);
  k_ln<<<NIMG, 64, 0, stream>>>(xtm, tm_g, tm_b);

  // 8) post head -> ano_map (d_out offset 256), classifier -> logits
  k_post<<<12544, 256, 0, stream>>>(ax, post_w, post_b, out + 256);
  k_cls<<<NIMG, 256, 0, stream>>>(xtm, c_w1, c_b1, c_w2, c_b2, out);
}

// Round 9
// 997.072 us; speedup vs baseline: 1.9867x; 1.3291x over previous
//
#include <hip/hip_runtime.h>
#include <cstdint>
#include <cstddef>

// Model dims
constexpr int TT   = 64;    // T
constexpr int DD   = 512;   // D
constexpr int NHEAD= 8;
constexpr int DHH  = 64;
constexpr int NPIX = 196;   // 14*14
constexpr int CIN  = 768;
constexpr int KSEL = 44;    // int(0.7*64)
constexpr int NG_FM= 784;   // B*N
constexpr int NIMG = 256;   // B*T
// distance_adj underflow band: exp(-|0.6*d^2+0.2|) in fp32.
// d=12 -> 2.4e-38 (normal). d=13 -> subnormal -> flushed (FTZ). d>=14 -> 0.
constexpr int DBAND = 12;

typedef __attribute__((ext_vector_type(8))) short bf16x8;
typedef __attribute__((ext_vector_type(4))) float f32x4;

__device__ __forceinline__ short bfr(float x) {
  union { float f; unsigned u; } v; v.f = x;
  unsigned r = (v.u + 0x7fffu + ((v.u >> 16) & 1u)) >> 16;   // RNE
  return (short)r;
}
__device__ __forceinline__ float bf2f(short s) {
  return __uint_as_float(((unsigned)(unsigned short)s) << 16);
}

// ---------------------------------------------------------------------------
// prep: split pre_w (f32 [o][k]) into bf16 hi/lo pair, same layout.
// ---------------------------------------------------------------------------
__global__ void k_prepPW(const float* __restrict__ pw, short* __restrict__ hi,
                         short* __restrict__ lo)
{
  int m = blockIdx.x * 256 + threadIdx.x;            // < 512*768
  float x = pw[m];
  short h = bfr(x);
  union { unsigned u; float f; } hf; hf.u = ((unsigned)(unsigned short)h) << 16;
  hi[m] = h;
  lo[m] = bfr(x - hf.f);
}

// ---------------------------------------------------------------------------
// prep: transpose fmap [n][c][hw] f32 -> [n][hw][c] bf16 hi/lo (quarter-batch).
// ---------------------------------------------------------------------------
__global__ __launch_bounds__(256) void k_prepFM(
    const float* __restrict__ fmap, short* __restrict__ fh,
    short* __restrict__ fl, int n0)
{
  __shared__ float ar[64][197];                      // pitch 197: 2-way max
  const int cc = blockIdx.x;                         // 12 chunks of 64 ch
  const int nl = blockIdx.y;                         // 0..63
  const int tid = threadIdx.x;
  const float* src = fmap + ((size_t)(n0 + nl) * CIN + cc * 64) * NPIX;
  for (int i = tid; i < 64 * 49; i += 256) {         // 196 = 49 float4, aligned
    int c = i / 49, q = i - c * 49;
    float4 v = *(const float4*)&src[(size_t)c * NPIX + q * 4];
    *(float4*)&ar[c][q * 4] = v;
  }
  __syncthreads();
  for (int i = tid; i < NPIX * 16; i += 256) {
    int hw = i >> 4, cg = i & 15;
    short h4[4], l4[4];
    #pragma unroll
    for (int j = 0; j < 4; j++) {
      float x = ar[cg * 4 + j][hw];
      unsigned u = __float_as_uint(x);
      h4[j] = (short)(u >> 16);                      // truncation hi
      float r = x - __uint_as_float(u & 0xffff0000u);
      l4[j] = bfr(r);                                // RNE lo
    }
    size_t dst = ((size_t)nl * NPIX + hw) * CIN + cc * 64 + cg * 4;
    *(short4*)&fh[dst] = make_short4(h4[0], h4[1], h4[2], h4[3]);
    *(short4*)&fl[dst] = make_short4(l4[0], l4[1], l4[2], l4[3]);
  }
}

// ---------------------------------------------------------------------------
// K1: pre head 1x1 conv (768->512) + bias + ReLU via split-bf16 MFMA.
// Pure-MFMA main loop, direct global fragment loads, no LDS/barriers until
// epilogue. Writes fp32 ax (top-k/residual/LN) AND bf16 axb (GEMM A-operand).
// ---------------------------------------------------------------------------
__global__ __launch_bounds__(256) void k_preconv2(
    const short* __restrict__ fh, const short* __restrict__ fl,
    const short* __restrict__ pwh, const short* __restrict__ pwl,
    const float* __restrict__ pb, float* __restrict__ ax,
    short* __restrict__ axb, int n0)
{
  __shared__ float arena[7616];                      // epilogue only
  const int wg = blockIdx.x;                         // 512 (64 imgs)
  const int mt = (wg >> 3) & 7;                      // o-chunk
  const int nl = (wg & 7) | ((wg >> 6) << 3);        // local image (XCD-group)
  const int n  = n0 + nl;
  const int b  = n >> 6, t = n & 63;
  const int tid = threadIdx.x;
  const int w = tid >> 6, l = tid & 63;
  const int lr = l & 15, lg = l >> 4;
  const int o0 = mt * 64;

  const int hwt0 = (w == 0) ? 0 : 1 + 3 * w;         // waves: 4,3,3,3 hw-tiles
  const int nq   = (w == 0) ? 4 : 3;

  const short* fhb = fh + (size_t)nl * (NPIX * CIN);
  const short* flb = fl + (size_t)nl * (NPIX * CIN);

  f32x4 acc[4][4];                                   // [q][ot]
  #pragma unroll
  for (int q = 0; q < 4; q++)
    #pragma unroll
    for (int ot = 0; ot < 4; ot++) acc[q][ot] = (f32x4){0.f, 0.f, 0.f, 0.f};

  for (int ks = 0; ks < 24; ks++) {
    const int kb = ks * 32 + lg * 8;
    bf16x8 Ah[4], Al[4];
    #pragma unroll
    for (int ot = 0; ot < 4; ot++) {
      size_t arow = (size_t)(o0 + ot * 16 + lr) * CIN + kb;
      Ah[ot] = *(const bf16x8*)&pwh[arow];
      Al[ot] = *(const bf16x8*)&pwl[arow];
    }
    #pragma unroll
    for (int q = 0; q < 4; q++) if (q < nq) {
      const int hw = (hwt0 + q) * 16 + lr;           // may reach 207: pad'd buf
      size_t brow = (size_t)hw * CIN + kb;
      bf16x8 Bh = *(const bf16x8*)&fhb[brow];
      bf16x8 Bl = *(const bf16x8*)&flb[brow];
      #pragma unroll
      for (int ot = 0; ot < 4; ot++) {
        acc[q][ot] = __builtin_amdgcn_mfma_f32_16x16x32_bf16(Al[ot], Bh, acc[q][ot], 0, 0, 0);
        acc[q][ot] = __builtin_amdgcn_mfma_f32_16x16x32_bf16(Ah[ot], Bl, acc[q][ot], 0, 0, 0);
        acc[q][ot] = __builtin_amdgcn_mfma_f32_16x16x32_bf16(Ah[ot], Bh, acc[q][ot], 0, 0, 0);
      }
    }
  }

  // epilogue: bias + relu, reorder via skewed LDS, coalesced 64-float rows
  float4 pbf[4];
  #pragma unroll
  for (int ot = 0; ot < 4; ot++)
    pbf[ot] = *(const float4*)&pb[o0 + ot * 16 + 4 * lg];

  #pragma unroll
  for (int pass = 0; pass < 2; pass++) {
    const int tbase = pass ? 7 : 0;
    const int tend  = pass ? 13 : 7;
    const int rbase = tbase * 16;
    const int rows  = (tend - tbase) * 16;
    __syncthreads();
    #pragma unroll
    for (int q = 0; q < 4; q++) if (q < nq) {
      int hwt = hwt0 + q;
      if (hwt >= tbase && hwt < tend) {
        int row_l = hwt * 16 + lr - rbase;
        #pragma unroll
        for (int ot = 0; ot < 4; ot++) {
          int col = (ot * 16 + 4 * lg + 4 * row_l) % 68;   // skew: conflict-free
          f32x4 a = acc[q][ot];
          float4 o4v;
          o4v.x = fmaxf(a[0] + pbf[ot].x, 0.f);
          o4v.y = fmaxf(a[1] + pbf[ot].y, 0.f);
          o4v.z = fmaxf(a[2] + pbf[ot].z, 0.f);
          o4v.w = fmaxf(a[3] + pbf[ot].w, 0.f);
          *(float4*)&arena[row_l * 68 + col] = o4v;
        }
      }
    }
    __syncthreads();
    for (int i = tid; i < rows * 16; i += 256) {
      int row_l = i >> 4, o4 = i & 15;
      int hw = rbase + row_l;
      if (hw < NPIX) {
        int col = (o4 * 4 + 4 * row_l) % 68;
        float4 v = *(const float4*)&arena[row_l * 68 + col];
        size_t idx = ((size_t)(b * NPIX + hw) * TT + t) * DD + o0 + o4 * 4;
        *(float4*)&ax[idx] = v;
        *(short4*)&axb[idx] = make_short4(bfr(v.x), bfr(v.y), bfr(v.z), bfr(v.w));
      }
    }
  }
}

// ---------------------------------------------------------------------------
// Weight preps -> bf16, N-major [j][k] so MFMA B-fragments are contiguous-K.
// ---------------------------------------------------------------------------
__global__ void k_prepWb(const float* __restrict__ W, short* __restrict__ o)
{
  int m = blockIdx.x * 256 + threadIdx.x;            // j*512+k, < 262144
  int k = m & 511, j = m >> 9;
  o[m] = bfr(W[(size_t)(j >> 6) * (DD * DHH) + (size_t)k * DHH + (j & 63)]);
}

__global__ void k_prepLWb(const float* __restrict__ a, short* __restrict__ o)
{
  int m = blockIdx.x * 256 + threadIdx.x;            // lin_w is already [j][k]
  o[m] = bfr(a[m]);
}

__global__ void k_cvt(const float* __restrict__ a, short* __restrict__ o)
{
  int m = blockIdx.x * 256 + threadIdx.x;
  o[m] = bfr(a[m]);
}

// ---------------------------------------------------------------------------
// K2: per-graph top-k selection bitmask (fp64 squared-norm ranking).
// ---------------------------------------------------------------------------
__global__ void k_topk(const float* __restrict__ x, unsigned long long* __restrict__ sel)
{
  int g = blockIdx.x, lane = threadIdx.x;            // 64 threads
  const float* row = x + ((size_t)g * TT + lane) * DD;
  double s = 0.0;
  for (int dd = 0; dd < DD; dd += 4) {
    float4 v = *(const float4*)(row + dd);
    s += (double)v.x * (double)v.x + (double)v.y * (double)v.y
       + (double)v.z * (double)v.z + (double)v.w * (double)v.w;
  }
  __shared__ double mag[64];
  mag[lane] = s;
  __syncthreads();
  int rank = 0;
  for (int j = 0; j < 64; j++) {
    double m = mag[j];
    rank += (m > s) || (m == s && j < lane);
  }
  unsigned long long bal = __ballot(rank < KSEL);
  if (lane == 0) sel[g] = bal;
}

// ---------------------------------------------------------------------------
// K3a/K4: flat GEMM  Out[M x 512] = Ab[M x 512](bf16) @ Bb^T (Bb [512 N][512 K]
// bf16 N-major). m97-style: 128x128 tile, BK=32, 4 waves (2x2 of 64x64),
// LDS double-buffer, one barrier per K-step, next-tile loads issued before
// compute. Optional +bias +Res(f32); writes f32 Outf and/or bf16 Outb.
// Grid: Mtiles*4 1D; swz=1 groups the 4 N-blocks of an M-tile on one XCD.
// ---------------------------------------------------------------------------
__global__ __launch_bounds__(256) void k_gemm(
    const short* __restrict__ Ab, const short* __restrict__ Bb,
    const float* __restrict__ bias, const float* __restrict__ Res,
    float* __restrict__ Outf, short* __restrict__ Outb,
    int Mtiles, int swz)
{
  __shared__ short Asl[2][128 * 32];
  __shared__ short Bsl[2][128 * 32];
  const int wg = blockIdx.x;
  int mt, nt;
  if (swz) { int xcd = wg & 7, idx = wg >> 3; mt = xcd * (Mtiles >> 3) + (idx >> 2); nt = idx & 3; }
  else     { mt = wg >> 2; nt = wg & 3; }
  const int m0 = mt * 128, n0 = nt * 128;
  const int tid = threadIdx.x;
  const int l  = tid & 63;
  const int lr = l & 15, lg = l >> 4;
  const int wm = (tid >> 7) & 1, wn = (tid >> 6) & 1;   // wave quadrant

  // staging: thread t covers 32B of A row (m0+srow) and B row (n0+srow)
  const int srow = tid >> 1, skq = tid & 1;
  const short* gA = Ab + (size_t)(m0 + srow) * DD + skq * 16;
  const short* gB = Bb + (size_t)(n0 + srow) * DD + skq * 16;
  const int soff = srow * 32 + skq * 16;             // shorts; 64B row stride

  bf16x8 ra0 = *(const bf16x8*)(gA);
  bf16x8 ra1 = *(const bf16x8*)(gA + 8);
  bf16x8 rb0 = *(const bf16x8*)(gB);
  bf16x8 rb1 = *(const bf16x8*)(gB + 8);
  *(bf16x8*)&Asl[0][soff]     = ra0;
  *(bf16x8*)&Asl[0][soff + 8] = ra1;
  *(bf16x8*)&Bsl[0][soff]     = rb0;
  *(bf16x8*)&Bsl[0][soff + 8] = rb1;
  __syncthreads();

  f32x4 acc[4][4] = {};
  for (int ks = 0; ks < 16; ks++) {
    const int cur = ks & 1;
    if (ks < 15) {                                   // issue next-tile loads
      const int k0 = (ks + 1) * 32;
      ra0 = *(const bf16x8*)(gA + k0);
      ra1 = *(const bf16x8*)(gA + k0 + 8);
      rb0 = *(const bf16x8*)(gB + k0);
      rb1 = *(const bf16x8*)(gB + k0 + 8);
    }
    bf16x8 af[4], bfv[4];
    #pragma unroll
    for (int mi = 0; mi < 4; mi++)
      af[mi] = *(const bf16x8*)&Asl[cur][(wm * 64 + mi * 16 + lr) * 32 + lg * 8];
    #pragma unroll
    for (int ni = 0; ni < 4; ni++)
      bfv[ni] = *(const bf16x8*)&Bsl[cur][(wn * 64 + ni * 16 + lr) * 32 + lg * 8];
    #pragma unroll
    for (int mi = 0; mi < 4; mi++)
      #pragma unroll
      for (int ni = 0; ni < 4; ni++)
        acc[mi][ni] = __builtin_amdgcn_mfma_f32_16x16x32_bf16(af[mi], bfv[ni], acc[mi][ni], 0, 0, 0);
    if (ks < 15) {                                   // write next buf (disjoint)
      *(bf16x8*)&Asl[cur ^ 1][soff]     = ra0;
      *(bf16x8*)&Asl[cur ^ 1][soff + 8] = ra1;
      *(bf16x8*)&Bsl[cur ^ 1][soff]     = rb0;
      *(bf16x8*)&Bsl[cur ^ 1][soff + 8] = rb1;
      __syncthreads();
    }
  }

  // epilogue (C/D layout: col = lr, row = lg*4 + r, validated)
  #pragma unroll
  for (int mi = 0; mi < 4; mi++) {
    #pragma unroll
    for (int r = 0; r < 4; r++) {
      const size_t row = (size_t)(m0 + wm * 64 + mi * 16 + lg * 4 + r);
      #pragma unroll
      for (int ni = 0; ni < 4; ni++) {
        const int col = n0 + wn * 64 + ni * 16 + lr;
        float v = acc[mi][ni][r];
        if (bias) v += bias[col];
        if (Res)  v += Res[row * DD + col];
        if (Outf) Outf[row * DD + col] = v;
        if (Outb) Outb[row * DD + col] = bfr(v);
      }
    }
  }
}

// ---------------------------------------------------------------------------
// K3b: fused GAT attention per (head, graph); h in bf16, in-place.
// ---------------------------------------------------------------------------
__global__ __launch_bounds__(256) void k_attn(
    short* __restrict__ tmp, const float* __restrict__ a1v,
    const float* __restrict__ a2v, const unsigned long long* __restrict__ sel)
{
  __shared__ float hs[64][68];
  __shared__ float attnv[64][68];
  __shared__ float s1[64], s2[64], aw[128], cnorm[64];
  const int h = blockIdx.x, g = blockIdx.y;
  const int tid = threadIdx.x;
  const int r = tid >> 4, c = tid & 15;
  short* base = tmp + (size_t)g * TT * DD + h * DHH;

  for (int i = tid; i < 4096; i += 256) {
    int t = i >> 6, dh = i & 63;
    hs[t][dh] = bf2f(base[(size_t)t * DD + dh]);
  }
  if (tid < 128) aw[tid] = (tid < 64) ? a1v[h * 64 + tid] : a2v[h * 64 + (tid - 64)];
  __syncthreads();

  if (tid < 64) {
    float v1 = 0.f, v2 = 0.f;
    for (int dh = 0; dh < 64; dh++) { float hv = hs[tid][dh]; v1 += hv * aw[dh]; v2 += hv * aw[64 + dh]; }
    s1[tid] = v1; s2[tid] = v2;
  }
  __syncthreads();

  const unsigned long long sm = sel[g];
  if (tid < 64) {
    const int i = tid;
    const bool seli = (sm >> i) & 1ULL;
    const float vi = s1[i];
    float mx = -1e30f;
    for (int j = 0; j < 64; j++) {
      float e = vi + s2[j];
      e = e >= 0.f ? e : 0.2f * e;                   // leaky_relu(0.2)
      int dist = i > j ? i - j : j - i;
      bool ok = (seli || ((sm >> j) & 1ULL)) && (dist <= DBAND);
      e = ok ? e : -9e15f;
      attnv[i][j] = e;
      mx = fmaxf(mx, e);
    }
    float sum = 0.f;
    for (int j = 0; j < 64; j++) { float p = expf(attnv[i][j] - mx); attnv[i][j] = p; sum += p; }
    float inv = 1.f / sum;
    for (int j = 0; j < 64; j++) attnv[i][j] *= inv;
  }
  __syncthreads();

  float oc[4][4];
  #pragma unroll
  for (int i = 0; i < 4; i++)
    #pragma unroll
    for (int j = 0; j < 4; j++) oc[i][j] = 0.f;
  for (int j = 0; j < 64; j++) {
    float p[4];
    #pragma unroll
    for (int di = 0; di < 4; di++) p[di] = attnv[r * 4 + di][j];
    float4 hv = *(const float4*)&hs[j][c * 4];
    float hb[4] = {hv.x, hv.y, hv.z, hv.w};
    #pragma unroll
    for (int di = 0; di < 4; di++)
      #pragma unroll
      for (int dj = 0; dj < 4; dj++)
        oc[di][dj] += p[di] * hb[dj];
  }

  float cs4[4] = {0.f, 0.f, 0.f, 0.f};
  #pragma unroll
  for (int di = 0; di < 4; di++)
    #pragma unroll
    for (int dj = 0; dj < 4; dj++) {
      float v = oc[di][dj];
      v = v > 0.f ? v : expm1f(v);
      v = v >= 0.f ? sqrtf(v) : -sqrtf(-v);
      oc[di][dj] = v;
      cs4[dj] += v * v;
    }
  __syncthreads();
  *(float4*)&attnv[r][c * 4] = make_float4(cs4[0], cs4[1], cs4[2], cs4[3]);
  __syncthreads();
  if (tid < 64) {
    float ssum = 0.f;
    for (int rr = 0; rr < 16; rr++) ssum += attnv[rr][tid];
    cnorm[tid] = fmaxf(sqrtf(ssum), 1e-12f);
  }
  __syncthreads();
  float4 cn = *(const float4*)&cnorm[c * 4];
  float inv4[4] = {1.f / cn.x, 1.f / cn.y, 1.f / cn.z, 1.f / cn.w};
  #pragma unroll
  for (int di = 0; di < 4; di++) {
    short4 s4 = make_short4(bfr(oc[di][0] * inv4[0]), bfr(oc[di][1] * inv4[1]),
                            bfr(oc[di][2] * inv4[2]), bfr(oc[di][3] * inv4[3]));
    *(short4*)&base[(size_t)(r * 4 + di) * DD + c * 4] = s4;
  }
}

// ---------------------------------------------------------------------------
// K5: LayerNorm in-place, one wave per 512-row.
// ---------------------------------------------------------------------------
__global__ void k_ln(float* __restrict__ x, const float* __restrict__ gam, const float* __restrict__ bet)
{
  const size_t row = blockIdx.x;
  const int lane = threadIdx.x;
  float* p = x + row * DD + lane * 8;
  float4 v0 = *(float4*)p;
  float4 v1 = *(float4*)(p + 4);
  float va[8] = {v0.x, v0.y, v0.z, v0.w, v1.x, v1.y, v1.z, v1.w};
  float s = 0.f;
  #pragma unroll
  for (int i = 0; i < 8; i++) s += va[i];
  #pragma unroll
  for (int m = 32; m >= 1; m >>= 1) s += __shfl_xor(s, m);
  float mean = s * (1.f / 512.f);
  float q = 0.f;
  #pragma unroll
  for (int i = 0; i < 8; i++) { float d = va[i] - mean; q += d * d; }
  #pragma unroll
  for (int m = 32; m >= 1; m >>= 1) q += __shfl_xor(q, m);
  float rstd = rsqrtf(q * (1.f / 512.f) + 1e-5f);
  const float* gp = gam + lane * 8;
  const float* bp = bet + lane * 8;
  float4 g0 = *(const float4*)gp, g1 = *(const float4*)(gp + 4);
  float4 b0 = *(const float4*)bp, b1 = *(const float4*)(bp + 4);
  float ga[8] = {g0.x, g0.y, g0.z, g0.w, g1.x, g1.y, g1.z, g1.w};
  float ba[8] = {b0.x, b0.y, b0.z, b0.w, b1.x, b1.y, b1.z, b1.w};
  float o[8];
  #pragma unroll
  for (int i = 0; i < 8; i++) o[i] = (va[i] - mean) * rstd * ga[i] + ba[i];
  *(float4*)p       = make_float4(o[0], o[1], o[2], o[3]);
  *(float4*)(p + 4) = make_float4(o[4], o[5], o[6], o[7]);
}

// ---------------------------------------------------------------------------
// K6: post head 1x1 conv (512->1): one wave per (b,t,hw) output.
// ---------------------------------------------------------------------------
__global__ void k_post(const float* __restrict__ y, const float* __restrict__ pw,
                       const float* __restrict__ pb, float* __restrict__ outp)
{
  int m = blockIdx.x * 4 + (threadIdx.x >> 6);
  int lane = threadIdx.x & 63;
  int b = m / 12544;
  int rem = m - b * 12544;
  int t = rem / 196;
  int hw = rem - t * 196;
  const float* row = y + ((size_t)(b * NPIX + hw) * TT + t) * DD + lane * 8;
  float4 a0 = *(const float4*)row, a1 = *(const float4*)(row + 4);
  float4 w0 = *(const float4*)(pw + lane * 8), w1 = *(const float4*)(pw + lane * 8 + 4);
  float s = a0.x * w0.x + a0.y * w0.y + a0.z * w0.z + a0.w * w0.w
          + a1.x * w1.x + a1.y * w1.y + a1.z * w1.z + a1.w * w1.w;
  #pragma unroll
  for (int mm = 32; mm >= 1; mm >>= 1) s += __shfl_xor(s, mm);
  if (lane == 0) outp[m] = s + pb[0];
}

// ---------------------------------------------------------------------------
// K7: classifier Conv1d(512->512)+GELU(exact)+Conv1d(512->1), one block per (b,t).
// ---------------------------------------------------------------------------
__global__ __launch_bounds__(256) void k_cls(
    const float* __restrict__ xv, const float* __restrict__ w1,
    const float* __restrict__ b1, const float* __restrict__ w2,
    const float* __restrict__ b2, float* __restrict__ outp)
{
  const int m = blockIdx.x;                          // b*64+t
  const int tid = threadIdx.x;
  __shared__ float xr[512];
  __shared__ float red[256];
  xr[tid] = xv[(size_t)m * DD + tid];
  xr[tid + 256] = xv[(size_t)m * DD + tid + 256];
  __syncthreads();
  float part = 0.f;
  for (int o = tid; o < 512; o += 256) {
    const float* wr = w1 + (size_t)o * DD;
    float d = 0.f;
    for (int cc = 0; cc < DD; cc += 4) {
      float4 wv = *(const float4*)(wr + cc);
      d += wv.x * xr[cc] + wv.y * xr[cc + 1] + wv.z * xr[cc + 2] + wv.w * xr[cc + 3];
    }
    d += b1[o];
    float ge = 0.5f * d * (1.0f + erff(d * 0.70710678118654752f));
    part += ge * w2[o];
  }
  red[tid] = part;
  __syncthreads();
  for (int s = 128; s > 0; s >>= 1) {
    if (tid < s) red[tid] += red[tid + s];
    __syncthreads();
  }
  if (tid == 0) outp[m] = red[0] + b2[0];
}

// ---------------------------------------------------------------------------
extern "C" void kernel_launch(void* const* d_in, const int* in_sizes, int n_in,
                              void* d_out, int out_size, void* d_ws, size_t ws_size,
                              hipStream_t stream)
{
  const float* x_v    = (const float*)d_in[0];
  const float* fmap   = (const float*)d_in[1];
  const float* pre_w  = (const float*)d_in[2];
  const float* pre_b  = (const float*)d_in[3];
  const float* post_w = (const float*)d_in[4];
  const float* post_b = (const float*)d_in[5];
  const float* tm_W   = (const float*)d_in[6];
  const float* tm_a1  = (const float*)d_in[7];
  const float* tm_a2  = (const float*)d_in[8];
  const float* tm_lw  = (const float*)d_in[9];
  const float* tm_lb  = (const float*)d_in[10];
  const float* tm_g   = (const float*)d_in[11];
  const float* tm_b   = (const float*)d_in[12];
  const float* fm_W   = (const float*)d_in[13];
  const float* fm_a1  = (const float*)d_in[14];
  const float* fm_a2  = (const float*)d_in[15];
  const float* fm_lw  = (const float*)d_in[16];
  const float* fm_lb  = (const float*)d_in[17];
  const float* fm_g   = (const float*)d_in[18];
  const float* fm_b   = (const float*)d_in[19];
  const float* c_w1   = (const float*)d_in[20];
  const float* c_b1   = (const float*)d_in[21];
  const float* c_w2   = (const float*)d_in[22];
  const float* c_b2   = (const float*)d_in[23];
  float* out = (float*)d_out;

  // workspace carve-up (~210 MB, same footprint as before)
  float* wsf    = (float*)d_ws;
  float* ax     = wsf;                           // 25,690,112 f
  short* axb    = (short*)(ax + 25690112);       // 25,690,112 bf16
  short* tmpb   = axb + 25690112;                // 25,690,112 bf16
  float* xtm    = (float*)(tmpb + 25690112);     // 131,072 f
  short* xvb    = (short*)(xtm + 131072);        // 131,072 bf16
  short* tmptmb = xvb + 131072;                  // 131,072 bf16
  short* WTb_fm = tmptmb + 131072;               // 262,144 bf16
  short* WTb_tm = WTb_fm + 262144;               // 262,144 bf16
  short* LWb_fm = WTb_tm + 262144;               // 262,144 bf16
  short* LWb_tm = LWb_fm + 262144;               // 262,144 bf16
  short* pwb_hi = LWb_tm + 262144;               // 393,216 bf16
  short* pwb_lo = pwb_hi + 393216;               // 393,216 bf16
  unsigned long long* sel_fm = (unsigned long long*)(pwb_lo + 393216); // 784
  unsigned long long* sel_tm = sel_fm + 784;                           // 4
  // bf16 fmap quarter-batch staging ALIASES tmpb (tmpb first written at
  // step 4, after all preconv quarters are done).
  short* fmh = tmpb;                             // 9,646,080 shorts
  short* fml = fmh + 9646080;                    // 9,646,080 shorts (< tmpb sz)

  // 1) weight preps + x_v bf16
  k_prepPW<<<1536, 256, 0, stream>>>(pre_w, pwb_hi, pwb_lo);
  k_prepWb<<<1024, 256, 0, stream>>>(fm_W, WTb_fm);
  k_prepWb<<<1024, 256, 0, stream>>>(tm_W, WTb_tm);
  k_prepLWb<<<1024, 256, 0, stream>>>(fm_lw, LWb_fm);
  k_prepLWb<<<1024, 256, 0, stream>>>(tm_lw, LWb_tm);
  k_cvt<<<512, 256, 0, stream>>>(x_v, xvb);

  // 2) pre head conv in four image-quarters: transpose+split, pure-MFMA conv
  for (int qtr = 0; qtr < 4; qtr++) {
    k_prepFM<<<dim3(12, 64), 256, 0, stream>>>(fmap, fmh, fml, qtr * 64);
    k_preconv2<<<512, 256, 0, stream>>>(fmh, fml, pwb_hi, pwb_lo, pre_b, ax, axb, qtr * 64);
  }

  // 3) top-k selection bitmasks (fp64 ranking)
  k_topk<<<NG_FM, 64, 0, stream>>>(ax, sel_fm);
  k_topk<<<4, 64, 0, stream>>>(x_v, sel_tm);

  // 4) h = x @ Wcat  (tiled MFMA GEMM, bf16 out). M=50176 / M=256 flat.
  k_gemm<<<1568, 256, 0, stream>>>(axb, WTb_fm, nullptr, nullptr, nullptr, tmpb, 392, 1);
  k_gemm<<<8, 256, 0, stream>>>(xvb, WTb_tm, nullptr, nullptr, nullptr, tmptmb, 2, 0);

  // 5) fused attention + elu + signed-sqrt + column-normalize (bf16 in-place)
  k_attn<<<dim3(NHEAD, NG_FM), 256, 0, stream>>>(tmpb, fm_a1, fm_a2, sel_fm);
  k_attn<<<dim3(NHEAD, 4), 256, 0, stream>>>(tmptmb, tm_a1, tm_a2, sel_tm);

  // 6) x = x + tmp @ lin_w.T + lin_b  (tiled MFMA GEMM, f32 out w/ residual)
  hipMemcpyAsync(xtm, x_v, (size_t)131072 * 4, hipMemcpyDeviceToDevice, stream);
  k_gemm<<<1568, 256, 0, stream>>>(tmpb, LWb_fm, fm_lb, ax, ax, nullptr, 392, 1);
  k_gemm<<<8, 256, 0, stream>>>(tmptmb, LWb_tm, tm_lb, xtm, xtm, nullptr, 2, 0);

  // 7) layernorm in-place
  k_ln<<<NG_FM * TT, 64, 0, stream>>>(ax, fm_g, fm_b);
  k_ln<<<NIMG, 64, 0, stream>>>(xtm, tm_g, tm_b);

  // 8) post head -> ano_map (d_out offset 256), classifier -> logits
  k_post<<<12544, 256, 0, stream>>>(ax, post_w, post_b, out + 256);
  k_cls<<<NIMG, 256, 0, stream>>>(xtm, c_w1, c_b1, c_w2, c_b2, out);
}

// Round 10
// 849.547 us; speedup vs baseline: 2.3317x; 1.1737x over previous
//
#include <hip/hip_runtime.h>
#include <cstdint>
#include <cstddef>

// Model dims
constexpr int TT   = 64;    // T
constexpr int DD   = 512;   // D
constexpr int NHEAD= 8;
constexpr int DHH  = 64;
constexpr int NPIX = 196;   // 14*14
constexpr int CIN  = 768;
constexpr int KSEL = 44;    // int(0.7*64)
constexpr int NG_FM= 784;   // B*N
constexpr int NIMG = 256;   // B*T
// distance_adj underflow band: exp(-|0.6*d^2+0.2|) in fp32.
// d=12 -> 2.4e-38 (normal). d=13 -> subnormal -> flushed (FTZ). d>=14 -> 0.
constexpr int DBAND = 12;

typedef __attribute__((ext_vector_type(8))) short bf16x8;
typedef __attribute__((ext_vector_type(4))) float f32x4;

__device__ __forceinline__ short bfr(float x) {
  union { float f; unsigned u; } v; v.f = x;
  unsigned r = (v.u + 0x7fffu + ((v.u >> 16) & 1u)) >> 16;   // RNE
  return (short)r;
}
__device__ __forceinline__ float bf2f(short s) {
  return __uint_as_float(((unsigned)(unsigned short)s) << 16);
}

// ---------------------------------------------------------------------------
// prep: pre_w (f32 [o][k], k=768) -> bf16 hi/lo in MFMA FRAGMENT order:
// addr = (((mt*4+ot)*24 + ks)*64 + lg*16 + lr)*8 + j, o=mt*64+ot*16+lr,
// k=ks*32+lg*8+j. Each wave fragment load = contiguous 1KB.
// ---------------------------------------------------------------------------
__global__ void k_prepPW2(const float* __restrict__ pw, short* __restrict__ hi,
                          short* __restrict__ lo)
{
  int m = blockIdx.x * 256 + threadIdx.x;            // < 512*96
  int o = m / 96, kc = m - o * 96;
  int mt = o >> 6, ot = (o >> 4) & 3, lr = o & 15;
  int ks = kc >> 2, lg = kc & 3;
  size_t addr = ((((size_t)(mt * 4 + ot) * 24 + ks) * 64 + lg * 16 + lr)) * 8;
  const float* src = pw + (size_t)o * CIN + kc * 8;
  #pragma unroll
  for (int j = 0; j < 8; j++) {
    float x = src[j];
    unsigned u = __float_as_uint(x);
    hi[addr + j] = (short)(u >> 16);
    lo[addr + j] = bfr(x - __uint_as_float(u & 0xffff0000u));
  }
}

// ---------------------------------------------------------------------------
// prep: fmap [n][c][hw] f32 -> bf16 hi/lo FRAGMENT order (quarter-batch):
// addr = ((((nl*13 + hwt)*24 + ks)*64 + lg*16 + lr)*8 + j,
// hw = hwt*16+lr (0..207, >=196 zero-filled), k = ks*32+lg*8+j.
// ---------------------------------------------------------------------------
__global__ __launch_bounds__(256) void k_prepFM3(
    const float* __restrict__ fmap, short* __restrict__ fh,
    short* __restrict__ fl, int n0)
{
  __shared__ float ar[64][197];                      // pitch 197
  const int cc = blockIdx.x;                         // 12 chunks of 64 ch
  const int nl = blockIdx.y;                         // 0..63
  const int tid = threadIdx.x;
  const float* src = fmap + ((size_t)(n0 + nl) * CIN + cc * 64) * NPIX;
  for (int i = tid; i < 64 * 49; i += 256) {
    int c = i / 49, q = i - c * 49;
    float4 v = *(const float4*)&src[(size_t)c * NPIX + q * 4];
    *(float4*)&ar[c][q * 4] = v;
  }
  __syncthreads();
  for (int i = tid; i < 208 * 8; i += 256) {
    int hw = i >> 3, kc = i & 7;
    int ks = cc * 2 + (kc >> 2), lg = kc & 3;
    size_t addr = ((((size_t)nl * 13 + (hw >> 4)) * 24 + ks) * 64 + lg * 16 + (hw & 15)) * 8;
    union { short s[8]; bf16x8 v; } hh, ll;
    #pragma unroll
    for (int j = 0; j < 8; j++) {
      float x = (hw < NPIX) ? ar[kc * 8 + j][hw] : 0.f;
      unsigned u = __float_as_uint(x);
      hh.s[j] = (short)(u >> 16);
      ll.s[j] = bfr(x - __uint_as_float(u & 0xffff0000u));
    }
    *(bf16x8*)&fh[addr] = hh.v;
    *(bf16x8*)&fl[addr] = ll.v;
  }
}

// ---------------------------------------------------------------------------
// K1: pre head 1x1 conv (768->512) + bias + ReLU via split-bf16 MFMA.
// ALL operands pre-arranged in fragment order -> every load is a coalesced
// 1KB wave burst from L2; no LDS/barriers in main loop.
// Writes fp32 ax (top-k/residual/LN) AND bf16 axb (GEMM A-operand).
// ---------------------------------------------------------------------------
__global__ __launch_bounds__(256) void k_preconv3(
    const short* __restrict__ fmfh, const short* __restrict__ fmfl,
    const short* __restrict__ pwfh, const short* __restrict__ pwfl,
    const float* __restrict__ pb, float* __restrict__ ax,
    short* __restrict__ axb, int n0)
{
  __shared__ float arena[7616];                      // epilogue only
  const int wg = blockIdx.x;                         // 512 (64 imgs)
  const int mt = (wg >> 3) & 7;                      // o-chunk
  const int nl = (wg & 7) | ((wg >> 6) << 3);        // local image (XCD-group)
  const int n  = n0 + nl;
  const int b  = n >> 6, t = n & 63;
  const int tid = threadIdx.x;
  const int w = tid >> 6, l = tid & 63;
  const int lr = l & 15, lg = l >> 4;
  const int o0 = mt * 64;

  const int hwt0 = (w == 0) ? 0 : 1 + 3 * w;         // waves: 4,3,3,3 hw-tiles
  const int nq   = (w == 0) ? 4 : 3;

  f32x4 acc[4][4];                                   // [q][ot]
  #pragma unroll
  for (int q = 0; q < 4; q++)
    #pragma unroll
    for (int ot = 0; ot < 4; ot++) acc[q][ot] = (f32x4){0.f, 0.f, 0.f, 0.f};

  for (int ks = 0; ks < 24; ks++) {
    bf16x8 Ah[4], Al[4];
    #pragma unroll
    for (int ot = 0; ot < 4; ot++) {
      size_t off = (((size_t)(mt * 4 + ot) * 24 + ks) * 64 + l) * 8;
      Ah[ot] = *(const bf16x8*)&pwfh[off];
      Al[ot] = *(const bf16x8*)&pwfl[off];
    }
    #pragma unroll
    for (int q = 0; q < 4; q++) if (q < nq) {
      size_t boff = ((((size_t)nl * 13 + hwt0 + q) * 24 + ks) * 64 + l) * 8;
      bf16x8 Bh = *(const bf16x8*)&fmfh[boff];
      bf16x8 Bl = *(const bf16x8*)&fmfl[boff];
      #pragma unroll
      for (int ot = 0; ot < 4; ot++) {
        acc[q][ot] = __builtin_amdgcn_mfma_f32_16x16x32_bf16(Al[ot], Bh, acc[q][ot], 0, 0, 0);
        acc[q][ot] = __builtin_amdgcn_mfma_f32_16x16x32_bf16(Ah[ot], Bl, acc[q][ot], 0, 0, 0);
        acc[q][ot] = __builtin_amdgcn_mfma_f32_16x16x32_bf16(Ah[ot], Bh, acc[q][ot], 0, 0, 0);
      }
    }
  }

  // epilogue: bias + relu, reorder via skewed LDS, coalesced 64-float rows
  float4 pbf[4];
  #pragma unroll
  for (int ot = 0; ot < 4; ot++)
    pbf[ot] = *(const float4*)&pb[o0 + ot * 16 + 4 * lg];

  #pragma unroll
  for (int pass = 0; pass < 2; pass++) {
    const int tbase = pass ? 7 : 0;
    const int tend  = pass ? 13 : 7;
    const int rbase = tbase * 16;
    const int rows  = (tend - tbase) * 16;
    __syncthreads();
    #pragma unroll
    for (int q = 0; q < 4; q++) if (q < nq) {
      int hwt = hwt0 + q;
      if (hwt >= tbase && hwt < tend) {
        int row_l = hwt * 16 + lr - rbase;
        #pragma unroll
        for (int ot = 0; ot < 4; ot++) {
          int col = (ot * 16 + 4 * lg + 4 * row_l) % 68;   // skew: conflict-free
          f32x4 a = acc[q][ot];
          float4 o4v;
          o4v.x = fmaxf(a[0] + pbf[ot].x, 0.f);
          o4v.y = fmaxf(a[1] + pbf[ot].y, 0.f);
          o4v.z = fmaxf(a[2] + pbf[ot].z, 0.f);
          o4v.w = fmaxf(a[3] + pbf[ot].w, 0.f);
          *(float4*)&arena[row_l * 68 + col] = o4v;
        }
      }
    }
    __syncthreads();
    for (int i = tid; i < rows * 16; i += 256) {
      int row_l = i >> 4, o4 = i & 15;
      int hw = rbase + row_l;
      if (hw < NPIX) {
        int col = (o4 * 4 + 4 * row_l) % 68;
        float4 v = *(const float4*)&arena[row_l * 68 + col];
        size_t idx = ((size_t)(b * NPIX + hw) * TT + t) * DD + o0 + o4 * 4;
        *(float4*)&ax[idx] = v;
        *(short4*)&axb[idx] = make_short4(bfr(v.x), bfr(v.y), bfr(v.z), bfr(v.w));
      }
    }
  }
}

// ---------------------------------------------------------------------------
// GEMM B-operand preps -> bf16 FRAGMENT order:
// addr = (((j>>4)*16 + ks)*64 + lg*16 + (j&15))*8 + jj,  j=N-col, k=ks*32+lg*8+jj.
// ---------------------------------------------------------------------------
__global__ void k_prepWb2(const float* __restrict__ W, short* __restrict__ o)
{
  int m = blockIdx.x * 256 + threadIdx.x;            // < 512*64
  int j = m >> 6, kc = m & 63;
  int ks = kc >> 2, lg = kc & 3;
  size_t addr = (((size_t)(j >> 4) * 16 + ks) * 64 + lg * 16 + (j & 15)) * 8;
  #pragma unroll
  for (int jj = 0; jj < 8; jj++) {
    int k = kc * 8 + jj;
    o[addr + jj] = bfr(W[(size_t)(j >> 6) * (DD * DHH) + (size_t)k * DHH + (j & 63)]);
  }
}

__global__ void k_prepLWb2(const float* __restrict__ a, short* __restrict__ o)
{
  int m = blockIdx.x * 256 + threadIdx.x;            // < 512*64
  int j = m >> 6, kc = m & 63;
  int ks = kc >> 2, lg = kc & 3;
  size_t addr = (((size_t)(j >> 4) * 16 + ks) * 64 + lg * 16 + (j & 15)) * 8;
  const float* src = a + (size_t)j * DD + kc * 8;
  #pragma unroll
  for (int jj = 0; jj < 8; jj++) o[addr + jj] = bfr(src[jj]);
}

__global__ void k_cvt(const float* __restrict__ a, short* __restrict__ o)
{
  int m = blockIdx.x * 256 + threadIdx.x;
  o[m] = bfr(a[m]);
}

// ---------------------------------------------------------------------------
// K2: per-graph top-k selection bitmask (fp64 squared-norm ranking).
// ---------------------------------------------------------------------------
__global__ void k_topk(const float* __restrict__ x, unsigned long long* __restrict__ sel)
{
  int g = blockIdx.x, lane = threadIdx.x;            // 64 threads
  const float* row = x + ((size_t)g * TT + lane) * DD;
  double s = 0.0;
  for (int dd = 0; dd < DD; dd += 4) {
    float4 v = *(const float4*)(row + dd);
    s += (double)v.x * (double)v.x + (double)v.y * (double)v.y
       + (double)v.z * (double)v.z + (double)v.w * (double)v.w;
  }
  __shared__ double mag[64];
  mag[lane] = s;
  __syncthreads();
  int rank = 0;
  for (int j = 0; j < 64; j++) {
    double m = mag[j];
    rank += (m > s) || (m == s && j < lane);
  }
  unsigned long long bal = __ballot(rank < KSEL);
  if (lane == 0) sel[g] = bal;
}

// ---------------------------------------------------------------------------
// K3a/K4: flat GEMM  Out[M x 512] = Ab[M x 512](bf16) @ B (fragment-ordered
// bf16). A through LDS (pad-80B rows: ds_read 2-way max), B direct coalesced
// fragment loads from L2. 128x128 tile, BK=32, double-buffer, 1 barrier/step.
// ---------------------------------------------------------------------------
__global__ __launch_bounds__(256) void k_gemm(
    const short* __restrict__ Ab, const short* __restrict__ Bbf,
    const float* __restrict__ bias, const float* __restrict__ Res,
    float* __restrict__ Outf, short* __restrict__ Outb,
    int Mtiles, int swz)
{
  __shared__ short Asl[2][128 * 40];                 // 80B rows: conflict-free
  const int wg = blockIdx.x;
  int mt, nt;
  if (swz) { int xcd = wg & 7, idx = wg >> 3; mt = xcd * (Mtiles >> 3) + (idx >> 2); nt = idx & 3; }
  else     { mt = wg >> 2; nt = wg & 3; }
  const int m0 = mt * 128, n0 = nt * 128;
  const int tid = threadIdx.x;
  const int l  = tid & 63;
  const int lr = l & 15, lg = l >> 4;
  const int wm = (tid >> 7) & 1, wn = (tid >> 6) & 1;   // wave quadrant

  const int srow = tid >> 1, skq = tid & 1;
  const short* gA = Ab + (size_t)(m0 + srow) * DD + skq * 16;
  const int soff = srow * 40 + skq * 16;

  bf16x8 ra0 = *(const bf16x8*)(gA);
  bf16x8 ra1 = *(const bf16x8*)(gA + 8);
  *(bf16x8*)&Asl[0][soff]     = ra0;
  *(bf16x8*)&Asl[0][soff + 8] = ra1;
  __syncthreads();

  f32x4 acc[4][4] = {};
  for (int ks = 0; ks < 16; ks++) {
    const int cur = ks & 1;
    if (ks < 15) {                                   // issue next A-tile loads
      const int k0 = (ks + 1) * 32;
      ra0 = *(const bf16x8*)(gA + k0);
      ra1 = *(const bf16x8*)(gA + k0 + 8);
    }
    bf16x8 af[4], bfv[4];
    #pragma unroll
    for (int mi = 0; mi < 4; mi++)
      af[mi] = *(const bf16x8*)&Asl[cur][(wm * 64 + mi * 16 + lr) * 40 + lg * 8];
    #pragma unroll
    for (int ni = 0; ni < 4; ni++) {
      size_t boff = (((size_t)(nt * 8 + wn * 4 + ni) * 16 + ks) * 64 + l) * 8;
      bfv[ni] = *(const bf16x8*)&Bbf[boff];
    }
    #pragma unroll
    for (int mi = 0; mi < 4; mi++)
      #pragma unroll
      for (int ni = 0; ni < 4; ni++)
        acc[mi][ni] = __builtin_amdgcn_mfma_f32_16x16x32_bf16(af[mi], bfv[ni], acc[mi][ni], 0, 0, 0);
    if (ks < 15) {
      *(bf16x8*)&Asl[cur ^ 1][soff]     = ra0;
      *(bf16x8*)&Asl[cur ^ 1][soff + 8] = ra1;
      __syncthreads();
    }
  }

  // epilogue (C/D layout: col = lr, row = lg*4 + r, validated)
  #pragma unroll
  for (int mi = 0; mi < 4; mi++) {
    #pragma unroll
    for (int r = 0; r < 4; r++) {
      const size_t row = (size_t)(m0 + wm * 64 + mi * 16 + lg * 4 + r);
      #pragma unroll
      for (int ni = 0; ni < 4; ni++) {
        const int col = n0 + wn * 64 + ni * 16 + lr;
        float v = acc[mi][ni][r];
        if (bias) v += bias[col];
        if (Res)  v += Res[row * DD + col];
        if (Outf) Outf[row * DD + col] = v;
        if (Outb) Outb[row * DD + col] = bfr(v);
      }
    }
  }
}

// ---------------------------------------------------------------------------
// K3b: fused GAT attention per (head, graph); h in bf16, in-place.
// ---------------------------------------------------------------------------
__global__ __launch_bounds__(256) void k_attn(
    short* __restrict__ tmp, const float* __restrict__ a1v,
    const float* __restrict__ a2v, const unsigned long long* __restrict__ sel)
{
  __shared__ float hs[64][68];
  __shared__ float attnv[64][68];
  __shared__ float s1[64], s2[64], aw[128], cnorm[64];
  const int h = blockIdx.x, g = blockIdx.y;
  const int tid = threadIdx.x;
  const int r = tid >> 4, c = tid & 15;
  short* base = tmp + (size_t)g * TT * DD + h * DHH;

  for (int i = tid; i < 4096; i += 256) {
    int t = i >> 6, dh = i & 63;
    hs[t][dh] = bf2f(base[(size_t)t * DD + dh]);
  }
  if (tid < 128) aw[tid] = (tid < 64) ? a1v[h * 64 + tid] : a2v[h * 64 + (tid - 64)];
  __syncthreads();

  if (tid < 64) {
    float v1 = 0.f, v2 = 0.f;
    for (int dh = 0; dh < 64; dh++) { float hv = hs[tid][dh]; v1 += hv * aw[dh]; v2 += hv * aw[64 + dh]; }
    s1[tid] = v1; s2[tid] = v2;
  }
  __syncthreads();

  const unsigned long long sm = sel[g];
  if (tid < 64) {
    const int i = tid;
    const bool seli = (sm >> i) & 1ULL;
    const float vi = s1[i];
    float mx = -1e30f;
    for (int j = 0; j < 64; j++) {
      float e = vi + s2[j];
      e = e >= 0.f ? e : 0.2f * e;                   // leaky_relu(0.2)
      int dist = i > j ? i - j : j - i;
      bool ok = (seli || ((sm >> j) & 1ULL)) && (dist <= DBAND);
      e = ok ? e : -9e15f;
      attnv[i][j] = e;
      mx = fmaxf(mx, e);
    }
    float sum = 0.f;
    for (int j = 0; j < 64; j++) { float p = expf(attnv[i][j] - mx); attnv[i][j] = p; sum += p; }
    float inv = 1.f / sum;
    for (int j = 0; j < 64; j++) attnv[i][j] *= inv;
  }
  __syncthreads();

  float oc[4][4];
  #pragma unroll
  for (int i = 0; i < 4; i++)
    #pragma unroll
    for (int j = 0; j < 4; j++) oc[i][j] = 0.f;
  for (int j = 0; j < 64; j++) {
    float p[4];
    #pragma unroll
    for (int di = 0; di < 4; di++) p[di] = attnv[r * 4 + di][j];
    float4 hv = *(const float4*)&hs[j][c * 4];
    float hb[4] = {hv.x, hv.y, hv.z, hv.w};
    #pragma unroll
    for (int di = 0; di < 4; di++)
      #pragma unroll
      for (int dj = 0; dj < 4; dj++)
        oc[di][dj] += p[di] * hb[dj];
  }

  float cs4[4] = {0.f, 0.f, 0.f, 0.f};
  #pragma unroll
  for (int di = 0; di < 4; di++)
    #pragma unroll
    for (int dj = 0; dj < 4; dj++) {
      float v = oc[di][dj];
      v = v > 0.f ? v : expm1f(v);
      v = v >= 0.f ? sqrtf(v) : -sqrtf(-v);
      oc[di][dj] = v;
      cs4[dj] += v * v;
    }
  __syncthreads();
  *(float4*)&attnv[r][c * 4] = make_float4(cs4[0], cs4[1], cs4[2], cs4[3]);
  __syncthreads();
  if (tid < 64) {
    float ssum = 0.f;
    for (int rr = 0; rr < 16; rr++) ssum += attnv[rr][tid];
    cnorm[tid] = fmaxf(sqrtf(ssum), 1e-12f);
  }
  __syncthreads();
  float4 cn = *(const float4*)&cnorm[c * 4];
  float inv4[4] = {1.f / cn.x, 1.f / cn.y, 1.f / cn.z, 1.f / cn.w};
  #pragma unroll
  for (int di = 0; di < 4; di++) {
    short4 s4 = make_short4(bfr(oc[di][0] * inv4[0]), bfr(oc[di][1] * inv4[1]),
                            bfr(oc[di][2] * inv4[2]), bfr(oc[di][3] * inv4[3]));
    *(short4*)&base[(size_t)(r * 4 + di) * DD + c * 4] = s4;
  }
}

// ---------------------------------------------------------------------------
// K5: LayerNorm in-place, one wave per 512-row.
// ---------------------------------------------------------------------------
__global__ void k_ln(float* __restrict__ x, const float* __restrict__ gam, const float* __restrict__ bet)
{
  const size_t row = blockIdx.x;
  const int lane = threadIdx.x;
  float* p = x + row * DD + lane * 8;
  float4 v0 = *(float4*)p;
  float4 v1 = *(float4*)(p + 4);
  float va[8] = {v0.x, v0.y, v0.z, v0.w, v1.x, v1.y, v1.z, v1.w};
  float s = 0.f;
  #pragma unroll
  for (int i = 0; i < 8; i++) s += va[i];
  #pragma unroll
  for (int m = 32; m >= 1; m >>= 1) s += __shfl_xor(s, m);
  float mean = s * (1.f / 512.f);
  float q = 0.f;
  #pragma unroll
  for (int i = 0; i < 8; i++) { float d = va[i] - mean; q += d * d; }
  #pragma unroll
  for (int m = 32; m >= 1; m >>= 1) q += __shfl_xor(q, m);
  float rstd = rsqrtf(q * (1.f / 512.f) + 1e-5f);
  const float* gp = gam + lane * 8;
  const float* bp = bet + lane * 8;
  float4 g0 = *(const float4*)gp, g1 = *(const float4*)(gp + 4);
  float4 b0 = *(const float4*)bp, b1 = *(const float4*)(bp + 4);
  float ga[8] = {g0.x, g0.y, g0.z, g0.w, g1.x, g1.y, g1.z, g1.w};
  float ba[8] = {b0.x, b0.y, b0.z, b0.w, b1.x, b1.y, b1.z, b1.w};
  float o[8];
  #pragma unroll
  for (int i = 0; i < 8; i++) o[i] = (va[i] - mean) * rstd * ga[i] + ba[i];
  *(float4*)p       = make_float4(o[0], o[1], o[2], o[3]);
  *(float4*)(p + 4) = make_float4(o[4], o[5], o[6], o[7]);
}

// ---------------------------------------------------------------------------
// K6: post head 1x1 conv (512->1): one wave per (b,t,hw) output.
// ---------------------------------------------------------------------------
__global__ void k_post(const float* __restrict__ y, const float* __restrict__ pw,
                       const float* __restrict__ pb, float* __restrict__ outp)
{
  int m = blockIdx.x * 4 + (threadIdx.x >> 6);
  int lane = threadIdx.x & 63;
  int b = m / 12544;
  int rem = m - b * 12544;
  int t = rem / 196;
  int hw = rem - t * 196;
  const float* row = y + ((size_t)(b * NPIX + hw) * TT + t) * DD + lane * 8;
  float4 a0 = *(const float4*)row, a1 = *(const float4*)(row + 4);
  float4 w0 = *(const float4*)(pw + lane * 8), w1 = *(const float4*)(pw + lane * 8 + 4);
  float s = a0.x * w0.x + a0.y * w0.y + a0.z * w0.z + a0.w * w0.w
          + a1.x * w1.x + a1.y * w1.y + a1.z * w1.z + a1.w * w1.w;
  #pragma unroll
  for (int mm = 32; mm >= 1; mm >>= 1) s += __shfl_xor(s, mm);
  if (lane == 0) outp[m] = s + pb[0];
}

// ---------------------------------------------------------------------------
// K7: classifier Conv1d(512->512)+GELU(exact)+Conv1d(512->1), one block per (b,t).
// ---------------------------------------------------------------------------
__global__ __launch_bounds__(256) void k_cls(
    const float* __restrict__ xv, const float* __restrict__ w1,
    const float* __restrict__ b1, const float* __restrict__ w2,
    const float* __restrict__ b2, float* __restrict__ outp)
{
  const int m = blockIdx.x;                          // b*64+t
  const int tid = threadIdx.x;
  __shared__ float xr[512];
  __shared__ float red[256];
  xr[tid] = xv[(size_t)m * DD + tid];
  xr[tid + 256] = xv[(size_t)m * DD + tid + 256];
  __syncthreads();
  float part = 0.f;
  for (int o = tid; o < 512; o += 256) {
    const float* wr = w1 + (size_t)o * DD;
    float d = 0.f;
    for (int cc = 0; cc < DD; cc += 4) {
      float4 wv = *(const float4*)(wr + cc);
      d += wv.x * xr[cc] + wv.y * xr[cc + 1] + wv.z * xr[cc + 2] + wv.w * xr[cc + 3];
    }
    d += b1[o];
    float ge = 0.5f * d * (1.0f + erff(d * 0.70710678118654752f));
    part += ge * w2[o];
  }
  red[tid] = part;
  __syncthreads();
  for (int s = 128; s > 0; s >>= 1) {
    if (tid < s) red[tid] += red[tid + s];
    __syncthreads();
  }
  if (tid == 0) outp[m] = red[0] + b2[0];
}

// ---------------------------------------------------------------------------
extern "C" void kernel_launch(void* const* d_in, const int* in_sizes, int n_in,
                              void* d_out, int out_size, void* d_ws, size_t ws_size,
                              hipStream_t stream)
{
  const float* x_v    = (const float*)d_in[0];
  const float* fmap   = (const float*)d_in[1];
  const float* pre_w  = (const float*)d_in[2];
  const float* pre_b  = (const float*)d_in[3];
  const float* post_w = (const float*)d_in[4];
  const float* post_b = (const float*)d_in[5];
  const float* tm_W   = (const float*)d_in[6];
  const float* tm_a1  = (const float*)d_in[7];
  const float* tm_a2  = (const float*)d_in[8];
  const float* tm_lw  = (const float*)d_in[9];
  const float* tm_lb  = (const float*)d_in[10];
  const float* tm_g   = (const float*)d_in[11];
  const float* tm_b   = (const float*)d_in[12];
  const float* fm_W   = (const float*)d_in[13];
  const float* fm_a1  = (const float*)d_in[14];
  const float* fm_a2  = (const float*)d_in[15];
  const float* fm_lw  = (const float*)d_in[16];
  const float* fm_lb  = (const float*)d_in[17];
  const float* fm_g   = (const float*)d_in[18];
  const float* fm_b   = (const float*)d_in[19];
  const float* c_w1   = (const float*)d_in[20];
  const float* c_b1   = (const float*)d_in[21];
  const float* c_w2   = (const float*)d_in[22];
  const float* c_b2   = (const float*)d_in[23];
  float* out = (float*)d_out;

  // workspace carve-up (~210 MB)
  float* wsf    = (float*)d_ws;
  float* ax     = wsf;                           // 25,690,112 f
  short* axb    = (short*)(ax + 25690112);       // 25,690,112 bf16
  short* tmpb   = axb + 25690112;                // 25,690,112 bf16
  float* xtm    = (float*)(tmpb + 25690112);     // 131,072 f
  short* xvb    = (short*)(xtm + 131072);        // 131,072 bf16
  short* tmptmb = xvb + 131072;                  // 131,072 bf16
  short* WTb_fm = tmptmb + 131072;               // 262,144 bf16 (fragment order)
  short* WTb_tm = WTb_fm + 262144;               // 262,144 bf16
  short* LWb_fm = WTb_tm + 262144;               // 262,144 bf16
  short* LWb_tm = LWb_fm + 262144;               // 262,144 bf16
  short* pwf_hi = LWb_tm + 262144;               // 393,216 bf16 (fragment order)
  short* pwf_lo = pwf_hi + 393216;               // 393,216 bf16
  unsigned long long* sel_fm = (unsigned long long*)(pwf_lo + 393216); // 784
  unsigned long long* sel_tm = sel_fm + 784;                           // 4
  // fm fragment quarter-batch staging ALIASES tmpb (tmpb first written at
  // step 4). Per quarter: 64 imgs * 13*24*64*8 = 10,223,616 shorts each.
  short* fmh = tmpb;                             // 10,223,616 shorts
  short* fml = fmh + 10223616;                   // 10,223,616 shorts (< tmpb)

  // 1) weight preps (fragment order) + x_v bf16
  k_prepPW2<<<192, 256, 0, stream>>>(pre_w, pwf_hi, pwf_lo);
  k_prepWb2<<<128, 256, 0, stream>>>(fm_W, WTb_fm);
  k_prepWb2<<<128, 256, 0, stream>>>(tm_W, WTb_tm);
  k_prepLWb2<<<128, 256, 0, stream>>>(fm_lw, LWb_fm);
  k_prepLWb2<<<128, 256, 0, stream>>>(tm_lw, LWb_tm);
  k_cvt<<<512, 256, 0, stream>>>(x_v, xvb);

  // 2) pre head conv in four image-quarters: fragment-prep, pure-MFMA conv
  for (int qtr = 0; qtr < 4; qtr++) {
    k_prepFM3<<<dim3(12, 64), 256, 0, stream>>>(fmap, fmh, fml, qtr * 64);
    k_preconv3<<<512, 256, 0, stream>>>(fmh, fml, pwf_hi, pwf_lo, pre_b, ax, axb, qtr * 64);
  }

  // 3) top-k selection bitmasks (fp64 ranking)
  k_topk<<<NG_FM, 64, 0, stream>>>(ax, sel_fm);
  k_topk<<<4, 64, 0, stream>>>(x_v, sel_tm);

  // 4) h = x @ Wcat  (tiled MFMA GEMM, bf16 out)
  k_gemm<<<1568, 256, 0, stream>>>(axb, WTb_fm, nullptr, nullptr, nullptr, tmpb, 392, 1);
  k_gemm<<<8, 256, 0, stream>>>(xvb, WTb_tm, nullptr, nullptr, nullptr, tmptmb, 2, 0);

  // 5) fused attention + elu + signed-sqrt + column-normalize (bf16 in-place)
  k_attn<<<dim3(NHEAD, NG_FM), 256, 0, stream>>>(tmpb, fm_a1, fm_a2, sel_fm);
  k_attn<<<dim3(NHEAD, 4), 256, 0, stream>>>(tmptmb, tm_a1, tm_a2, sel_tm);

  // 6) x = x + tmp @ lin_w.T + lin_b  (tiled MFMA GEMM, f32 out w/ residual)
  hipMemcpyAsync(xtm, x_v, (size_t)131072 * 4, hipMemcpyDeviceToDevice, stream);
  k_gemm<<<1568, 256, 0, stream>>>(tmpb, LWb_fm, fm_lb, ax, ax, nullptr, 392, 1);
  k_gemm<<<8, 256, 0, stream>>>(tmptmb, LWb_tm, tm_lb, xtm, xtm, nullptr, 2, 0);

  // 7) layernorm in-place
  k_ln<<<NG_FM * TT, 64, 0, stream>>>(ax, fm_g, fm_b);
  k_ln<<<NIMG, 64, 0, stream>>>(xtm, tm_g, tm_b);

  // 8) post head -> ano_map (d_out offset 256), classifier -> logits
  k_post<<<12544, 256, 0, stream>>>(ax, post_w, post_b, out + 256);
  k_cls<<<NIMG, 256, 0, stream>>>(xtm, c_w1, c_b1, c_w2, c_b2, out);
}

// Round 11
// 834.420 us; speedup vs baseline: 2.3740x; 1.0181x over previous
//
#include <hip/hip_runtime.h>
#include <cstdint>
#include <cstddef>

// Model dims
constexpr int TT   = 64;    // T
constexpr int DD   = 512;   // D
constexpr int NHEAD= 8;
constexpr int DHH  = 64;
constexpr int NPIX = 196;   // 14*14
constexpr int CIN  = 768;
constexpr int KSEL = 44;    // int(0.7*64)
constexpr int NG_FM= 784;   // B*N
constexpr int NIMG = 256;   // B*T
// distance_adj underflow band: exp(-|0.6*d^2+0.2|) in fp32.
// d=12 -> 2.4e-38 (normal). d=13 -> subnormal -> flushed (FTZ). d>=14 -> 0.
constexpr int DBAND = 12;

typedef __attribute__((ext_vector_type(8))) short bf16x8;
typedef __attribute__((ext_vector_type(4))) float f32x4;

__device__ __forceinline__ short bfr(float x) {
  union { float f; unsigned u; } v; v.f = x;
  unsigned r = (v.u + 0x7fffu + ((v.u >> 16) & 1u)) >> 16;   // RNE
  return (short)r;
}
__device__ __forceinline__ float bf2f(short s) {
  return __uint_as_float(((unsigned)(unsigned short)s) << 16);
}

// ---------------------------------------------------------------------------
// prep: pre_w (f32 [o][k], k=768) -> bf16 hi/lo in MFMA FRAGMENT order.
// ---------------------------------------------------------------------------
__global__ void k_prepPW2(const float* __restrict__ pw, short* __restrict__ hi,
                          short* __restrict__ lo)
{
  int m = blockIdx.x * 256 + threadIdx.x;            // < 512*96
  int o = m / 96, kc = m - o * 96;
  int mt = o >> 6, ot = (o >> 4) & 3, lr = o & 15;
  int ks = kc >> 2, lg = kc & 3;
  size_t addr = ((((size_t)(mt * 4 + ot) * 24 + ks) * 64 + lg * 16 + lr)) * 8;
  const float* src = pw + (size_t)o * CIN + kc * 8;
  #pragma unroll
  for (int j = 0; j < 8; j++) {
    float x = src[j];
    unsigned u = __float_as_uint(x);
    hi[addr + j] = (short)(u >> 16);
    lo[addr + j] = bfr(x - __uint_as_float(u & 0xffff0000u));
  }
}

// ---------------------------------------------------------------------------
// prep: fmap [n][c][hw] f32 -> bf16 hi/lo FRAGMENT order (quarter-batch).
// ---------------------------------------------------------------------------
__global__ __launch_bounds__(256) void k_prepFM3(
    const float* __restrict__ fmap, short* __restrict__ fh,
    short* __restrict__ fl, int n0)
{
  __shared__ float ar[64][197];                      // pitch 197
  const int cc = blockIdx.x;                         // 12 chunks of 64 ch
  const int nl = blockIdx.y;                         // 0..63
  const int tid = threadIdx.x;
  const float* src = fmap + ((size_t)(n0 + nl) * CIN + cc * 64) * NPIX;
  for (int i = tid; i < 64 * 49; i += 256) {
    int c = i / 49, q = i - c * 49;
    float4 v = *(const float4*)&src[(size_t)c * NPIX + q * 4];
    *(float4*)&ar[c][q * 4] = v;
  }
  __syncthreads();
  for (int i = tid; i < 208 * 8; i += 256) {
    int hw = i >> 3, kc = i & 7;
    int ks = cc * 2 + (kc >> 2), lg = kc & 3;
    size_t addr = ((((size_t)nl * 13 + (hw >> 4)) * 24 + ks) * 64 + lg * 16 + (hw & 15)) * 8;
    union { short s[8]; bf16x8 v; } hh, ll;
    #pragma unroll
    for (int j = 0; j < 8; j++) {
      float x = (hw < NPIX) ? ar[kc * 8 + j][hw] : 0.f;
      unsigned u = __float_as_uint(x);
      hh.s[j] = (short)(u >> 16);
      ll.s[j] = bfr(x - __uint_as_float(u & 0xffff0000u));
    }
    *(bf16x8*)&fh[addr] = hh.v;
    *(bf16x8*)&fl[addr] = ll.v;
  }
}

// ---------------------------------------------------------------------------
// K1: pre head 1x1 conv (768->512) + bias + ReLU via split-bf16 MFMA.
// Fragment-ordered operands: every load is a coalesced 1KB wave burst.
// Writes fp32 ax + bf16 axb, and f64 per-(g,t) squared-norm partials (atomic)
// for the top-k ranking (removes the 103MB topk read pass).
// ---------------------------------------------------------------------------
__global__ __launch_bounds__(256) void k_preconv3(
    const short* __restrict__ fmfh, const short* __restrict__ fmfl,
    const short* __restrict__ pwfh, const short* __restrict__ pwfl,
    const float* __restrict__ pb, float* __restrict__ ax,
    short* __restrict__ axb, double* __restrict__ sums, int n0)
{
  __shared__ float arena[7616];                      // epilogue only
  const int wg = blockIdx.x;                         // 512 (64 imgs)
  const int mt = (wg >> 3) & 7;                      // o-chunk
  const int nl = (wg & 7) | ((wg >> 6) << 3);        // local image (XCD-group)
  const int n  = n0 + nl;
  const int b  = n >> 6, t = n & 63;
  const int tid = threadIdx.x;
  const int w = tid >> 6, l = tid & 63;
  const int lr = l & 15, lg = l >> 4;
  const int o0 = mt * 64;

  const int hwt0 = (w == 0) ? 0 : 1 + 3 * w;         // waves: 4,3,3,3 hw-tiles
  const int nq   = (w == 0) ? 4 : 3;

  f32x4 acc[4][4];                                   // [q][ot]
  #pragma unroll
  for (int q = 0; q < 4; q++)
    #pragma unroll
    for (int ot = 0; ot < 4; ot++) acc[q][ot] = (f32x4){0.f, 0.f, 0.f, 0.f};

  for (int ks = 0; ks < 24; ks++) {
    bf16x8 Ah[4], Al[4];
    #pragma unroll
    for (int ot = 0; ot < 4; ot++) {
      size_t off = (((size_t)(mt * 4 + ot) * 24 + ks) * 64 + l) * 8;
      Ah[ot] = *(const bf16x8*)&pwfh[off];
      Al[ot] = *(const bf16x8*)&pwfl[off];
    }
    #pragma unroll
    for (int q = 0; q < 4; q++) if (q < nq) {
      size_t boff = ((((size_t)nl * 13 + hwt0 + q) * 24 + ks) * 64 + l) * 8;
      bf16x8 Bh = *(const bf16x8*)&fmfh[boff];
      bf16x8 Bl = *(const bf16x8*)&fmfl[boff];
      #pragma unroll
      for (int ot = 0; ot < 4; ot++) {
        acc[q][ot] = __builtin_amdgcn_mfma_f32_16x16x32_bf16(Al[ot], Bh, acc[q][ot], 0, 0, 0);
        acc[q][ot] = __builtin_amdgcn_mfma_f32_16x16x32_bf16(Ah[ot], Bl, acc[q][ot], 0, 0, 0);
        acc[q][ot] = __builtin_amdgcn_mfma_f32_16x16x32_bf16(Ah[ot], Bh, acc[q][ot], 0, 0, 0);
      }
    }
  }

  // epilogue: bias + relu, reorder via skewed LDS, coalesced stores + f64 norms
  float4 pbf[4];
  #pragma unroll
  for (int ot = 0; ot < 4; ot++)
    pbf[ot] = *(const float4*)&pb[o0 + ot * 16 + 4 * lg];

  #pragma unroll
  for (int pass = 0; pass < 2; pass++) {
    const int tbase = pass ? 7 : 0;
    const int tend  = pass ? 13 : 7;
    const int rbase = tbase * 16;
    const int rows  = (tend - tbase) * 16;
    __syncthreads();
    #pragma unroll
    for (int q = 0; q < 4; q++) if (q < nq) {
      int hwt = hwt0 + q;
      if (hwt >= tbase && hwt < tend) {
        int row_l = hwt * 16 + lr - rbase;
        #pragma unroll
        for (int ot = 0; ot < 4; ot++) {
          int col = (ot * 16 + 4 * lg + 4 * row_l) % 68;   // skew: conflict-free
          f32x4 a = acc[q][ot];
          float4 o4v;
          o4v.x = fmaxf(a[0] + pbf[ot].x, 0.f);
          o4v.y = fmaxf(a[1] + pbf[ot].y, 0.f);
          o4v.z = fmaxf(a[2] + pbf[ot].z, 0.f);
          o4v.w = fmaxf(a[3] + pbf[ot].w, 0.f);
          *(float4*)&arena[row_l * 68 + col] = o4v;
        }
      }
    }
    __syncthreads();
    for (int i = tid; i < rows * 16; i += 256) {      // trip uniform: rows*16 % 256 == 0
      int row_l = i >> 4, o4 = i & 15;
      int hw = rbase + row_l;
      float4 v = make_float4(0.f, 0.f, 0.f, 0.f);
      if (hw < NPIX) {
        int col = (o4 * 4 + 4 * row_l) % 68;
        v = *(const float4*)&arena[row_l * 68 + col];
        size_t idx = ((size_t)(b * NPIX + hw) * TT + t) * DD + o0 + o4 * 4;
        *(float4*)&ax[idx] = v;
        *(short4*)&axb[idx] = make_short4(bfr(v.x), bfr(v.y), bfr(v.z), bfr(v.w));
      }
      // f64 partial squared-norm over this 64-o chunk (16 lanes share hw)
      double vs = (double)v.x * v.x + (double)v.y * v.y
                + (double)v.z * v.z + (double)v.w * v.w;
      vs += __shfl_xor(vs, 1); vs += __shfl_xor(vs, 2);
      vs += __shfl_xor(vs, 4); vs += __shfl_xor(vs, 8);
      if ((i & 15) == 0 && hw < NPIX)
        atomicAdd(&sums[(size_t)(b * NPIX + hw) * TT + t], vs);
    }
  }
}

// ---------------------------------------------------------------------------
// GEMM B-operand preps -> bf16 FRAGMENT order.
// ---------------------------------------------------------------------------
__global__ void k_prepWb2(const float* __restrict__ W, short* __restrict__ o)
{
  int m = blockIdx.x * 256 + threadIdx.x;            // < 512*64
  int j = m >> 6, kc = m & 63;
  int ks = kc >> 2, lg = kc & 3;
  size_t addr = (((size_t)(j >> 4) * 16 + ks) * 64 + lg * 16 + (j & 15)) * 8;
  #pragma unroll
  for (int jj = 0; jj < 8; jj++) {
    int k = kc * 8 + jj;
    o[addr + jj] = bfr(W[(size_t)(j >> 6) * (DD * DHH) + (size_t)k * DHH + (j & 63)]);
  }
}

__global__ void k_prepLWb2(const float* __restrict__ a, short* __restrict__ o)
{
  int m = blockIdx.x * 256 + threadIdx.x;            // < 512*64
  int j = m >> 6, kc = m & 63;
  int ks = kc >> 2, lg = kc & 3;
  size_t addr = (((size_t)(j >> 4) * 16 + ks) * 64 + lg * 16 + (j & 15)) * 8;
  const float* src = a + (size_t)j * DD + kc * 8;
  #pragma unroll
  for (int jj = 0; jj < 8; jj++) o[addr + jj] = bfr(src[jj]);
}

__global__ void k_cvt(const float* __restrict__ a, short* __restrict__ o)
{
  int m = blockIdx.x * 256 + threadIdx.x;
  o[m] = bfr(a[m]);
}

// ---------------------------------------------------------------------------
// K2a: TM top-k (fp64 squared-norm ranking from f32 input).
// ---------------------------------------------------------------------------
__global__ void k_topk(const float* __restrict__ x, unsigned long long* __restrict__ sel)
{
  int g = blockIdx.x, lane = threadIdx.x;            // 64 threads
  const float* row = x + ((size_t)g * TT + lane) * DD;
  double s = 0.0;
  for (int dd = 0; dd < DD; dd += 4) {
    float4 v = *(const float4*)(row + dd);
    s += (double)v.x * (double)v.x + (double)v.y * (double)v.y
       + (double)v.z * (double)v.z + (double)v.w * (double)v.w;
  }
  __shared__ double mag[64];
  mag[lane] = s;
  __syncthreads();
  int rank = 0;
  for (int j = 0; j < 64; j++) {
    double m = mag[j];
    rank += (m > s) || (m == s && j < lane);
  }
  unsigned long long bal = __ballot(rank < KSEL);
  if (lane == 0) sel[g] = bal;
}

// ---------------------------------------------------------------------------
// K2b: FM top-k from precomputed f64 norm sums.
// ---------------------------------------------------------------------------
__global__ void k_topk2(const double* __restrict__ sums, unsigned long long* __restrict__ sel)
{
  int g = blockIdx.x, lane = threadIdx.x;
  double s = sums[(size_t)g * TT + lane];
  __shared__ double mag[64];
  mag[lane] = s;
  __syncthreads();
  int rank = 0;
  for (int j = 0; j < 64; j++) {
    double m = mag[j];
    rank += (m > s) || (m == s && j < lane);
  }
  unsigned long long bal = __ballot(rank < KSEL);
  if (lane == 0) sel[g] = bal;
}

// ---------------------------------------------------------------------------
// K3a/K4: flat GEMM  Out[M x 512] = Ab[M x 512](bf16) @ B(fragment-ordered).
// 4-deep register prefetch of A (counted vmcnt via per-reg compiler waits),
// B prefetched 1 step ahead; LDS double-buffer; fully unrolled K-loop.
// ---------------------------------------------------------------------------
__global__ __launch_bounds__(256) void k_gemm(
    const short* __restrict__ Ab, const short* __restrict__ Bbf,
    const float* __restrict__ bias, const float* __restrict__ Res,
    float* __restrict__ Outf, short* __restrict__ Outb,
    int Mtiles, int swz)
{
  __shared__ short Asl[2][128 * 40];                 // 80B rows
  const int wg = blockIdx.x;
  int mt, nt;
  if (swz) { int xcd = wg & 7, idx = wg >> 3; mt = xcd * (Mtiles >> 3) + (idx >> 2); nt = idx & 3; }
  else     { mt = wg >> 2; nt = wg & 3; }
  const int m0 = mt * 128, n0 = nt * 128;
  const int tid = threadIdx.x;
  const int l  = tid & 63;
  const int lr = l & 15, lg = l >> 4;
  const int wm = (tid >> 7) & 1, wn = (tid >> 6) & 1;   // wave quadrant

  const int srow = tid >> 1, skq = tid & 1;
  const short* gA = Ab + (size_t)(m0 + srow) * DD + skq * 16;
  const int soff = srow * 40 + skq * 16;

  // prologue: prefetch A steps 0..3 into 4 reg slots
  bf16x8 pa[4][2];
  #pragma unroll
  for (int s = 0; s < 4; s++) {
    pa[s][0] = *(const bf16x8*)(gA + s * 32);
    pa[s][1] = *(const bf16x8*)(gA + s * 32 + 8);
  }
  *(bf16x8*)&Asl[0][soff]     = pa[0][0];
  *(bf16x8*)&Asl[0][soff + 8] = pa[0][1];
  // B prefetch for step 0
  bf16x8 bnext[4];
  #pragma unroll
  for (int ni = 0; ni < 4; ni++)
    bnext[ni] = *(const bf16x8*)&Bbf[(((size_t)(nt * 8 + wn * 4 + ni) * 16 + 0) * 64 + l) * 8];
  __syncthreads();

  f32x4 acc[4][4] = {};
  #pragma unroll
  for (int ks = 0; ks < 16; ks++) {
    const int cur = ks & 1;
    if (ks + 4 < 16) {                               // A prefetch, 4 steps ahead
      pa[ks & 3][0] = *(const bf16x8*)(gA + (ks + 4) * 32);
      pa[ks & 3][1] = *(const bf16x8*)(gA + (ks + 4) * 32 + 8);
    }
    bf16x8 bcur[4];
    #pragma unroll
    for (int ni = 0; ni < 4; ni++) bcur[ni] = bnext[ni];
    if (ks + 1 < 16) {                               // B prefetch, 1 step ahead
      #pragma unroll
      for (int ni = 0; ni < 4; ni++)
        bnext[ni] = *(const bf16x8*)&Bbf[(((size_t)(nt * 8 + wn * 4 + ni) * 16 + ks + 1) * 64 + l) * 8];
    }
    bf16x8 af[4];
    #pragma unroll
    for (int mi = 0; mi < 4; mi++)
      af[mi] = *(const bf16x8*)&Asl[cur][(wm * 64 + mi * 16 + lr) * 40 + lg * 8];
    #pragma unroll
    for (int mi = 0; mi < 4; mi++)
      #pragma unroll
      for (int ni = 0; ni < 4; ni++)
        acc[mi][ni] = __builtin_amdgcn_mfma_f32_16x16x32_bf16(af[mi], bcur[ni], acc[mi][ni], 0, 0, 0);
    if (ks < 15) {
      *(bf16x8*)&Asl[cur ^ 1][soff]     = pa[(ks + 1) & 3][0];
      *(bf16x8*)&Asl[cur ^ 1][soff + 8] = pa[(ks + 1) & 3][1];
      __syncthreads();
    }
  }

  // epilogue (C/D layout: col = lr, row = lg*4 + r, validated)
  #pragma unroll
  for (int mi = 0; mi < 4; mi++) {
    #pragma unroll
    for (int r = 0; r < 4; r++) {
      const size_t row = (size_t)(m0 + wm * 64 + mi * 16 + lg * 4 + r);
      #pragma unroll
      for (int ni = 0; ni < 4; ni++) {
        const int col = n0 + wn * 64 + ni * 16 + lr;
        float v = acc[mi][ni][r];
        if (bias) v += bias[col];
        if (Res)  v += Res[row * DD + col];
        if (Outf) Outf[row * DD + col] = v;
        if (Outb) Outb[row * DD + col] = bfr(v);
      }
    }
  }
}

// ---------------------------------------------------------------------------
// K3b: fused GAT attention per (head, graph); h bf16 in-place.
// Softmax wave-parallel: 4 lanes per row, 16 j's each.
// ---------------------------------------------------------------------------
__global__ __launch_bounds__(256) void k_attn(
    short* __restrict__ tmp, const float* __restrict__ a1v,
    const float* __restrict__ a2v, const unsigned long long* __restrict__ sel)
{
  __shared__ float hs[64][68];
  __shared__ float attnv[64][68];
  __shared__ float s1[64], s2[64], aw[128], cnorm[64];
  const int h = blockIdx.x, g = blockIdx.y;
  const int tid = threadIdx.x;
  const int r = tid >> 4, c = tid & 15;
  short* base = tmp + (size_t)g * TT * DD + h * DHH;

  for (int i = tid; i < 4096; i += 256) {
    int t = i >> 6, dh = i & 63;
    hs[t][dh] = bf2f(base[(size_t)t * DD + dh]);
  }
  if (tid < 128) aw[tid] = (tid < 64) ? a1v[h * 64 + tid] : a2v[h * 64 + (tid - 64)];
  __syncthreads();

  const int i4 = tid >> 2, sub = tid & 3;
  {
    float v1 = 0.f, v2 = 0.f;
    #pragma unroll
    for (int q = 0; q < 16; q++) {
      int dh = sub * 16 + q;
      float hv = hs[i4][dh];
      v1 += hv * aw[dh]; v2 += hv * aw[64 + dh];
    }
    v1 += __shfl_xor(v1, 1); v1 += __shfl_xor(v1, 2);
    v2 += __shfl_xor(v2, 1); v2 += __shfl_xor(v2, 2);
    if (sub == 0) { s1[i4] = v1; s2[i4] = v2; }
  }
  __syncthreads();

  const unsigned long long sm = sel[g];
  {
    const bool seli = (sm >> i4) & 1ULL;
    const float vi = s1[i4];
    float ev[16];
    float mx = -1e30f;
    #pragma unroll
    for (int q = 0; q < 16; q++) {
      int j = sub * 16 + q;
      float e = vi + s2[j];
      e = e >= 0.f ? e : 0.2f * e;                   // leaky_relu(0.2)
      int dist = i4 > j ? i4 - j : j - i4;
      bool ok = (seli || ((sm >> j) & 1ULL)) && (dist <= DBAND);
      e = ok ? e : -9e15f;
      ev[q] = e;
      mx = fmaxf(mx, e);
    }
    mx = fmaxf(mx, __shfl_xor(mx, 1));
    mx = fmaxf(mx, __shfl_xor(mx, 2));
    float sum = 0.f;
    #pragma unroll
    for (int q = 0; q < 16; q++) { ev[q] = expf(ev[q] - mx); sum += ev[q]; }
    sum += __shfl_xor(sum, 1); sum += __shfl_xor(sum, 2);
    float inv = 1.f / sum;
    #pragma unroll
    for (int q = 0; q < 16; q++) attnv[i4][sub * 16 + q] = ev[q] * inv;
  }
  __syncthreads();

  float oc[4][4];
  #pragma unroll
  for (int i = 0; i < 4; i++)
    #pragma unroll
    for (int j = 0; j < 4; j++) oc[i][j] = 0.f;
  for (int j = 0; j < 64; j++) {
    float p[4];
    #pragma unroll
    for (int di = 0; di < 4; di++) p[di] = attnv[r * 4 + di][j];
    float4 hv = *(const float4*)&hs[j][c * 4];
    float hb[4] = {hv.x, hv.y, hv.z, hv.w};
    #pragma unroll
    for (int di = 0; di < 4; di++)
      #pragma unroll
      for (int dj = 0; dj < 4; dj++)
        oc[di][dj] += p[di] * hb[dj];
  }

  float cs4[4] = {0.f, 0.f, 0.f, 0.f};
  #pragma unroll
  for (int di = 0; di < 4; di++)
    #pragma unroll
    for (int dj = 0; dj < 4; dj++) {
      float v = oc[di][dj];
      v = v > 0.f ? v : expm1f(v);
      v = v >= 0.f ? sqrtf(v) : -sqrtf(-v);
      oc[di][dj] = v;
      cs4[dj] += v * v;
    }
  __syncthreads();
  *(float4*)&attnv[r][c * 4] = make_float4(cs4[0], cs4[1], cs4[2], cs4[3]);
  __syncthreads();
  if (tid < 64) {
    float ssum = 0.f;
    for (int rr = 0; rr < 16; rr++) ssum += attnv[rr][tid];
    cnorm[tid] = fmaxf(sqrtf(ssum), 1e-12f);
  }
  __syncthreads();
  float4 cn = *(const float4*)&cnorm[c * 4];
  float inv4[4] = {1.f / cn.x, 1.f / cn.y, 1.f / cn.z, 1.f / cn.w};
  #pragma unroll
  for (int di = 0; di < 4; di++) {
    short4 s4 = make_short4(bfr(oc[di][0] * inv4[0]), bfr(oc[di][1] * inv4[1]),
                            bfr(oc[di][2] * inv4[2]), bfr(oc[di][3] * inv4[3]));
    *(short4*)&base[(size_t)(r * 4 + di) * DD + c * 4] = s4;
  }
}

// ---------------------------------------------------------------------------
// K5: LayerNorm in-place (TM path), one wave per 512-row.
// ---------------------------------------------------------------------------
__global__ void k_ln(float* __restrict__ x, const float* __restrict__ gam, const float* __restrict__ bet)
{
  const size_t row = blockIdx.x;
  const int lane = threadIdx.x;
  float* p = x + row * DD + lane * 8;
  float4 v0 = *(float4*)p;
  float4 v1 = *(float4*)(p + 4);
  float va[8] = {v0.x, v0.y, v0.z, v0.w, v1.x, v1.y, v1.z, v1.w};
  float s = 0.f;
  #pragma unroll
  for (int i = 0; i < 8; i++) s += va[i];
  #pragma unroll
  for (int m = 32; m >= 1; m >>= 1) s += __shfl_xor(s, m);
  float mean = s * (1.f / 512.f);
  float q = 0.f;
  #pragma unroll
  for (int i = 0; i < 8; i++) { float d = va[i] - mean; q += d * d; }
  #pragma unroll
  for (int m = 32; m >= 1; m >>= 1) q += __shfl_xor(q, m);
  float rstd = rsqrtf(q * (1.f / 512.f) + 1e-5f);
  const float* gp = gam + lane * 8;
  const float* bp = bet + lane * 8;
  float4 g0 = *(const float4*)gp, g1 = *(const float4*)(gp + 4);
  float4 b0 = *(const float4*)bp, b1 = *(const float4*)(bp + 4);
  float ga[8] = {g0.x, g0.y, g0.z, g0.w, g1.x, g1.y, g1.z, g1.w};
  float ba[8] = {b0.x, b0.y, b0.z, b0.w, b1.x, b1.y, b1.z, b1.w};
  float o[8];
  #pragma unroll
  for (int i = 0; i < 8; i++) o[i] = (va[i] - mean) * rstd * ga[i] + ba[i];
  *(float4*)p       = make_float4(o[0], o[1], o[2], o[3]);
  *(float4*)(p + 4) = make_float4(o[4], o[5], o[6], o[7]);
}

// ---------------------------------------------------------------------------
// K6: fused LayerNorm + post 1x1 conv (512->1) for FM path: read y once,
// emit one scalar per row. One wave per row.
// ---------------------------------------------------------------------------
__global__ __launch_bounds__(256) void k_lnpost(
    const float* __restrict__ y, const float* __restrict__ gam,
    const float* __restrict__ bet, const float* __restrict__ pw,
    const float* __restrict__ pb, float* __restrict__ outp)
{
  const size_t row = (size_t)blockIdx.x * 4 + (threadIdx.x >> 6);
  const int lane = threadIdx.x & 63;
  const float* p = y + row * DD + lane * 8;
  float4 v0 = *(const float4*)p;
  float4 v1 = *(const float4*)(p + 4);
  float va[8] = {v0.x, v0.y, v0.z, v0.w, v1.x, v1.y, v1.z, v1.w};
  float s = 0.f;
  #pragma unroll
  for (int i = 0; i < 8; i++) s += va[i];
  #pragma unroll
  for (int m = 32; m >= 1; m >>= 1) s += __shfl_xor(s, m);
  float mean = s * (1.f / 512.f);
  float q = 0.f;
  #pragma unroll
  for (int i = 0; i < 8; i++) { float d = va[i] - mean; q += d * d; }
  #pragma unroll
  for (int m = 32; m >= 1; m >>= 1) q += __shfl_xor(q, m);
  float rstd = rsqrtf(q * (1.f / 512.f) + 1e-5f);
  float4 g0 = *(const float4*)(gam + lane * 8), g1 = *(const float4*)(gam + lane * 8 + 4);
  float4 b0 = *(const float4*)(bet + lane * 8), b1 = *(const float4*)(bet + lane * 8 + 4);
  float4 w0 = *(const float4*)(pw + lane * 8),  w1 = *(const float4*)(pw + lane * 8 + 4);
  float ga[8] = {g0.x, g0.y, g0.z, g0.w, g1.x, g1.y, g1.z, g1.w};
  float ba[8] = {b0.x, b0.y, b0.z, b0.w, b1.x, b1.y, b1.z, b1.w};
  float wv[8] = {w0.x, w0.y, w0.z, w0.w, w1.x, w1.y, w1.z, w1.w};
  float d = 0.f;
  #pragma unroll
  for (int i = 0; i < 8; i++) d += ((va[i] - mean) * rstd * ga[i] + ba[i]) * wv[i];
  #pragma unroll
  for (int m = 32; m >= 1; m >>= 1) d += __shfl_xor(d, m);
  if (lane == 0) {
    int gidx = (int)(row >> 6);
    int b = gidx / NPIX, hw = gidx - b * NPIX, t = (int)(row & 63);
    outp[(size_t)b * (TT * NPIX) + t * NPIX + hw] = d + pb[0];
  }
}

// ---------------------------------------------------------------------------
// K7: classifier Conv1d(512->512)+GELU(exact)+Conv1d(512->1), one block per (b,t).
// ---------------------------------------------------------------------------
__global__ __launch_bounds__(256) void k_cls(
    const float* __restrict__ xv, const float* __restrict__ w1,
    const float* __restrict__ b1, const float* __restrict__ w2,
    const float* __restrict__ b2, float* __restrict__ outp)
{
  const int m = blockIdx.x;                          // b*64+t
  const int tid = threadIdx.x;
  __shared__ float xr[512];
  __shared__ float red[256];
  xr[tid] = xv[(size_t)m * DD + tid];
  xr[tid + 256] = xv[(size_t)m * DD + tid + 256];
  __syncthreads();
  float part = 0.f;
  for (int o = tid; o < 512; o += 256) {
    const float* wr = w1 + (size_t)o * DD;
    float d = 0.f;
    for (int cc = 0; cc < DD; cc += 4) {
      float4 wv = *(const float4*)(wr + cc);
      d += wv.x * xr[cc] + wv.y * xr[cc + 1] + wv.z * xr[cc + 2] + wv.w * xr[cc + 3];
    }
    d += b1[o];
    float ge = 0.5f * d * (1.0f + erff(d * 0.70710678118654752f));
    part += ge * w2[o];
  }
  red[tid] = part;
  __syncthreads();
  for (int s = 128; s > 0; s >>= 1) {
    if (tid < s) red[tid] += red[tid + s];
    __syncthreads();
  }
  if (tid == 0) outp[m] = red[0] + b2[0];
}

// ---------------------------------------------------------------------------
extern "C" void kernel_launch(void* const* d_in, const int* in_sizes, int n_in,
                              void* d_out, int out_size, void* d_ws, size_t ws_size,
                              hipStream_t stream)
{
  const float* x_v    = (const float*)d_in[0];
  const float* fmap   = (const float*)d_in[1];
  const float* pre_w  = (const float*)d_in[2];
  const float* pre_b  = (const float*)d_in[3];
  const float* post_w = (const float*)d_in[4];
  const float* post_b = (const float*)d_in[5];
  const float* tm_W   = (const float*)d_in[6];
  const float* tm_a1  = (const float*)d_in[7];
  const float* tm_a2  = (const float*)d_in[8];
  const float* tm_lw  = (const float*)d_in[9];
  const float* tm_lb  = (const float*)d_in[10];
  const float* tm_g   = (const float*)d_in[11];
  const float* tm_b   = (const float*)d_in[12];
  const float* fm_W   = (const float*)d_in[13];
  const float* fm_a1  = (const float*)d_in[14];
  const float* fm_a2  = (const float*)d_in[15];
  const float* fm_lw  = (const float*)d_in[16];
  const float* fm_lb  = (const float*)d_in[17];
  const float* fm_g   = (const float*)d_in[18];
  const float* fm_b   = (const float*)d_in[19];
  const float* c_w1   = (const float*)d_in[20];
  const float* c_b1   = (const float*)d_in[21];
  const float* c_w2   = (const float*)d_in[22];
  const float* c_b2   = (const float*)d_in[23];
  float* out = (float*)d_out;

  // workspace carve-up (~210 MB)
  float* wsf    = (float*)d_ws;
  float* ax     = wsf;                           // 25,690,112 f
  short* axb    = (short*)(ax + 25690112);       // 25,690,112 bf16
  short* tmpb   = axb + 25690112;                // 25,690,112 bf16
  float* xtm    = (float*)(tmpb + 25690112);     // 131,072 f
  short* xvb    = (short*)(xtm + 131072);        // 131,072 bf16
  short* tmptmb = xvb + 131072;                  // 131,072 bf16
  short* WTb_fm = tmptmb + 131072;               // 262,144 bf16 (fragment order)
  short* WTb_tm = WTb_fm + 262144;               // 262,144 bf16
  short* LWb_fm = WTb_tm + 262144;               // 262,144 bf16
  short* LWb_tm = LWb_fm + 262144;               // 262,144 bf16
  short* pwf_hi = LWb_tm + 262144;               // 393,216 bf16 (fragment order)
  short* pwf_lo = pwf_hi + 393216;               // 393,216 bf16
  unsigned long long* sel_fm = (unsigned long long*)(pwf_lo + 393216); // 784
  unsigned long long* sel_tm = sel_fm + 784;                           // 4
  double* sums  = (double*)(sel_tm + 4);         // 50,176 f64 (topk partials)
  // fm fragment quarter-batch staging ALIASES tmpb (tmpb first written at
  // step 4). Per quarter: 64 imgs * 13*24*64*8 = 10,223,616 shorts each.
  short* fmh = tmpb;                             // 10,223,616 shorts
  short* fml = fmh + 10223616;                   // 10,223,616 shorts (< tmpb)

  // 0) zero topk partial sums (re-zeroed every call; atomics accumulate)
  hipMemsetAsync(sums, 0, (size_t)NG_FM * TT * sizeof(double), stream);

  // 1) weight preps (fragment order) + x_v bf16
  k_prepPW2<<<192, 256, 0, stream>>>(pre_w, pwf_hi, pwf_lo);
  k_prepWb2<<<128, 256, 0, stream>>>(fm_W, WTb_fm);
  k_prepWb2<<<128, 256, 0, stream>>>(tm_W, WTb_tm);
  k_prepLWb2<<<128, 256, 0, stream>>>(fm_lw, LWb_fm);
  k_prepLWb2<<<128, 256, 0, stream>>>(tm_lw, LWb_tm);
  k_cvt<<<512, 256, 0, stream>>>(x_v, xvb);

  // 2) pre head conv in four image-quarters (emits f64 norm partials)
  for (int qtr = 0; qtr < 4; qtr++) {
    k_prepFM3<<<dim3(12, 64), 256, 0, stream>>>(fmap, fmh, fml, qtr * 64);
    k_preconv3<<<512, 256, 0, stream>>>(fmh, fml, pwf_hi, pwf_lo, pre_b, ax, axb, sums, qtr * 64);
  }

  // 3) top-k selection bitmasks
  k_topk2<<<NG_FM, 64, 0, stream>>>(sums, sel_fm);
  k_topk<<<4, 64, 0, stream>>>(x_v, sel_tm);

  // 4) h = x @ Wcat  (pipelined MFMA GEMM, bf16 out)
  k_gemm<<<1568, 256, 0, stream>>>(axb, WTb_fm, nullptr, nullptr, nullptr, tmpb, 392, 1);
  k_gemm<<<8, 256, 0, stream>>>(xvb, WTb_tm, nullptr, nullptr, nullptr, tmptmb, 2, 0);

  // 5) fused attention + elu + signed-sqrt + column-normalize (bf16 in-place)
  k_attn<<<dim3(NHEAD, NG_FM), 256, 0, stream>>>(tmpb, fm_a1, fm_a2, sel_fm);
  k_attn<<<dim3(NHEAD, 4), 256, 0, stream>>>(tmptmb, tm_a1, tm_a2, sel_tm);

  // 6) x = x + tmp @ lin_w.T + lin_b  (pipelined GEMM; TM residual = x_v direct)
  k_gemm<<<1568, 256, 0, stream>>>(tmpb, LWb_fm, fm_lb, ax, ax, nullptr, 392, 1);
  k_gemm<<<8, 256, 0, stream>>>(tmptmb, LWb_tm, tm_lb, x_v, xtm, nullptr, 2, 0);

  // 7) FM: fused LN + post conv -> ano_map; TM: LN in-place
  k_lnpost<<<12544, 256, 0, stream>>>(ax, fm_g, fm_b, post_w, post_b, out + 256);
  k_ln<<<NIMG, 64, 0, stream>>>(xtm, tm_g, tm_b);

  // 8) classifier -> logits
  k_cls<<<NIMG, 256, 0, stream>>>(xtm, c_w1, c_b1, c_w2, c_b2, out);
}